// Round 2
// baseline (3667.263 us; speedup 1.0000x reference)
//
#include <hip/hip_runtime.h>
#include <cstdint>
#include <cstddef>

#define NNODES 50000
#define NRELS  500
#define NEDGE  500000
#define NNHOP  100000
#define NETOT  600000
#define D1     200

// ---------------------------------------------------------------- utilities
__global__ void k_zero(int* __restrict__ p, int n){
  int i = blockIdx.x*blockDim.x + threadIdx.x;
  if (i < n) p[i] = 0;
}

__global__ void k_mask_set(const int* __restrict__ batch, float* __restrict__ mask, int nb){
  int i = blockIdx.x*blockDim.x + threadIdx.x;
  if (i < nb) mask[batch[3*i+2]] = 1.0f;
}

// ---------------------------------------------------------------- edge sort (CSR by src)
__global__ void k_hist(const int* __restrict__ el, const int* __restrict__ nh, int* __restrict__ deg){
  int e = blockIdx.x*blockDim.x + threadIdx.x;
  if (e >= NETOT) return;
  int s = (e < NEDGE) ? el[e] : nh[4*(e-NEDGE)+3];
  atomicAdd(&deg[s], 1);
}

__global__ void k_scan1(int* __restrict__ data, int n, int* __restrict__ part){
  __shared__ int sh[256];
  int t = threadIdx.x, i = blockIdx.x*256 + t;
  int v = (i < n) ? data[i] : 0;
  sh[t] = v; __syncthreads();
  for (int o = 1; o < 256; o <<= 1){
    int x = (t >= o) ? sh[t-o] : 0;
    __syncthreads();
    sh[t] += x;
    __syncthreads();
  }
  if (i < n) data[i] = sh[t] - v;          // block-local exclusive
  if (t == 255) part[blockIdx.x] = sh[255]; // block total
}

__global__ void k_scan2(int* __restrict__ part, int nb){
  __shared__ int sh[256];
  int t = threadIdx.x;
  int v = (t < nb) ? part[t] : 0;
  sh[t] = v; __syncthreads();
  for (int o = 1; o < 256; o <<= 1){
    int x = (t >= o) ? sh[t-o] : 0;
    __syncthreads();
    sh[t] += x;
    __syncthreads();
  }
  if (t < nb) part[t] = sh[t] - v;         // exclusive block offsets
}

__global__ void k_scan3(int* __restrict__ data, int n, const int* __restrict__ part){
  int i = blockIdx.x*256 + threadIdx.x;
  if (i < n) data[i] += part[blockIdx.x];
  if (i == 0) data[n] = NETOT;
}

__global__ void k_scatter(const int* __restrict__ el, const int* __restrict__ et,
                          const int* __restrict__ nh, const int* __restrict__ rowofs,
                          int* __restrict__ cur, int* __restrict__ sdst,
                          int* __restrict__ set0, int* __restrict__ set1){
  int e = blockIdx.x*blockDim.x + threadIdx.x;
  if (e >= NETOT) return;
  int s, d, t0, t1;
  if (e < NEDGE){ s = el[e]; d = el[NEDGE+e]; t0 = et[e]; t1 = -1; }
  else { int i = e - NEDGE; s = nh[4*i+3]; d = nh[4*i+0]; t0 = nh[4*i+1]; t1 = nh[4*i+2]; }
  int p = rowofs[s] + atomicAdd(&cur[s], 1);
  sdst[p] = d; set0[p] = t0; set1[p] = t1;
}

// ---------------------------------------------------------------- row kernels
__global__ __launch_bounds__(64) void k_l2norm(const float* __restrict__ in, float* __restrict__ out, int D){
  int n = blockIdx.x, lane = threadIdx.x;
  const float* row = in + (size_t)n*D;
  float v[4]; float ss = 0.f;
  #pragma unroll
  for (int k = 0; k < 4; k++){ int c = lane + 64*k; v[k] = (c < D) ? row[c] : 0.f; ss += v[k]*v[k]; }
  #pragma unroll
  for (int o = 32; o; o >>= 1) ss += __shfl_xor(ss, o, 64);
  float sc = 1.0f / fmaxf(sqrtf(ss), 1e-12f);
  float* orow = out + (size_t)n*D;
  #pragma unroll
  for (int k = 0; k < 4; k++){ int c = lane + 64*k; if (c < D) orow[c] = v[k]*sc; }
}

// out = l2norm(base + m*h), m = mask[n] or 1.0
__global__ __launch_bounds__(64) void k_combine_norm(const float* __restrict__ base, const float* __restrict__ h,
                                                     const float* __restrict__ mask, float* __restrict__ out, int D){
  int n = blockIdx.x, lane = threadIdx.x;
  float m = mask ? mask[n] : 1.0f;
  const float* b = base + (size_t)n*D;
  const float* hr = h + (size_t)n*D;
  float v[4]; float ss = 0.f;
  #pragma unroll
  for (int k = 0; k < 4; k++){ int c = lane + 64*k; v[k] = (c < D) ? (b[c] + m*hr[c]) : 0.f; ss += v[k]*v[k]; }
  #pragma unroll
  for (int o = 32; o; o >>= 1) ss += __shfl_xor(ss, o, 64);
  float sc = 1.0f / fmaxf(sqrtf(ss), 1e-12f);
  float* orow = out + (size_t)n*D;
  #pragma unroll
  for (int k = 0; k < 4; k++){ int c = lane + 64*k; if (c < D) orow[c] = v[k]*sc; }
}

__global__ void k_transpose(const float* __restrict__ W, int K, int Nc, float* __restrict__ Wt){
  int idx = blockIdx.x*blockDim.x + threadIdx.x;
  if (idx >= K*Nc) return;
  int k = idx / Nc, j = idx % Nc;
  Wt[(size_t)j*K + k] = W[idx];
}

__global__ void k_rowdot(const float* __restrict__ X, int M, int D,
                         const float* __restrict__ a2, float* __restrict__ out){
  int wid = threadIdx.x >> 6, lane = threadIdx.x & 63;
  int row = blockIdx.x*4 + wid;
  if (row >= M) return;
  const float* r = X + (size_t)row*D;
  float p = 0.f;
  #pragma unroll
  for (int k = 0; k < 4; k++){ int c = lane + 64*k; if (c < D) p += r[c]*a2[c]; }
  #pragma unroll
  for (int o = 32; o; o >>= 1) p += __shfl_xor(p, o, 64);
  if (lane == 0) out[row] = p;
}

// ---------------------------------------------------------------- fp32 NT GEMM
// C[m][j] = sum_k A[m*lda+k] * B[j*ldb + boff + k];   C is M x Nn, ldc = Nn
#define BM 128
#define BN 64
#define BKK 32
__global__ __launch_bounds__(256) void k_gemm_nt(
    const float* __restrict__ A, int M, int K, int lda,
    const float* __restrict__ B, int ldb, int boff, int Nn,
    float* __restrict__ C, int ldc)
{
  __shared__ float As[BM][BKK+1];
  __shared__ float Bs[BN][BKK+1];
  int tid = threadIdx.x;
  int m0 = blockIdx.x * BM, n0 = blockIdx.y * BN;
  int tx = tid & 15, ty = tid >> 4;
  int kL = tid & 31, rBase = tid >> 5;   // rBase in [0,8)
  float acc[8][4] = {};

  for (int kk = 0; kk < K; kk += BKK){
    #pragma unroll
    for (int r = 0; r < 16; r++){
      int m = rBase + 8*r;               // 0..127
      int gm = m0 + m, gk = kk + kL;
      As[m][kL] = (gm < M && gk < K) ? A[(size_t)gm*lda + gk] : 0.f;
    }
    #pragma unroll
    for (int r = 0; r < 8; r++){
      int n = rBase + 8*r;               // 0..63
      int gn = n0 + n, gk = kk + kL;
      Bs[n][kL] = (gn < Nn && gk < K) ? B[(size_t)gn*ldb + boff + gk] : 0.f;
    }
    __syncthreads();
    #pragma unroll
    for (int k = 0; k < BKK; k++){
      float b[4];
      #pragma unroll
      for (int j = 0; j < 4; j++) b[j] = Bs[tx*4+j][k];
      #pragma unroll
      for (int i = 0; i < 8; i++){
        float a = As[ty*8+i][k];
        #pragma unroll
        for (int j = 0; j < 4; j++) acc[i][j] += a*b[j];
      }
    }
    __syncthreads();
  }
  #pragma unroll
  for (int i = 0; i < 8; i++){
    int gm = m0 + ty*8 + i;
    if (gm >= M) continue;
    #pragma unroll
    for (int j = 0; j < 4; j++){
      int gn = n0 + tx*4 + j;
      if (gn < Nn) C[(size_t)gm*ldc + gn] = acc[i][j];
    }
  }
}

// ---------------------------------------------------------------- attention aggregation
// one wave per src node; h'[n] = elu( xs[n] + (sum_e w_e*(xd[dst]+rr[t0](+rr[t1])))/S ), 0 if S==0
__global__ __launch_bounds__(64) void k_agg(
    const int* __restrict__ rowofs, const int* __restrict__ sdst,
    const int* __restrict__ set0, const int* __restrict__ set1,
    const float* __restrict__ ps, const float* __restrict__ pd, const float* __restrict__ prs,
    const float* xs, const float* __restrict__ xd, const float* __restrict__ rr,
    float* out, int D, int ldOut, int coff)
{
  int n = blockIdx.x, lane = threadIdx.x;
  int beg = rowofs[n], end = rowofs[n+1];
  float acc[4] = {0.f,0.f,0.f,0.f};
  float S = 0.f;
  float psn = ps[n];
  for (int i = beg; i < end; ++i){
    int d = sdst[i], t0 = set0[i], t1 = set1[i];
    float logit = psn + pd[d] + prs[t0];
    const float* xr = xd + (size_t)d*D;
    const float* r0 = rr + (size_t)t0*D;
    if (t1 >= 0){
      logit += prs[t1];
      const float* r1 = rr + (size_t)t1*D;
      float lr = (logit > 0.f) ? logit : 0.2f*logit;
      float wgt = expf(-lr);
      S += wgt;
      #pragma unroll
      for (int k = 0; k < 4; k++){ int c = lane + 64*k; if (c < D) acc[k] += wgt*(xr[c] + r0[c] + r1[c]); }
    } else {
      float lr = (logit > 0.f) ? logit : 0.2f*logit;
      float wgt = expf(-lr);
      S += wgt;
      #pragma unroll
      for (int k = 0; k < 4; k++){ int c = lane + 64*k; if (c < D) acc[k] += wgt*(xr[c] + r0[c]); }
    }
  }
  float inv = (S > 0.f) ? 1.0f/S : 0.f;
  const float* xrow = xs + (size_t)n*D;
  float* orow = out + (size_t)n*ldOut + coff;
  #pragma unroll
  for (int k = 0; k < 4; k++){
    int c = lane + 64*k;
    if (c < D){
      float hv = (S > 0.f) ? (xrow[c] + acc[k]*inv) : 0.f;
      hv = (hv > 0.f) ? hv : expm1f(hv);     // elu (applied in all 5 calls)
      orow[c] = hv;
    }
  }
}

// ---------------------------------------------------------------- driver
extern "C" void kernel_launch(void* const* d_in, const int* in_sizes, int n_in,
                              void* d_out, int out_size, void* d_ws, size_t ws_size,
                              hipStream_t stream) {
  const float* entity   = (const float*)d_in[0];
  const float* relation = (const float*)d_in[1];
  const float* W_ent    = (const float*)d_in[2];
  const float* g0_a0    = (const float*)d_in[3];
  const float* g0_s0    = (const float*)d_in[4];
  const float* g0_a1    = (const float*)d_in[5];
  const float* g0_s1    = (const float*)d_in[6];
  const float* g0_W     = (const float*)d_in[7];
  const float* g0_oa    = (const float*)d_in[8];
  const float* g0_os    = (const float*)d_in[9];
  const float* g1_a0    = (const float*)d_in[10];
  const float* g1_s0    = (const float*)d_in[11];
  const float* g1_W     = (const float*)d_in[12];
  const float* g1_oa    = (const float*)d_in[13];
  const float* g1_os    = (const float*)d_in[14];
  const int*   el       = (const int*)d_in[15];
  const int*   et       = (const int*)d_in[16];
  const int*   nh       = (const int*)d_in[17];
  const int*   batch    = (const int*)d_in[18];

  // ---- workspace layout (~231 MB) ----
  char* w = (char*)d_ws;
  auto alloc = [&](size_t bytes)->char*{ char* p = w; w += (bytes + 255) & ~(size_t)255; return p; };
  float* ENT0  = (float*)alloc((size_t)NNODES*100*4);
  float* ENTUP = (float*)alloc((size_t)NNODES*D1*4);
  float* X1    = (float*)alloc((size_t)NNODES*D1*4);   // layer0 concat out; reused as x2 in layer1
  float* ENT1  = (float*)alloc((size_t)NNODES*D1*4);
  float* XS    = (float*)alloc((size_t)NNODES*D1*4);   // xs; also aliased as h-buffer (row n read-then-written by same thread)
  float* XD    = (float*)alloc((size_t)NNODES*D1*4);
  float* REL0  = (float*)alloc((size_t)NRELS*100*4);
  float* RELUP = (float*)alloc((size_t)NRELS*D1*4);
  float* REL1  = (float*)alloc((size_t)NRELS*D1*4);
  float* OR0   = (float*)alloc((size_t)NRELS*D1*4);
  float* OR1   = (float*)alloc((size_t)NRELS*D1*4);
  float* RR    = (float*)alloc((size_t)NRELS*D1*4);
  float* PS    = (float*)alloc((size_t)NNODES*4);
  float* PD    = (float*)alloc((size_t)NNODES*4);
  float* PRS   = (float*)alloc((size_t)NRELS*4);
  float* MASK  = (float*)alloc((size_t)NNODES*4);
  float* WET   = (float*)alloc((size_t)200*100*4);
  float* G0WT  = (float*)alloc((size_t)200*100*4);
  float* G1WT  = (float*)alloc((size_t)200*200*4);
  int*   ROWOFS= (int*)alloc((size_t)(NNODES+1)*4);
  int*   CUR   = (int*)alloc((size_t)NNODES*4);
  int*   PART  = (int*)alloc((size_t)256*4);
  int*   SDST  = (int*)alloc((size_t)NETOT*4);
  int*   SET0  = (int*)alloc((size_t)NETOT*4);
  int*   SET1  = (int*)alloc((size_t)NETOT*4);
  (void)ws_size; (void)in_sizes; (void)n_in; (void)out_size;

  float* outEnt = (float*)d_out;
  float* outRel = outEnt + (size_t)NNODES*D1;

  const int TB = 256;
  auto gb = [&](int n){ return (n + TB - 1)/TB; };

  // ---- graph preprocessing (once per launch, deterministic work) ----
  k_zero<<<gb(NNODES+1), TB, 0, stream>>>(ROWOFS, NNODES+1);
  k_zero<<<gb(NNODES),   TB, 0, stream>>>(CUR,    NNODES);
  k_zero<<<gb(NNODES),   TB, 0, stream>>>((int*)MASK, NNODES);
  k_mask_set<<<gb(10000), TB, 0, stream>>>(batch, MASK, 10000);
  k_hist<<<gb(NETOT), TB, 0, stream>>>(el, nh, ROWOFS);
  int nScanBlocks = (NNODES + 255)/256;          // 196
  k_scan1<<<nScanBlocks, 256, 0, stream>>>(ROWOFS, NNODES, PART);
  k_scan2<<<1, 256, 0, stream>>>(PART, nScanBlocks);
  k_scan3<<<nScanBlocks, 256, 0, stream>>>(ROWOFS, NNODES, PART);
  k_scatter<<<gb(NETOT), TB, 0, stream>>>(el, et, nh, ROWOFS, CUR, SDST, SET0, SET1);

  // ---- input normalization, weight transposes ----
  k_l2norm<<<NNODES, 64, 0, stream>>>(entity,   ENT0, 100);
  k_l2norm<<<NRELS,  64, 0, stream>>>(relation, REL0, 100);
  k_transpose<<<gb(100*200), TB, 0, stream>>>(W_ent, 100, 200, WET);
  k_transpose<<<gb(100*200), TB, 0, stream>>>(g0_W,  100, 200, G0WT);
  k_transpose<<<gb(200*200), TB, 0, stream>>>(g1_W,  200, 200, G1WT);

  auto gemm = [&](const float* A, int M, int K, int lda, const float* B, int ldb, int boff, int Nn, float* C){
    dim3 g((M + BM - 1)/BM, (Nn + BN - 1)/BN);
    k_gemm_nt<<<g, 256, 0, stream>>>(A, M, K, lda, B, ldb, boff, Nn, C, Nn);
  };
  auto rowdot = [&](const float* X, int M, int D, const float* a2, float* o){
    k_rowdot<<<(M + 3)/4, 256, 0, stream>>>(X, M, D, a2, o);
  };
  auto agg = [&](const float* xs, const float* xd, const float* rr, float* out, int D, int ldOut, int coff){
    k_agg<<<NNODES, 64, 0, stream>>>(ROWOFS, SDST, SET0, SET1, PS, PD, PRS, xs, xd, rr, out, D, ldOut, coff);
  };

  // ---- ent_up / rel_up ----
  gemm(ENT0, NNODES, 100, 100, WET, 100, 0, 200, ENTUP);
  gemm(REL0, NRELS,  100, 100, WET, 100, 0, 200, RELUP);

  // ---- layer0: two heads (din=100 -> dout=100 each) ----
  for (int h = 0; h < 2; h++){
    const float* aw = h ? g0_a1 : g0_a0;
    const float* s2 = h ? g0_s1 : g0_s0;
    gemm(ENT0, NNODES, 100, 100, aw, 300, 0,   100, XS);
    gemm(ENT0, NNODES, 100, 100, aw, 300, 100, 100, XD);
    gemm(REL0, NRELS,  100, 100, aw, 300, 200, 100, RR);
    rowdot(XS, NNODES, 100, s2, PS);
    rowdot(XD, NNODES, 100, s2, PD);
    rowdot(RR, NRELS,  100, s2, PRS);
    agg(XS, XD, RR, X1, 100, 200, h*100);
  }

  // ---- layer0: output attention (din=200 -> 200) ----
  gemm(REL0, NRELS, 100, 100, G0WT, 100, 0, 200, OR0);       // out_rel0 = rel0 @ g0_W
  gemm(X1, NNODES, 200, 200, g0_oa, 600, 0,   200, XS);
  gemm(X1, NNODES, 200, 200, g0_oa, 600, 200, 200, XD);
  gemm(OR0, NRELS, 200, 200, g0_oa, 600, 400, 200, RR);
  rowdot(XS, NNODES, 200, g0_os, PS);
  rowdot(XD, NNODES, 200, g0_os, PD);
  rowdot(RR, NRELS,  200, g0_os, PRS);
  agg(XS, XD, RR, XS, 200, 200, 0);                          // h-buffer aliases XS (safe: per-row read-then-write)
  k_combine_norm<<<NNODES, 64, 0, stream>>>(ENTUP, XS, MASK, ENT1, 200);
  k_combine_norm<<<NRELS,  64, 0, stream>>>(RELUP, OR0, nullptr, REL1, 200);

  // ---- layer1: one head (din=200 -> 200) ----
  gemm(ENT1, NNODES, 200, 200, g1_a0, 600, 0,   200, XS);
  gemm(ENT1, NNODES, 200, 200, g1_a0, 600, 200, 200, XD);
  gemm(REL1, NRELS,  200, 200, g1_a0, 600, 400, 200, RR);
  rowdot(XS, NNODES, 200, g1_s0, PS);
  rowdot(XD, NNODES, 200, g1_s0, PD);
  rowdot(RR, NRELS,  200, g1_s0, PRS);
  agg(XS, XD, RR, X1, 200, 200, 0);                          // x2 reuses X1 buffer

  // ---- layer1: output attention ----
  gemm(REL1, NRELS, 200, 200, G1WT, 200, 0, 200, OR1);       // out_rel1 = rel1 @ g1_W
  gemm(X1, NNODES, 200, 200, g1_oa, 600, 0,   200, XS);
  gemm(X1, NNODES, 200, 200, g1_oa, 600, 200, 200, XD);
  gemm(OR1, NRELS, 200, 200, g1_oa, 600, 400, 200, RR);
  rowdot(XS, NNODES, 200, g1_os, PS);
  rowdot(XD, NNODES, 200, g1_os, PD);
  rowdot(RR, NRELS,  200, g1_os, PRS);
  agg(XS, XD, RR, XS, 200, 200, 0);

  // ---- final combines -> d_out ----
  k_combine_norm<<<NNODES, 64, 0, stream>>>(ENT1, XS, MASK, outEnt, 200);
  k_combine_norm<<<NRELS,  64, 0, stream>>>(REL1, OR1, nullptr, outRel, 200);
}

// Round 3
// 1391.627 us; speedup vs baseline: 2.6352x; 2.6352x over previous
//
#include <hip/hip_runtime.h>
#include <hip/hip_bf16.h>
#include <cstdint>
#include <cstddef>

#define NNODES 50000
#define NRELS  500
#define NEDGE  500000
#define NNHOP  100000
#define NETOT  600000

typedef __attribute__((ext_vector_type(8))) short bf16x8;
typedef __attribute__((ext_vector_type(4))) float f32x4;

// ---------------------------------------------------------------- utilities
__global__ void k_zero(int* __restrict__ p, int n){
  int i = blockIdx.x*blockDim.x + threadIdx.x;
  if (i < n) p[i] = 0;
}

__global__ void k_mask_set(const int* __restrict__ batch, float* __restrict__ mask, int nb){
  int i = blockIdx.x*blockDim.x + threadIdx.x;
  if (i < nb) mask[batch[3*i+2]] = 1.0f;
}

__global__ void k_padcols(__hip_bfloat16* __restrict__ dst, int Mpad, int K, int Kp){
  int padw = Kp - K;
  int i = blockIdx.x*blockDim.x + threadIdx.x;
  if (i >= Mpad*padw) return;
  int r = i / padw, k = K + (i - (i/padw)*padw);
  dst[(size_t)r*Kp + k] = __float2bfloat16(0.f);
}

// ---------------------------------------------------------------- edge CSR (by src, 1hop|nhop split)
__global__ void k_hist2(const int* __restrict__ el, const int* __restrict__ nh,
                        int* __restrict__ degT, int* __restrict__ deg1){
  int e = blockIdx.x*blockDim.x + threadIdx.x;
  if (e >= NETOT) return;
  if (e < NEDGE){ int s = el[e]; atomicAdd(&degT[s], 1); atomicAdd(&deg1[s], 1); }
  else { int s = nh[4*(e-NEDGE)+3]; atomicAdd(&degT[s], 1); }
}

__global__ void k_scan1(int* __restrict__ data, int n, int* __restrict__ part){
  __shared__ int sh[256];
  int t = threadIdx.x, i = blockIdx.x*256 + t;
  int v = (i < n) ? data[i] : 0;
  sh[t] = v; __syncthreads();
  for (int o = 1; o < 256; o <<= 1){
    int x = (t >= o) ? sh[t-o] : 0;
    __syncthreads();
    sh[t] += x;
    __syncthreads();
  }
  if (i < n) data[i] = sh[t] - v;
  if (t == 255) part[blockIdx.x] = sh[255];
}

__global__ void k_scan2(int* __restrict__ part, int nb){
  __shared__ int sh[256];
  int t = threadIdx.x;
  int v = (t < nb) ? part[t] : 0;
  sh[t] = v; __syncthreads();
  for (int o = 1; o < 256; o <<= 1){
    int x = (t >= o) ? sh[t-o] : 0;
    __syncthreads();
    sh[t] += x;
    __syncthreads();
  }
  if (t < nb) part[t] = sh[t] - v;
}

__global__ void k_scan3(int* __restrict__ data, int n, const int* __restrict__ part){
  int i = blockIdx.x*256 + threadIdx.x;
  if (i < n) data[i] += part[blockIdx.x];
  if (i == 0) data[n] = NETOT;
}

__global__ void k_split(const int* __restrict__ rowofs, const int* __restrict__ deg1,
                        int* __restrict__ split){
  int i = blockIdx.x*blockDim.x + threadIdx.x;
  if (i < NNODES) split[i] = rowofs[i] + deg1[i];
}

__global__ void k_scatter2(const int* __restrict__ el, const int* __restrict__ et,
                           const int* __restrict__ nh, const int* __restrict__ rowofs,
                           const int* __restrict__ split,
                           int* __restrict__ cur1, int* __restrict__ curN,
                           int* __restrict__ sdst, int* __restrict__ set0, int* __restrict__ set1){
  int e = blockIdx.x*blockDim.x + threadIdx.x;
  if (e >= NETOT) return;
  if (e < NEDGE){
    int s = el[e];
    int p = rowofs[s] + atomicAdd(&cur1[s], 1);
    sdst[p] = el[NEDGE+e]; set0[p] = et[e];
  } else {
    int i = e - NEDGE;
    int s = nh[4*i+3];
    int p = split[s] + atomicAdd(&curN[s], 1);
    sdst[p] = nh[4*i+0]; set0[p] = nh[4*i+1]; set1[p] = nh[4*i+2];
  }
}

// ---------------------------------------------------------------- row kernels
// l2norm(in[M][D]) -> bf16 [M][KP] (pad cols zero)
template<int D, int KP>
__global__ __launch_bounds__(64) void k_l2norm_bf(const float* __restrict__ in,
                                                  __hip_bfloat16* __restrict__ bfout){
  constexpr int NK = KP/64;
  int n = blockIdx.x, lane = threadIdx.x;
  const float* row = in + (size_t)n*D;
  float v[NK]; float ss = 0.f;
  #pragma unroll
  for (int k = 0; k < NK; k++){ int c = lane + 64*k; v[k] = (c < D) ? row[c] : 0.f; ss += v[k]*v[k]; }
  #pragma unroll
  for (int o = 32; o; o >>= 1) ss += __shfl_xor(ss, o, 64);
  float sc = 1.0f / fmaxf(sqrtf(ss), 1e-12f);
  __hip_bfloat16* orow = bfout + (size_t)n*KP;
  #pragma unroll
  for (int k = 0; k < NK; k++){ int c = lane + 64*k; orow[c] = __float2bfloat16(v[k]*sc); }
}

// out = l2norm(base + m*h); fp32 out (c<D) and optional bf16 out (c<KP, pad zero)
template<int D, int KP>
__global__ __launch_bounds__(64) void k_combine_norm(const float* __restrict__ base,
                                                     const float* __restrict__ h,
                                                     const float* __restrict__ mask,
                                                     float* __restrict__ outf,
                                                     __hip_bfloat16* __restrict__ outb){
  constexpr int NK = (KP+63)/64;
  int n = blockIdx.x, lane = threadIdx.x;
  float m = mask ? mask[n] : 1.0f;
  const float* b = base + (size_t)n*D;
  const float* hr = h + (size_t)n*D;
  float v[NK]; float ss = 0.f;
  #pragma unroll
  for (int k = 0; k < NK; k++){ int c = lane + 64*k; v[k] = (c < D) ? (b[c] + m*hr[c]) : 0.f; ss += v[k]*v[k]; }
  #pragma unroll
  for (int o = 32; o; o >>= 1) ss += __shfl_xor(ss, o, 64);
  float sc = 1.0f / fmaxf(sqrtf(ss), 1e-12f);
  float* orow = outf + (size_t)n*D;
  #pragma unroll
  for (int k = 0; k < NK; k++){ int c = lane + 64*k; if (c < D) orow[c] = v[k]*sc; }
  if (outb){
    __hip_bfloat16* brow = outb + (size_t)n*KP;
    #pragma unroll
    for (int k = 0; k < NK; k++){ int c = lane + 64*k; if (c < KP) brow[c] = __float2bfloat16(v[k]*sc); }
  }
}

__global__ void k_rowdot(const float* __restrict__ X, int M, int D,
                         const float* __restrict__ a2, float* __restrict__ out){
  int wid = threadIdx.x >> 6, lane = threadIdx.x & 63;
  int row = blockIdx.x*4 + wid;
  if (row >= M) return;
  const float* r = X + (size_t)row*D;
  float p = 0.f;
  #pragma unroll
  for (int k = 0; k < 4; k++){ int c = lane + 64*k; if (c < D) p += r[c]*a2[c]; }
  #pragma unroll
  for (int o = 32; o; o >>= 1) p += __shfl_xor(p, o, 64);
  if (lane == 0) out[row] = p;
}

// ---------------------------------------------------------------- weight -> bf16 slices
// dst[r][k] = src[r*ldsrc + boff + k]  (zero-pad r>=rows, k>=K)
__global__ void k_w2bf_nt(const float* __restrict__ src, int ldsrc, int boff,
                          int rows, int K, __hip_bfloat16* __restrict__ dst, int Kp, int rowsPad){
  int i = blockIdx.x*blockDim.x + threadIdx.x;
  if (i >= rowsPad*Kp) return;
  int r = i / Kp, k = i - r*Kp;
  float v = (r < rows && k < K) ? src[(size_t)r*ldsrc + boff + k] : 0.f;
  dst[i] = __float2bfloat16(v);
}

// dst[r][k] = src[k*ldsrc + r]  (transpose)
__global__ void k_w2bf_t(const float* __restrict__ src, int ldsrc,
                         int rows, int K, __hip_bfloat16* __restrict__ dst, int Kp, int rowsPad){
  int i = blockIdx.x*blockDim.x + threadIdx.x;
  if (i >= rowsPad*Kp) return;
  int r = i / Kp, k = i - r*Kp;
  float v = (r < rows && k < K) ? src[(size_t)k*ldsrc + r] : 0.f;
  dst[i] = __float2bfloat16(v);
}

// ---------------------------------------------------------------- bf16 MFMA GEMM (NT)
// C[m][c] = sum_k A[m][k]*B[c][k]; A [Mpad][Kp] bf16, B [Npad][Kp] bf16, both zero-padded.
// Tile 128x64, 4 waves (2x2), 16x16x32 MFMA, global_load_lds staging, chunk-XOR swizzle.
__global__ __launch_bounds__(256) void k_gemm_mfma(
    const __hip_bfloat16* __restrict__ A, const __hip_bfloat16* __restrict__ B,
    float* __restrict__ C, int M, int Nn, int Kp, int ldc)
{
  __shared__ __hip_bfloat16 As[128*32];   // 8 KB, [row][k] rows of 64B = 4 chunks, swizzled
  __shared__ __hip_bfloat16 Bs[64*32];    // 4 KB
  const int tid = threadIdx.x;
  const int wave = tid >> 6, lane = tid & 63;
  const int lg = lane >> 4, li = lane & 15;
  const int m0 = blockIdx.y * 128, n0 = blockIdx.x * 64;
  const int wr = wave >> 1, wc = wave & 1;
  f32x4 acc[4][2] = {};

  const int ar0 = tid >> 2;          // A row, round 0 (0..63)
  const int ar1 = (tid + 256) >> 2;  // A row, round 1 (64..127)
  const int ap  = tid & 3;           // LDS chunk position within row
  const char* Ab = (const char*)A;
  const char* Bb = (const char*)B;
  char* asB = (char*)As;
  char* bsB = (char*)Bs;

  for (int kk = 0; kk < Kp; kk += 32){
    {
      int g0 = ap ^ ((ar0 >> 1) & 3);
      const char* s0 = Ab + ((size_t)(m0 + ar0)*Kp + kk)*2 + g0*16;
      __builtin_amdgcn_global_load_lds((const __attribute__((address_space(1))) void*)s0,
          (__attribute__((address_space(3))) void*)(asB + wave*1024), 16, 0, 0);
      int g1 = ap ^ ((ar1 >> 1) & 3);
      const char* s1 = Ab + ((size_t)(m0 + ar1)*Kp + kk)*2 + g1*16;
      __builtin_amdgcn_global_load_lds((const __attribute__((address_space(1))) void*)s1,
          (__attribute__((address_space(3))) void*)(asB + 4096 + wave*1024), 16, 0, 0);
      int gb = ap ^ ((ar0 >> 1) & 3);
      const char* sb = Bb + ((size_t)(n0 + ar0)*Kp + kk)*2 + gb*16;
      __builtin_amdgcn_global_load_lds((const __attribute__((address_space(1))) void*)sb,
          (__attribute__((address_space(3))) void*)(bsB + wave*1024), 16, 0, 0);
    }
    __syncthreads();
    bf16x8 av[4], bv[2];
    #pragma unroll
    for (int mf = 0; mf < 4; mf++){
      int row = wr*64 + mf*16 + li;
      int p = lg ^ ((row >> 1) & 3);
      av[mf] = *(const bf16x8*)(asB + row*64 + p*16);
    }
    #pragma unroll
    for (int nf = 0; nf < 2; nf++){
      int row = wc*32 + nf*16 + li;
      int p = lg ^ ((row >> 1) & 3);
      bv[nf] = *(const bf16x8*)(bsB + row*64 + p*16);
    }
    #pragma unroll
    for (int mf = 0; mf < 4; mf++)
      #pragma unroll
      for (int nf = 0; nf < 2; nf++)
        acc[mf][nf] = __builtin_amdgcn_mfma_f32_16x16x32_bf16(av[mf], bv[nf], acc[mf][nf], 0, 0, 0);
    __syncthreads();
  }
  #pragma unroll
  for (int mf = 0; mf < 4; mf++){
    #pragma unroll
    for (int nf = 0; nf < 2; nf++){
      int gc = n0 + wc*32 + nf*16 + li;
      if (gc >= Nn) continue;
      int gr0 = m0 + wr*64 + mf*16 + lg*4;
      #pragma unroll
      for (int r = 0; r < 4; r++){
        int gr = gr0 + r;
        if (gr < M) C[(size_t)gr*ldc + gc] = acc[mf][nf][r];
      }
    }
  }
}

// ---------------------------------------------------------------- OR -> bf16 padded (reuse k_w2bf_nt)

// ---------------------------------------------------------------- attention aggregation v2
// 4 waves/block, one node per wave. CSR split: [beg,sp) 1-hop, [sp,end) n-hop.
template<int DD>
__global__ __launch_bounds__(256) void k_agg2(
    const int* __restrict__ rowofs, const int* __restrict__ split,
    const int* __restrict__ sdst, const int* __restrict__ set0, const int* __restrict__ set1,
    const float* __restrict__ ps, const float* __restrict__ pd, const float* __restrict__ prs,
    const float* __restrict__ xs, const float* __restrict__ xd, const float* __restrict__ rr,
    float* __restrict__ outf, int coff_f,
    __hip_bfloat16* __restrict__ outb, int ldb, int coffb)
{
  constexpr int NK = (DD + 63)/64;
  int wave = threadIdx.x >> 6, lane = threadIdx.x & 63;
  int n = blockIdx.x*4 + wave;
  int beg = rowofs[n], sp = split[n], end = rowofs[n+1];
  float acc[NK];
  #pragma unroll
  for (int k = 0; k < NK; k++) acc[k] = 0.f;
  float S = 0.f;
  float psn = ps[n];

  int i = beg;
  for (; i + 1 < sp; i += 2){
    int d0 = sdst[i],   t0 = set0[i];
    int d1 = sdst[i+1], t1 = set0[i+1];
    float l0 = psn + pd[d0] + prs[t0];
    float l1 = psn + pd[d1] + prs[t1];
    float w0 = __expf(-((l0 > 0.f) ? l0 : 0.2f*l0));
    float w1 = __expf(-((l1 > 0.f) ? l1 : 0.2f*l1));
    const float* x0 = xd + (size_t)d0*DD;
    const float* r0 = rr + (size_t)t0*DD;
    const float* x1 = xd + (size_t)d1*DD;
    const float* r1 = rr + (size_t)t1*DD;
    S += w0 + w1;
    #pragma unroll
    for (int k = 0; k < NK; k++){
      int c = lane + 64*k;
      if (c < DD) acc[k] += w0*(x0[c] + r0[c]) + w1*(x1[c] + r1[c]);
    }
  }
  if (i < sp){
    int d0 = sdst[i], t0 = set0[i];
    float l0 = psn + pd[d0] + prs[t0];
    float w0 = __expf(-((l0 > 0.f) ? l0 : 0.2f*l0));
    const float* x0 = xd + (size_t)d0*DD;
    const float* r0 = rr + (size_t)t0*DD;
    S += w0;
    #pragma unroll
    for (int k = 0; k < NK; k++){
      int c = lane + 64*k;
      if (c < DD) acc[k] += w0*(x0[c] + r0[c]);
    }
  }
  for (i = sp; i < end; ++i){
    int d = sdst[i], t0 = set0[i], t1 = set1[i];
    float lg = psn + pd[d] + prs[t0] + prs[t1];
    float w = __expf(-((lg > 0.f) ? lg : 0.2f*lg));
    const float* x0 = xd + (size_t)d*DD;
    const float* r0 = rr + (size_t)t0*DD;
    const float* r1 = rr + (size_t)t1*DD;
    S += w;
    #pragma unroll
    for (int k = 0; k < NK; k++){
      int c = lane + 64*k;
      if (c < DD) acc[k] += w*(x0[c] + r0[c] + r1[c]);
    }
  }

  float inv = (S > 0.f) ? 1.0f/S : 0.f;
  const float* xrow = xs + (size_t)n*DD;
  #pragma unroll
  for (int k = 0; k < NK; k++){
    int c = lane + 64*k;
    if (c < DD){
      float hv = (S > 0.f) ? (xrow[c] + acc[k]*inv) : 0.f;
      hv = (hv > 0.f) ? hv : expm1f(hv);          // elu (all 5 calls)
      if (outf) outf[(size_t)n*DD + coff_f + c] = hv;
      if (outb) outb[(size_t)n*ldb + coffb + c] = __float2bfloat16(hv);
    }
  }
}

// ---------------------------------------------------------------- driver
extern "C" void kernel_launch(void* const* d_in, const int* in_sizes, int n_in,
                              void* d_out, int out_size, void* d_ws, size_t ws_size,
                              hipStream_t stream) {
  const float* entity   = (const float*)d_in[0];
  const float* relation = (const float*)d_in[1];
  const float* W_ent    = (const float*)d_in[2];
  const float* g0_a0    = (const float*)d_in[3];
  const float* g0_s0    = (const float*)d_in[4];
  const float* g0_a1    = (const float*)d_in[5];
  const float* g0_s1    = (const float*)d_in[6];
  const float* g0_W     = (const float*)d_in[7];
  const float* g0_oa    = (const float*)d_in[8];
  const float* g0_os    = (const float*)d_in[9];
  const float* g1_a0    = (const float*)d_in[10];
  const float* g1_s0    = (const float*)d_in[11];
  const float* g1_W     = (const float*)d_in[12];
  const float* g1_oa    = (const float*)d_in[13];
  const float* g1_os    = (const float*)d_in[14];
  const int*   el       = (const int*)d_in[15];
  const int*   et       = (const int*)d_in[16];
  const int*   nh       = (const int*)d_in[17];
  const int*   batch    = (const int*)d_in[18];
  (void)in_sizes; (void)n_in; (void)out_size; (void)ws_size;

  const int MP = 50048;   // 391*128
  const int RP = 512;     // rel rows padded

  char* w = (char*)d_ws;
  auto alloc = [&](size_t bytes)->char*{ char* p = w; w += (bytes + 255) & ~(size_t)255; return p; };
  // fp32
  float* ENTUP = (float*)alloc((size_t)NNODES*200*4);
  float* ENT1  = (float*)alloc((size_t)NNODES*200*4);
  float* XS    = (float*)alloc((size_t)NNODES*200*4);
  float* XD    = (float*)alloc((size_t)NNODES*200*4);
  float* RELUP = (float*)alloc((size_t)NRELS*200*4);
  float* REL1  = (float*)alloc((size_t)NRELS*200*4);
  float* OR0   = (float*)alloc((size_t)NRELS*200*4);
  float* OR1   = (float*)alloc((size_t)NRELS*200*4);
  float* RR    = (float*)alloc((size_t)NRELS*200*4);
  float* PS    = (float*)alloc((size_t)NNODES*4);
  float* PD    = (float*)alloc((size_t)NNODES*4);
  float* PRS   = (float*)alloc((size_t)NRELS*4);
  float* MASK  = (float*)alloc((size_t)NNODES*4);
  // bf16 A arenas
  __hip_bfloat16* AENT0 = (__hip_bfloat16*)alloc((size_t)MP*128*2);
  __hip_bfloat16* AX1   = (__hip_bfloat16*)alloc((size_t)MP*224*2);
  __hip_bfloat16* AENT1 = (__hip_bfloat16*)alloc((size_t)MP*224*2);
  __hip_bfloat16* AREL0 = (__hip_bfloat16*)alloc((size_t)RP*128*2);
  __hip_bfloat16* AREL1 = (__hip_bfloat16*)alloc((size_t)RP*224*2);
  __hip_bfloat16* AOR   = (__hip_bfloat16*)alloc((size_t)RP*224*2);
  // bf16 weights
  __hip_bfloat16* WETb  = (__hip_bfloat16*)alloc((size_t)256*128*2);
  __hip_bfloat16* G0WTb = (__hip_bfloat16*)alloc((size_t)256*128*2);
  __hip_bfloat16* A0b   = (__hip_bfloat16*)alloc((size_t)6*128*128*2);   // h0 s/d/r, h1 s/d/r
  __hip_bfloat16* OA0b  = (__hip_bfloat16*)alloc((size_t)3*256*224*2);
  __hip_bfloat16* A1b   = (__hip_bfloat16*)alloc((size_t)3*256*224*2);
  __hip_bfloat16* G1WTb = (__hip_bfloat16*)alloc((size_t)256*224*2);
  __hip_bfloat16* OA1b  = (__hip_bfloat16*)alloc((size_t)3*256*224*2);
  // ints
  int* ROWOFS = (int*)alloc((size_t)(NNODES+1)*4);
  int* SPLIT  = (int*)alloc((size_t)NNODES*4);
  int* DEG1   = (int*)alloc((size_t)NNODES*4);
  int* CUR1   = (int*)alloc((size_t)NNODES*4);
  int* CURN   = (int*)alloc((size_t)NNODES*4);
  int* PART   = (int*)alloc((size_t)256*4);
  int* SDST   = (int*)alloc((size_t)NETOT*4);
  int* SET0   = (int*)alloc((size_t)NETOT*4);
  int* SET1   = (int*)alloc((size_t)NETOT*4);

  float* outEnt = (float*)d_out;
  float* outRel = outEnt + (size_t)NNODES*200;

  const int TB = 256;
  auto gb = [&](long long n){ return (int)((n + TB - 1)/TB); };

  // ---- preprocessing ----
  k_zero<<<gb(NNODES+1), TB, 0, stream>>>(ROWOFS, NNODES+1);
  k_zero<<<gb(NNODES), TB, 0, stream>>>(DEG1, NNODES);
  k_zero<<<gb(NNODES), TB, 0, stream>>>(CUR1, NNODES);
  k_zero<<<gb(NNODES), TB, 0, stream>>>(CURN, NNODES);
  k_zero<<<gb(NNODES), TB, 0, stream>>>((int*)MASK, NNODES);
  k_mask_set<<<gb(10000), TB, 0, stream>>>(batch, MASK, 10000);
  k_hist2<<<gb(NETOT), TB, 0, stream>>>(el, nh, ROWOFS, DEG1);
  int nsb = (NNODES + 255)/256;
  k_scan1<<<nsb, 256, 0, stream>>>(ROWOFS, NNODES, PART);
  k_scan2<<<1, 256, 0, stream>>>(PART, nsb);
  k_scan3<<<nsb, 256, 0, stream>>>(ROWOFS, NNODES, PART);
  k_split<<<gb(NNODES), TB, 0, stream>>>(ROWOFS, DEG1, SPLIT);
  k_scatter2<<<gb(NETOT), TB, 0, stream>>>(el, et, nh, ROWOFS, SPLIT, CUR1, CURN, SDST, SET0, SET1);

  // ---- normalize inputs -> bf16 arenas ----
  k_l2norm_bf<100,128><<<NNODES, 64, 0, stream>>>(entity, AENT0);
  k_l2norm_bf<100,128><<<NRELS, 64, 0, stream>>>(relation, AREL0);

  // ---- weights -> bf16 ----
  auto cvnt = [&](const float* s, int ld, int boff, int rows, int K, __hip_bfloat16* d, int Kp, int rp){
    k_w2bf_nt<<<gb((long long)rp*Kp), TB, 0, stream>>>(s, ld, boff, rows, K, d, Kp, rp);
  };
  auto cvt = [&](const float* s, int ld, int rows, int K, __hip_bfloat16* d, int Kp, int rp){
    k_w2bf_t<<<gb((long long)rp*Kp), TB, 0, stream>>>(s, ld, rows, K, d, Kp, rp);
  };
  cvt (W_ent, 200, 200, 100, WETb, 128, 256);
  cvt (g0_W,  200, 200, 100, G0WTb, 128, 256);
  cvnt(g0_a0, 300, 0,   100, 100, A0b + 0*128*128, 128, 128);
  cvnt(g0_a0, 300, 100, 100, 100, A0b + 1*128*128, 128, 128);
  cvnt(g0_a0, 300, 200, 100, 100, A0b + 2*128*128, 128, 128);
  cvnt(g0_a1, 300, 0,   100, 100, A0b + 3*128*128, 128, 128);
  cvnt(g0_a1, 300, 100, 100, 100, A0b + 4*128*128, 128, 128);
  cvnt(g0_a1, 300, 200, 100, 100, A0b + 5*128*128, 128, 128);
  cvnt(g0_oa, 600, 0,   200, 200, OA0b + 0*256*224, 224, 256);
  cvnt(g0_oa, 600, 200, 200, 200, OA0b + 1*256*224, 224, 256);
  cvnt(g0_oa, 600, 400, 200, 200, OA0b + 2*256*224, 224, 256);
  cvnt(g1_a0, 600, 0,   200, 200, A1b + 0*256*224, 224, 256);
  cvnt(g1_a0, 600, 200, 200, 200, A1b + 1*256*224, 224, 256);
  cvnt(g1_a0, 600, 400, 200, 200, A1b + 2*256*224, 224, 256);
  cvt (g1_W,  200, 200, 200, G1WTb, 224, 256);
  cvnt(g1_oa, 600, 0,   200, 200, OA1b + 0*256*224, 224, 256);
  cvnt(g1_oa, 600, 200, 200, 200, OA1b + 1*256*224, 224, 256);
  cvnt(g1_oa, 600, 400, 200, 200, OA1b + 2*256*224, 224, 256);

  // ---- pad zeros (rows >= M; AX1 pad cols) ----
  k_zero<<<gb(48*128/2), TB, 0, stream>>>((int*)(AENT0 + (size_t)NNODES*128), 48*128/2);
  k_zero<<<gb(48*224/2), TB, 0, stream>>>((int*)(AX1   + (size_t)NNODES*224), 48*224/2);
  k_zero<<<gb(48*224/2), TB, 0, stream>>>((int*)(AENT1 + (size_t)NNODES*224), 48*224/2);
  k_zero<<<gb(12*128/2), TB, 0, stream>>>((int*)(AREL0 + (size_t)NRELS*128), 12*128/2);
  k_zero<<<gb(12*224/2), TB, 0, stream>>>((int*)(AREL1 + (size_t)NRELS*224), 12*224/2);
  k_padcols<<<gb((long long)MP*24), TB, 0, stream>>>(AX1, MP, 200, 224);

  auto gemm = [&](const __hip_bfloat16* A, const __hip_bfloat16* B, float* C, int M, int Nn, int Kp){
    dim3 g((Nn + 63)/64, (M + 127)/128);
    k_gemm_mfma<<<g, 256, 0, stream>>>(A, B, C, M, Nn, Kp, Nn);
  };
  auto rowdot = [&](const float* X, int M, int D, const float* a2, float* o){
    k_rowdot<<<(M + 3)/4, 256, 0, stream>>>(X, M, D, a2, o);
  };

  // ---- ent_up / rel_up ----
  gemm(AENT0, WETb, ENTUP, NNODES, 200, 128);
  gemm(AREL0, WETb, RELUP, NRELS,  200, 128);

  // ---- layer0: two heads (din=100 -> 100) ----
  for (int h = 0; h < 2; h++){
    const __hip_bfloat16* as = A0b + (size_t)(3*h+0)*128*128;
    const __hip_bfloat16* ad = A0b + (size_t)(3*h+1)*128*128;
    const __hip_bfloat16* ar = A0b + (size_t)(3*h+2)*128*128;
    const float* s2 = h ? g0_s1 : g0_s0;
    gemm(AENT0, as, XS, NNODES, 100, 128);
    gemm(AENT0, ad, XD, NNODES, 100, 128);
    gemm(AREL0, ar, RR, NRELS,  100, 128);
    rowdot(XS, NNODES, 100, s2, PS);
    rowdot(XD, NNODES, 100, s2, PD);
    rowdot(RR, NRELS,  100, s2, PRS);
    k_agg2<100><<<NNODES/4, 256, 0, stream>>>(ROWOFS, SPLIT, SDST, SET0, SET1, PS, PD, PRS,
        XS, XD, RR, nullptr, 0, AX1, 224, h*100);
  }

  // ---- layer0: output attention (din=200 -> 200) ----
  gemm(AREL0, G0WTb, OR0, NRELS, 200, 128);
  cvnt(OR0, 200, 0, NRELS, 200, AOR, 224, RP);
  gemm(AX1, OA0b + 0*256*224, XS, NNODES, 200, 224);
  gemm(AX1, OA0b + 1*256*224, XD, NNODES, 200, 224);
  gemm(AOR, OA0b + 2*256*224, RR, NRELS,  200, 224);
  rowdot(XS, NNODES, 200, g0_os, PS);
  rowdot(XD, NNODES, 200, g0_os, PD);
  rowdot(RR, NRELS,  200, g0_os, PRS);
  k_agg2<200><<<NNODES/4, 256, 0, stream>>>(ROWOFS, SPLIT, SDST, SET0, SET1, PS, PD, PRS,
      XS, XD, RR, XS, 0, nullptr, 0, 0);   // fp32 out aliases XS (same-row read->write)
  k_combine_norm<200,224><<<NNODES, 64, 0, stream>>>(ENTUP, XS, MASK, ENT1, AENT1);
  k_combine_norm<200,224><<<NRELS, 64, 0, stream>>>(RELUP, OR0, nullptr, REL1, AREL1);

  // ---- layer1: one head (din=200 -> 200) ----
  gemm(AENT1, A1b + 0*256*224, XS, NNODES, 200, 224);
  gemm(AENT1, A1b + 1*256*224, XD, NNODES, 200, 224);
  gemm(AREL1, A1b + 2*256*224, RR, NRELS,  200, 224);
  rowdot(XS, NNODES, 200, g1_s0, PS);
  rowdot(XD, NNODES, 200, g1_s0, PD);
  rowdot(RR, NRELS,  200, g1_s0, PRS);
  k_agg2<200><<<NNODES/4, 256, 0, stream>>>(ROWOFS, SPLIT, SDST, SET0, SET1, PS, PD, PRS,
      XS, XD, RR, nullptr, 0, AX1, 224, 0);

  // ---- layer1: output attention ----
  gemm(AREL1, G1WTb, OR1, NRELS, 200, 224);
  cvnt(OR1, 200, 0, NRELS, 200, AOR, 224, RP);
  gemm(AX1, OA1b + 0*256*224, XS, NNODES, 200, 224);
  gemm(AX1, OA1b + 1*256*224, XD, NNODES, 200, 224);
  gemm(AOR, OA1b + 2*256*224, RR, NRELS,  200, 224);
  rowdot(XS, NNODES, 200, g1_os, PS);
  rowdot(XD, NNODES, 200, g1_os, PD);
  rowdot(RR, NRELS,  200, g1_os, PRS);
  k_agg2<200><<<NNODES/4, 256, 0, stream>>>(ROWOFS, SPLIT, SDST, SET0, SET1, PS, PD, PRS,
      XS, XD, RR, XS, 0, nullptr, 0, 0);

  // ---- final combines -> d_out ----
  k_combine_norm<200,224><<<NNODES, 64, 0, stream>>>(ENT1, XS, MASK, outEnt, nullptr);
  k_combine_norm<200,224><<<NRELS, 64, 0, stream>>>(REL1, OR1, nullptr, outRel, nullptr);
}

// Round 4
// 1146.130 us; speedup vs baseline: 3.1997x; 1.2142x over previous
//
#include <hip/hip_runtime.h>
#include <hip/hip_bf16.h>
#include <cstdint>
#include <cstddef>
#include <type_traits>

#define NNODES 50000
#define NRELS  500
#define NEDGE  500000
#define NETOT  600000
#define MP     50048
#define RPAD   512

typedef __attribute__((ext_vector_type(8))) short bf16x8;
typedef __attribute__((ext_vector_type(4))) float f32x4;

__device__ inline float bf2f(unsigned short s){
  union { unsigned u; float f; } v; v.u = ((unsigned)s) << 16; return v.f;
}
__device__ inline unsigned short f2bf(float f){
  __hip_bfloat16 h = __float2bfloat16(f);
  return __builtin_bit_cast(unsigned short, h);
}

// ---------------------------------------------------------------- utilities
__global__ void k_zero(int* __restrict__ p, int n){
  int i = blockIdx.x*blockDim.x + threadIdx.x;
  if (i < n) p[i] = 0;
}
__global__ void k_mask_set(const int* __restrict__ batch, float* __restrict__ mask, int nb){
  int i = blockIdx.x*blockDim.x + threadIdx.x;
  if (i < nb) mask[batch[3*i+2]] = 1.0f;
}
__global__ void k_padcols(__hip_bfloat16* __restrict__ dst, int Mpad, int K, int Kp){
  int padw = Kp - K;
  long long i = (long long)blockIdx.x*blockDim.x + threadIdx.x;
  if (i >= (long long)Mpad*padw) return;
  int r = (int)(i / padw), k = K + (int)(i - (long long)r*padw);
  dst[(size_t)r*Kp + k] = __float2bfloat16(0.f);
}

// ---------------------------------------------------------------- edge CSR (by src, unified records)
__global__ void k_hist(const int* __restrict__ el, const int* __restrict__ nh, int* __restrict__ deg){
  int e = blockIdx.x*blockDim.x + threadIdx.x;
  if (e >= NETOT) return;
  int s = (e < NEDGE) ? el[e] : nh[4*(e-NEDGE)+3];
  atomicAdd(&deg[s], 1);
}
__global__ void k_scan1(int* __restrict__ data, int n, int* __restrict__ part){
  __shared__ int sh[256];
  int t = threadIdx.x, i = blockIdx.x*256 + t;
  int v = (i < n) ? data[i] : 0;
  sh[t] = v; __syncthreads();
  for (int o = 1; o < 256; o <<= 1){
    int x = (t >= o) ? sh[t-o] : 0;
    __syncthreads(); sh[t] += x; __syncthreads();
  }
  if (i < n) data[i] = sh[t] - v;
  if (t == 255) part[blockIdx.x] = sh[255];
}
__global__ void k_scan2(int* __restrict__ part, int nb){
  __shared__ int sh[256];
  int t = threadIdx.x;
  int v = (t < nb) ? part[t] : 0;
  sh[t] = v; __syncthreads();
  for (int o = 1; o < 256; o <<= 1){
    int x = (t >= o) ? sh[t-o] : 0;
    __syncthreads(); sh[t] += x; __syncthreads();
  }
  if (t < nb) part[t] = sh[t] - v;
}
__global__ void k_scan3(int* __restrict__ data, int n, const int* __restrict__ part){
  int i = blockIdx.x*256 + threadIdx.x;
  if (i < n) data[i] += part[blockIdx.x];
  if (i == 0) data[n] = NETOT;
}
// unified scatter: t1 = NRELS (zero row) for 1-hop edges
__global__ void k_scatter(const int* __restrict__ el, const int* __restrict__ et,
                          const int* __restrict__ nh, const int* __restrict__ rowofs,
                          int* __restrict__ cur, int4* __restrict__ erec){
  int e = blockIdx.x*blockDim.x + threadIdx.x;
  if (e >= NETOT) return;
  int s, d, t0, t1;
  if (e < NEDGE){ s = el[e]; d = el[NEDGE+e]; t0 = et[e]; t1 = NRELS; }
  else { int i = e - NEDGE; s = nh[4*i+3]; d = nh[4*i+0]; t0 = nh[4*i+1]; t1 = nh[4*i+2]; }
  int p = rowofs[s] + atomicAdd(&cur[s], 1);
  erec[p] = make_int4(d, t0, t1, 0);
}

// ---------------------------------------------------------------- row kernels
template<int D, int KP>
__global__ __launch_bounds__(64) void k_l2norm_bf(const float* __restrict__ in,
                                                  __hip_bfloat16* __restrict__ bfout){
  constexpr int NK = KP/64;
  int n = blockIdx.x, lane = threadIdx.x;
  const float* row = in + (size_t)n*D;
  float v[NK]; float ss = 0.f;
  #pragma unroll
  for (int k = 0; k < NK; k++){ int c = lane + 64*k; v[k] = (c < D) ? row[c] : 0.f; ss += v[k]*v[k]; }
  #pragma unroll
  for (int o = 32; o; o >>= 1) ss += __shfl_xor(ss, o, 64);
  float sc = 1.0f / fmaxf(sqrtf(ss), 1e-12f);
  __hip_bfloat16* orow = bfout + (size_t)n*KP;
  #pragma unroll
  for (int k = 0; k < NK; k++){ int c = lane + 64*k; orow[c] = __float2bfloat16(v[k]*sc); }
}

// out = l2norm(base + m*h): fp32 out (c<D) and optional bf16 out (all KP cols, pad zero)
template<int D, int KP>
__global__ __launch_bounds__(64) void k_combine_norm(const float* __restrict__ base,
                                                     const float* __restrict__ h,
                                                     const float* __restrict__ mask,
                                                     float* __restrict__ outf,
                                                     __hip_bfloat16* __restrict__ outb){
  constexpr int NK = (KP+63)/64;
  int n = blockIdx.x, lane = threadIdx.x;
  float m = mask ? mask[n] : 1.0f;
  const float* b = base + (size_t)n*D;
  const float* hr = h + (size_t)n*D;
  float v[NK]; float ss = 0.f;
  #pragma unroll
  for (int k = 0; k < NK; k++){ int c = lane + 64*k; v[k] = (c < D) ? (b[c] + m*hr[c]) : 0.f; ss += v[k]*v[k]; }
  #pragma unroll
  for (int o = 32; o; o >>= 1) ss += __shfl_xor(ss, o, 64);
  float sc = 1.0f / fmaxf(sqrtf(ss), 1e-12f);
  float* orow = outf + (size_t)n*D;
  #pragma unroll
  for (int k = 0; k < NK; k++){ int c = lane + 64*k; if (c < D) orow[c] = v[k]*sc; }
  if (outb){
    __hip_bfloat16* brow = outb + (size_t)n*KP;
    #pragma unroll
    for (int k = 0; k < NK; k++){ int c = lane + 64*k; if (c < KP) brow[c] = __float2bfloat16(v[k]*sc); }
  }
}

// paired rowdot on interleaved bf16 C: o0[r] = X[r][c0..c0+D)·a2, o1[r] = X[r][c1..)·a2
__global__ void k_rowdot2(const __hip_bfloat16* __restrict__ X, int M, int ldx,
                          int c0, int c1, int D, const float* __restrict__ a2,
                          float* __restrict__ o0, float* __restrict__ o1){
  int wid = threadIdx.x >> 6, lane = threadIdx.x & 63;
  int row = blockIdx.x*4 + wid;
  if (row >= M) return;
  int nl = D >> 2;
  float p0 = 0.f, p1 = 0.f;
  if (lane < nl){
    float4 a = *(const float4*)(a2 + 4*lane);
    const __hip_bfloat16* base = X + (size_t)row*ldx;
    ushort4 x0 = *(const ushort4*)(base + c0 + 4*lane);
    p0 = bf2f(x0.x)*a.x + bf2f(x0.y)*a.y + bf2f(x0.z)*a.z + bf2f(x0.w)*a.w;
    if (o1){
      ushort4 x1 = *(const ushort4*)(base + c1 + 4*lane);
      p1 = bf2f(x1.x)*a.x + bf2f(x1.y)*a.y + bf2f(x1.z)*a.z + bf2f(x1.w)*a.w;
    }
  }
  #pragma unroll
  for (int o = 32; o; o >>= 1){ p0 += __shfl_xor(p0, o, 64); p1 += __shfl_xor(p1, o, 64); }
  if (lane == 0){ o0[row] = p0; if (o1) o1[row] = p1; }
}

// ---------------------------------------------------------------- mega weight->bf16 conversion
struct WEnt { int src, ld, boff, rows, K, tr, dstoff, Kp, rp; };
__device__ const WEnt g_went[18] = {
  {0,200,0,200,100,1,      0,128,256},   // WET   (W_ent^T)
  {3,200,0,200,100,1,  32768,128,256},   // G0WT
  {1,300,  0,100,100,0,  65536,128,128}, // BH0: h0 s
  {1,300,100,100,100,0,  81920,128,128}, //      h0 d
  {2,300,  0,100,100,0,  98304,128,128}, //      h1 s
  {2,300,100,100,100,0, 114688,128,128}, //      h1 d
  {1,300,200,100,100,0, 131072,128,128}, // BR0: h0 r
  {2,300,200,100,100,0, 147456,128,128}, //      h1 r
  {4,600,  0,200,200,0, 163840,224,256}, // BO0: s
  {4,600,200,200,200,0, 221184,224,256}, //      d
  {4,600,400,200,200,0, 278528,224,256}, // BO0r
  {5,600,  0,200,200,0, 335872,224,256}, // BA1: s
  {5,600,200,200,200,0, 393216,224,256}, //      d
  {5,600,400,200,200,0, 450560,224,256}, // BA1r
  {6,200,0,200,200,1,   507904,224,256}, // G1WT
  {7,600,  0,200,200,0, 565248,224,256}, // BO1: s
  {7,600,200,200,200,0, 622592,224,256}, //      d
  {7,600,400,200,200,0, 679936,224,256}, // BO1r
};
struct Ptr8 { const float* p[8]; };
__global__ void k_wconv(Ptr8 srcs, __hip_bfloat16* __restrict__ dst){
  WEnt e = g_went[blockIdx.y];
  int i = blockIdx.x*256 + threadIdx.x;
  if (i >= e.rp*e.Kp) return;
  int r = i / e.Kp, k = i - r*e.Kp;
  float v = 0.f;
  if (r < e.rows && k < e.K)
    v = e.tr ? srcs.p[e.src][(size_t)k*e.ld + r] : srcs.p[e.src][(size_t)r*e.ld + e.boff + k];
  dst[e.dstoff + i] = __float2bfloat16(v);
}

// dst[r][k] = src[r*ldsrc + k], zero-pad (used for OR -> bf16 A)
__global__ void k_w2bf_nt(const float* __restrict__ src, int ldsrc,
                          int rows, int K, __hip_bfloat16* __restrict__ dst, int Kp, int rowsPad){
  int i = blockIdx.x*blockDim.x + threadIdx.x;
  if (i >= rowsPad*Kp) return;
  int r = i / Kp, k = i - r*Kp;
  float v = (r < rows && k < K) ? src[(size_t)r*ldsrc + k] : 0.f;
  dst[i] = __float2bfloat16(v);
}

// ---------------------------------------------------------------- bf16 MFMA GEMM (NT)
// C[m][c] = sum_k A[m][k]*B[c][k]; A [Mpad][Kp] bf16, B [rp][Kp] bf16 zero-padded.
// Tile 128x64, 4 waves (2x2), 16x16x32 MFMA, global_load_lds, chunk-XOR swizzle.
template<typename CT>
__global__ __launch_bounds__(256) void k_gemm_mfma(
    const __hip_bfloat16* __restrict__ A, const __hip_bfloat16* __restrict__ B,
    CT* __restrict__ C, int M, int Nn, int Kp, int ldc)
{
  __shared__ __hip_bfloat16 As[128*32];
  __shared__ __hip_bfloat16 Bs[64*32];
  const int tid = threadIdx.x;
  const int wave = tid >> 6, lane = tid & 63;
  const int lg = lane >> 4, li = lane & 15;
  const int m0 = blockIdx.y * 128, n0 = blockIdx.x * 64;
  const int wr = wave >> 1, wc = wave & 1;
  f32x4 acc[4][2] = {};

  const int ar0 = tid >> 2;
  const int ar1 = (tid + 256) >> 2;
  const int ap  = tid & 3;
  const char* Ab = (const char*)A;
  const char* Bb = (const char*)B;
  char* asB = (char*)As;
  char* bsB = (char*)Bs;

  for (int kk = 0; kk < Kp; kk += 32){
    {
      int g0 = ap ^ ((ar0 >> 1) & 3);
      const char* s0 = Ab + ((size_t)(m0 + ar0)*Kp + kk)*2 + g0*16;
      __builtin_amdgcn_global_load_lds((const __attribute__((address_space(1))) void*)s0,
          (__attribute__((address_space(3))) void*)(asB + wave*1024), 16, 0, 0);
      int g1 = ap ^ ((ar1 >> 1) & 3);
      const char* s1 = Ab + ((size_t)(m0 + ar1)*Kp + kk)*2 + g1*16;
      __builtin_amdgcn_global_load_lds((const __attribute__((address_space(1))) void*)s1,
          (__attribute__((address_space(3))) void*)(asB + 4096 + wave*1024), 16, 0, 0);
      int gb = ap ^ ((ar0 >> 1) & 3);
      const char* sb = Bb + ((size_t)(n0 + ar0)*Kp + kk)*2 + gb*16;
      __builtin_amdgcn_global_load_lds((const __attribute__((address_space(1))) void*)sb,
          (__attribute__((address_space(3))) void*)(bsB + wave*1024), 16, 0, 0);
    }
    __syncthreads();
    bf16x8 av[4], bv[2];
    #pragma unroll
    for (int mf = 0; mf < 4; mf++){
      int row = wr*64 + mf*16 + li;
      int p = lg ^ ((row >> 1) & 3);
      av[mf] = *(const bf16x8*)(asB + row*64 + p*16);
    }
    #pragma unroll
    for (int nf = 0; nf < 2; nf++){
      int row = wc*32 + nf*16 + li;
      int p = lg ^ ((row >> 1) & 3);
      bv[nf] = *(const bf16x8*)(bsB + row*64 + p*16);
    }
    #pragma unroll
    for (int mf = 0; mf < 4; mf++)
      #pragma unroll
      for (int nf = 0; nf < 2; nf++)
        acc[mf][nf] = __builtin_amdgcn_mfma_f32_16x16x32_bf16(av[mf], bv[nf], acc[mf][nf], 0, 0, 0);
    __syncthreads();
  }
  #pragma unroll
  for (int mf = 0; mf < 4; mf++){
    #pragma unroll
    for (int nf = 0; nf < 2; nf++){
      int gc = n0 + wc*32 + nf*16 + li;
      if (gc >= Nn) continue;
      int gr0 = m0 + wr*64 + mf*16 + lg*4;
      #pragma unroll
      for (int r = 0; r < 4; r++){
        int gr = gr0 + r;
        if (gr < M){
          if constexpr (std::is_same<CT,float>::value) C[(size_t)gr*ldc + gc] = acc[mf][nf][r];
          else C[(size_t)gr*ldc + gc] = __float2bfloat16(acc[mf][nf][r]);
        }
      }
    }
  }
}

// ---------------------------------------------------------------- attention aggregation v3
// bf16 gathers, unified edge records (t1=NRELS -> zero row).
// DD=200: full wave per edge (50 lanes x 8B), 2-edge unroll.
// DD=100: two edges concurrently on half-waves (25 lanes x 8B each), cross-half reduce.
template<int DD, bool OUTF>
__global__ __launch_bounds__(256) void k_agg3(
    const int* __restrict__ rowofs, const int4* __restrict__ erec,
    const float* __restrict__ ps, const float* __restrict__ pd, const float* __restrict__ prs,
    const __hip_bfloat16* __restrict__ XSD, int ldx, int cxs, int cxd,
    const __hip_bfloat16* __restrict__ RRb, int ldr, int crr,
    float* __restrict__ outf, __hip_bfloat16* __restrict__ outb, int ldb, int coffb)
{
  int wave = threadIdx.x >> 6, lane = threadIdx.x & 63;
  int n = blockIdx.x*4 + wave;
  int beg = rowofs[n], end = rowofs[n+1];
  float psn = ps[n];
  float S = 0.f;
  f32x4 acc = {0.f,0.f,0.f,0.f};

  if constexpr (DD == 100){
    int sub = lane >> 5, li = lane & 31;
    bool act = li < 25;
    for (int i = beg + sub; i < end; i += 2){
      int4 er = erec[i];
      float lg = psn + pd[er.x] + prs[er.y] + prs[er.z];
      float w = __expf(-((lg > 0.f) ? lg : 0.2f*lg));
      S += w;
      if (act){
        ushort4 xd4 = *(const ushort4*)(XSD + (size_t)er.x*ldx + cxd + 4*li);
        ushort4 r0  = *(const ushort4*)(RRb + (size_t)er.y*ldr + crr + 4*li);
        ushort4 r1  = *(const ushort4*)(RRb + (size_t)er.z*ldr + crr + 4*li);
        acc.x += w*(bf2f(xd4.x)+bf2f(r0.x)+bf2f(r1.x));
        acc.y += w*(bf2f(xd4.y)+bf2f(r0.y)+bf2f(r1.y));
        acc.z += w*(bf2f(xd4.z)+bf2f(r0.z)+bf2f(r1.z));
        acc.w += w*(bf2f(xd4.w)+bf2f(r0.w)+bf2f(r1.w));
      }
    }
    S += __shfl_xor(S, 32, 64);
    acc.x += __shfl_xor(acc.x, 32, 64);
    acc.y += __shfl_xor(acc.y, 32, 64);
    acc.z += __shfl_xor(acc.z, 32, 64);
    acc.w += __shfl_xor(acc.w, 32, 64);
    if (sub == 0 && act){
      float inv = (S > 0.f) ? 1.0f/S : 0.f;
      ushort4 xs4 = *(const ushort4*)(XSD + (size_t)n*ldx + cxs + 4*li);
      float h0 = (S > 0.f) ? bf2f(xs4.x) + acc.x*inv : 0.f;
      float h1 = (S > 0.f) ? bf2f(xs4.y) + acc.y*inv : 0.f;
      float h2 = (S > 0.f) ? bf2f(xs4.z) + acc.z*inv : 0.f;
      float h3 = (S > 0.f) ? bf2f(xs4.w) + acc.w*inv : 0.f;
      h0 = (h0 > 0.f) ? h0 : expm1f(h0);
      h1 = (h1 > 0.f) ? h1 : expm1f(h1);
      h2 = (h2 > 0.f) ? h2 : expm1f(h2);
      h3 = (h3 > 0.f) ? h3 : expm1f(h3);
      ushort4 o; o.x = f2bf(h0); o.y = f2bf(h1); o.z = f2bf(h2); o.w = f2bf(h3);
      *(ushort4*)(outb + (size_t)n*ldb + coffb + 4*li) = o;
    }
  } else {
    bool act = lane < 50;
    int i = beg;
    for (; i + 1 < end; i += 2){
      int4 e0 = erec[i], e1 = erec[i+1];
      ushort4 xa={0,0,0,0}, ra0={0,0,0,0}, ra1={0,0,0,0}, xb={0,0,0,0}, rb0={0,0,0,0}, rb1={0,0,0,0};
      if (act){
        xa  = *(const ushort4*)(XSD + (size_t)e0.x*ldx + cxd + 4*lane);
        ra0 = *(const ushort4*)(RRb + (size_t)e0.y*ldr + crr + 4*lane);
        ra1 = *(const ushort4*)(RRb + (size_t)e0.z*ldr + crr + 4*lane);
        xb  = *(const ushort4*)(XSD + (size_t)e1.x*ldx + cxd + 4*lane);
        rb0 = *(const ushort4*)(RRb + (size_t)e1.y*ldr + crr + 4*lane);
        rb1 = *(const ushort4*)(RRb + (size_t)e1.z*ldr + crr + 4*lane);
      }
      float lg0 = psn + pd[e0.x] + prs[e0.y] + prs[e0.z];
      float lg1 = psn + pd[e1.x] + prs[e1.y] + prs[e1.z];
      float w0 = __expf(-((lg0 > 0.f) ? lg0 : 0.2f*lg0));
      float w1 = __expf(-((lg1 > 0.f) ? lg1 : 0.2f*lg1));
      S += w0 + w1;
      if (act){
        acc.x += w0*(bf2f(xa.x)+bf2f(ra0.x)+bf2f(ra1.x)) + w1*(bf2f(xb.x)+bf2f(rb0.x)+bf2f(rb1.x));
        acc.y += w0*(bf2f(xa.y)+bf2f(ra0.y)+bf2f(ra1.y)) + w1*(bf2f(xb.y)+bf2f(rb0.y)+bf2f(rb1.y));
        acc.z += w0*(bf2f(xa.z)+bf2f(ra0.z)+bf2f(ra1.z)) + w1*(bf2f(xb.z)+bf2f(rb0.z)+bf2f(rb1.z));
        acc.w += w0*(bf2f(xa.w)+bf2f(ra0.w)+bf2f(ra1.w)) + w1*(bf2f(xb.w)+bf2f(rb0.w)+bf2f(rb1.w));
      }
    }
    if (i < end){
      int4 e0 = erec[i];
      float lg0 = psn + pd[e0.x] + prs[e0.y] + prs[e0.z];
      float w0 = __expf(-((lg0 > 0.f) ? lg0 : 0.2f*lg0));
      S += w0;
      if (act){
        ushort4 xa  = *(const ushort4*)(XSD + (size_t)e0.x*ldx + cxd + 4*lane);
        ushort4 ra0 = *(const ushort4*)(RRb + (size_t)e0.y*ldr + crr + 4*lane);
        ushort4 ra1 = *(const ushort4*)(RRb + (size_t)e0.z*ldr + crr + 4*lane);
        acc.x += w0*(bf2f(xa.x)+bf2f(ra0.x)+bf2f(ra1.x));
        acc.y += w0*(bf2f(xa.y)+bf2f(ra0.y)+bf2f(ra1.y));
        acc.z += w0*(bf2f(xa.z)+bf2f(ra0.z)+bf2f(ra1.z));
        acc.w += w0*(bf2f(xa.w)+bf2f(ra0.w)+bf2f(ra1.w));
      }
    }
    if (act){
      float inv = (S > 0.f) ? 1.0f/S : 0.f;
      ushort4 xs4 = *(const ushort4*)(XSD + (size_t)n*ldx + cxs + 4*lane);
      float h0 = (S > 0.f) ? bf2f(xs4.x) + acc.x*inv : 0.f;
      float h1 = (S > 0.f) ? bf2f(xs4.y) + acc.y*inv : 0.f;
      float h2 = (S > 0.f) ? bf2f(xs4.z) + acc.z*inv : 0.f;
      float h3 = (S > 0.f) ? bf2f(xs4.w) + acc.w*inv : 0.f;
      h0 = (h0 > 0.f) ? h0 : expm1f(h0);
      h1 = (h1 > 0.f) ? h1 : expm1f(h1);
      h2 = (h2 > 0.f) ? h2 : expm1f(h2);
      h3 = (h3 > 0.f) ? h3 : expm1f(h3);
      if constexpr (OUTF){
        float4 o = make_float4(h0, h1, h2, h3);
        *(float4*)(outf + (size_t)n*200 + 4*lane) = o;
      } else {
        ushort4 o; o.x = f2bf(h0); o.y = f2bf(h1); o.z = f2bf(h2); o.w = f2bf(h3);
        *(ushort4*)(outb + (size_t)n*ldb + coffb + 4*lane) = o;
      }
    }
  }
}

// ---------------------------------------------------------------- driver
extern "C" void kernel_launch(void* const* d_in, const int* in_sizes, int n_in,
                              void* d_out, int out_size, void* d_ws, size_t ws_size,
                              hipStream_t stream) {
  const float* entity   = (const float*)d_in[0];
  const float* relation = (const float*)d_in[1];
  const float* W_ent    = (const float*)d_in[2];
  const float* g0_a0    = (const float*)d_in[3];
  const float* g0_s0    = (const float*)d_in[4];
  const float* g0_a1    = (const float*)d_in[5];
  const float* g0_s1    = (const float*)d_in[6];
  const float* g0_W     = (const float*)d_in[7];
  const float* g0_oa    = (const float*)d_in[8];
  const float* g0_os    = (const float*)d_in[9];
  const float* g1_a0    = (const float*)d_in[10];
  const float* g1_s0    = (const float*)d_in[11];
  const float* g1_W     = (const float*)d_in[12];
  const float* g1_oa    = (const float*)d_in[13];
  const float* g1_os    = (const float*)d_in[14];
  const int*   el       = (const int*)d_in[15];
  const int*   et       = (const int*)d_in[16];
  const int*   nh       = (const int*)d_in[17];
  const int*   batch    = (const int*)d_in[18];
  (void)in_sizes; (void)n_in; (void)out_size; (void)ws_size;

  char* w = (char*)d_ws;
  auto alloc = [&](size_t bytes)->char*{ char* p = w; w += (bytes + 255) & ~(size_t)255; return p; };
  // fp32
  float* ENTUP = (float*)alloc((size_t)MP*200*4);
  float* ENT1  = (float*)alloc((size_t)NNODES*200*4);
  float* XSF   = (float*)alloc((size_t)MP*200*4);
  float* RELUP = (float*)alloc((size_t)RPAD*200*4);
  float* REL1  = (float*)alloc((size_t)NRELS*200*4);
  float* OR0   = (float*)alloc((size_t)RPAD*200*4);
  float* OR1   = (float*)alloc((size_t)RPAD*200*4);
  float* PS    = (float*)alloc((size_t)NNODES*4);
  float* PD    = (float*)alloc((size_t)NNODES*4);
  float* PRS   = (float*)alloc((size_t)(NRELS+4)*4);
  // bf16 A arenas
  __hip_bfloat16* AENT0 = (__hip_bfloat16*)alloc((size_t)MP*128*2);
  __hip_bfloat16* AX1   = (__hip_bfloat16*)alloc((size_t)MP*224*2);
  __hip_bfloat16* AENT1 = (__hip_bfloat16*)alloc((size_t)MP*224*2);
  __hip_bfloat16* AREL0 = (__hip_bfloat16*)alloc((size_t)RPAD*128*2);   // contiguous with AREL1
  __hip_bfloat16* AREL1 = (__hip_bfloat16*)alloc((size_t)RPAD*224*2);
  __hip_bfloat16* AOR   = (__hip_bfloat16*)alloc((size_t)RPAD*224*2);
  // bf16 C buffers
  __hip_bfloat16* XSD   = (__hip_bfloat16*)alloc((size_t)MP*512*2);
  __hip_bfloat16* RRb   = (__hip_bfloat16*)alloc((size_t)RPAD*256*2);
  // weight arena
  __hip_bfloat16* WA    = (__hip_bfloat16*)alloc((size_t)737280*2);
  // ints: ROWOFS(50001) | CUR(50000) | MASK(50000)
  int* IALL = (int*)alloc((size_t)150001*4);
  int* ROWOFS = IALL;
  int* CUR    = IALL + 50001;
  float* MASK = (float*)(IALL + 100001);
  int4* EREC  = (int4*)alloc((size_t)NETOT*16);

  const __hip_bfloat16* WET   = WA;
  const __hip_bfloat16* G0WT  = WA + 32768;
  const __hip_bfloat16* BH0   = WA + 65536;
  const __hip_bfloat16* BR0   = WA + 131072;
  const __hip_bfloat16* BO0   = WA + 163840;
  const __hip_bfloat16* BO0r  = WA + 278528;
  const __hip_bfloat16* BA1   = WA + 335872;
  const __hip_bfloat16* BA1r  = WA + 450560;
  const __hip_bfloat16* G1WT  = WA + 507904;
  const __hip_bfloat16* BO1   = WA + 565248;
  const __hip_bfloat16* BO1r  = WA + 679936;

  float* outEnt = (float*)d_out;
  float* outRel = outEnt + (size_t)NNODES*200;

  const int TB = 256;
  auto gb = [&](long long n){ return (int)((n + TB - 1)/TB); };

  // ---- preprocessing ----
  k_zero<<<gb(150001), TB, 0, stream>>>(IALL, 150001);
  k_zero<<<gb((RPAD*128 + RPAD*224)/2), TB, 0, stream>>>((int*)AREL0, (RPAD*128 + RPAD*224)/2);
  k_mask_set<<<gb(10000), TB, 0, stream>>>(batch, MASK, 10000);
  k_hist<<<gb(NETOT), TB, 0, stream>>>(el, nh, ROWOFS);
  int nsb = (NNODES + 255)/256;
  { static_assert(true, ""); }
  int* PART = (int*)alloc((size_t)256*4);
  k_scan1<<<nsb, 256, 0, stream>>>(ROWOFS, NNODES, PART);
  k_scan2<<<1, 256, 0, stream>>>(PART, nsb);
  k_scan3<<<nsb, 256, 0, stream>>>(ROWOFS, NNODES, PART);
  k_scatter<<<gb(NETOT), TB, 0, stream>>>(el, et, nh, ROWOFS, CUR, EREC);
  k_padcols<<<gb((long long)MP*24), TB, 0, stream>>>(AX1, MP, 200, 224);

  // ---- inputs -> bf16 arenas; weights -> bf16 arena ----
  k_l2norm_bf<100,128><<<NNODES, 64, 0, stream>>>(entity, AENT0);
  k_l2norm_bf<100,128><<<NRELS, 64, 0, stream>>>(relation, AREL0);
  {
    Ptr8 srcs;
    srcs.p[0] = W_ent; srcs.p[1] = g0_a0; srcs.p[2] = g0_a1; srcs.p[3] = g0_W;
    srcs.p[4] = g0_oa; srcs.p[5] = g1_a0; srcs.p[6] = g1_W;  srcs.p[7] = g1_oa;
    dim3 g(448, 18);
    k_wconv<<<g, 256, 0, stream>>>(srcs, WA);
  }

  auto gemm_f = [&](const __hip_bfloat16* A, const __hip_bfloat16* B, float* C, int M, int Nn, int Kp, int ldc){
    dim3 g((Nn + 63)/64, (M + 127)/128);
    k_gemm_mfma<float><<<g, 256, 0, stream>>>(A, B, C, M, Nn, Kp, ldc);
  };
  auto gemm_b = [&](const __hip_bfloat16* A, const __hip_bfloat16* B, __hip_bfloat16* C, int M, int Nn, int Kp, int ldc){
    dim3 g((Nn + 63)/64, (M + 127)/128);
    k_gemm_mfma<__hip_bfloat16><<<g, 256, 0, stream>>>(A, B, C, M, Nn, Kp, ldc);
  };
  auto rd2_node = [&](int c0, int c1, int D, const float* a2){
    k_rowdot2<<<(NNODES + 3)/4, 256, 0, stream>>>(XSD, NNODES, 512, c0, c1, D, a2, PS, PD);
  };
  auto rd2_rel = [&](int c0, int D, const float* a2){
    k_rowdot2<<<(NRELS + 4)/4, 256, 0, stream>>>(RRb, NRELS+1, 256, c0, -1, D, a2, PRS, nullptr);
  };

  // ---- ent_up / rel_up ----
  gemm_f(AENT0, WET, ENTUP, MP, 200, 128, 200);
  gemm_f(AREL0, WET, RELUP, RPAD, 200, 128, 200);

  // ---- layer0 heads: one mega GEMM each side ----
  gemm_b(AENT0, BH0, XSD, MP, 512, 128, 512);
  gemm_b(AREL0, BR0, RRb, RPAD, 256, 128, 256);
  for (int h = 0; h < 2; h++){
    const float* s2 = h ? g0_s1 : g0_s0;
    rd2_node(256*h, 256*h + 128, 100, s2);
    rd2_rel(128*h, 100, s2);
    k_agg3<100,false><<<NNODES/4, 256, 0, stream>>>(ROWOFS, EREC, PS, PD, PRS,
        XSD, 512, 256*h, 256*h + 128, RRb, 256, 128*h, nullptr, AX1, 224, 100*h);
  }

  // ---- layer0 out-attention ----
  gemm_f(AREL0, G0WT, OR0, RPAD, 200, 128, 200);
  k_w2bf_nt<<<gb((long long)RPAD*224), TB, 0, stream>>>(OR0, 200, NRELS, 200, AOR, 224, RPAD);
  gemm_b(AX1, BO0, XSD, MP, 512, 224, 512);
  gemm_b(AOR, BO0r, RRb, RPAD, 256, 224, 256);
  rd2_node(0, 256, 200, g0_os);
  rd2_rel(0, 200, g0_os);
  k_agg3<200,true><<<NNODES/4, 256, 0, stream>>>(ROWOFS, EREC, PS, PD, PRS,
      XSD, 512, 0, 256, RRb, 256, 0, XSF, nullptr, 0, 0);
  k_combine_norm<200,224><<<NNODES, 64, 0, stream>>>(ENTUP, XSF, MASK, ENT1, AENT1);
  k_combine_norm<200,224><<<NRELS, 64, 0, stream>>>(RELUP, OR0, nullptr, REL1, AREL1);

  // ---- layer1 head ----
  gemm_b(AENT1, BA1, XSD, MP, 512, 224, 512);
  gemm_b(AREL1, BA1r, RRb, RPAD, 256, 224, 256);
  rd2_node(0, 256, 200, g1_s0);
  rd2_rel(0, 200, g1_s0);
  k_agg3<200,false><<<NNODES/4, 256, 0, stream>>>(ROWOFS, EREC, PS, PD, PRS,
      XSD, 512, 0, 256, RRb, 256, 0, nullptr, AX1, 224, 0);

  // ---- layer1 out-attention ----
  gemm_f(AREL1, G1WT, OR1, RPAD, 200, 224, 200);
  k_w2bf_nt<<<gb((long long)RPAD*224), TB, 0, stream>>>(OR1, 200, NRELS, 200, AOR, 224, RPAD);
  gemm_b(AX1, BO1, XSD, MP, 512, 224, 512);
  gemm_b(AOR, BO1r, RRb, RPAD, 256, 224, 256);
  rd2_node(0, 256, 200, g1_os);
  rd2_rel(0, 200, g1_os);
  k_agg3<200,true><<<NNODES/4, 256, 0, stream>>>(ROWOFS, EREC, PS, PD, PRS,
      XSD, 512, 0, 256, RRb, 256, 0, XSF, nullptr, 0, 0);

  // ---- final combines -> d_out ----
  k_combine_norm<200,224><<<NNODES, 64, 0, stream>>>(ENT1, XSF, MASK, outEnt, nullptr);
  k_combine_norm<200,224><<<NRELS, 64, 0, stream>>>(REL1, OR1, nullptr, outRel, nullptr);
}

// Round 5
// 822.162 us; speedup vs baseline: 4.4605x; 1.3940x over previous
//
#include <hip/hip_runtime.h>
#include <hip/hip_bf16.h>
#include <cstdint>
#include <cstddef>
#include <type_traits>

#define NNODES 50000
#define NRELS  500
#define NEDGE  500000
#define NETOT  600000
#define MP     50048
#define RPAD   512
#define HOTN   512

typedef __attribute__((ext_vector_type(8))) short bf16x8;
typedef __attribute__((ext_vector_type(4))) float f32x4;

__device__ inline float bf2f(unsigned short s){
  union { unsigned u; float f; } v; v.u = ((unsigned)s) << 16; return v.f;
}
__device__ inline unsigned short f2bf(float f){
  __hip_bfloat16 h = __float2bfloat16(f);
  return __builtin_bit_cast(unsigned short, h);
}

// ---------------------------------------------------------------- utilities
__global__ void k_zero(int* __restrict__ p, int n){
  int i = blockIdx.x*blockDim.x + threadIdx.x;
  if (i < n) p[i] = 0;
}
__global__ void k_mask_set(const int* __restrict__ batch, float* __restrict__ mask, int nb){
  int i = blockIdx.x*blockDim.x + threadIdx.x;
  if (i < nb) mask[batch[3*i+2]] = 1.0f;
}
__global__ void k_padcols(__hip_bfloat16* __restrict__ dst, int Mpad, int K, int Kp){
  int padw = Kp - K;
  long long i = (long long)blockIdx.x*blockDim.x + threadIdx.x;
  if (i >= (long long)Mpad*padw) return;
  int r = (int)(i / padw), k = K + (int)(i - (long long)r*padw);
  dst[(size_t)r*Kp + k] = __float2bfloat16(0.f);
}

// ---------------------------------------------------------------- edge CSR (by src, unified records)
__global__ void k_hist(const int* __restrict__ el, const int* __restrict__ nh, int* __restrict__ deg){
  int e = blockIdx.x*blockDim.x + threadIdx.x;
  if (e >= NETOT) return;
  int s = (e < NEDGE) ? el[e] : nh[4*(e-NEDGE)+3];
  atomicAdd(&deg[s], 1);
}
__global__ void k_scan1(int* __restrict__ data, int n, int* __restrict__ part){
  __shared__ int sh[256];
  int t = threadIdx.x, i = blockIdx.x*256 + t;
  int v = (i < n) ? data[i] : 0;
  sh[t] = v; __syncthreads();
  for (int o = 1; o < 256; o <<= 1){
    int x = (t >= o) ? sh[t-o] : 0;
    __syncthreads(); sh[t] += x; __syncthreads();
  }
  if (i < n) data[i] = sh[t] - v;
  if (t == 255) part[blockIdx.x] = sh[255];
}
__global__ void k_scan2(int* __restrict__ part, int nb){
  __shared__ int sh[256];
  int t = threadIdx.x;
  int v = (t < nb) ? part[t] : 0;
  sh[t] = v; __syncthreads();
  for (int o = 1; o < 256; o <<= 1){
    int x = (t >= o) ? sh[t-o] : 0;
    __syncthreads(); sh[t] += x; __syncthreads();
  }
  if (t < nb) part[t] = sh[t] - v;
}
__global__ void k_scan3(int* __restrict__ data, int n, const int* __restrict__ part){
  int i = blockIdx.x*256 + threadIdx.x;
  if (i < n) data[i] += part[blockIdx.x];
  if (i == 0) data[n] = NETOT;
}
// unified scatter: t1 = NRELS (zero row) for 1-hop edges
__global__ void k_scatter(const int* __restrict__ el, const int* __restrict__ et,
                          const int* __restrict__ nh, const int* __restrict__ rowofs,
                          int* __restrict__ cur, int4* __restrict__ erec){
  int e = blockIdx.x*blockDim.x + threadIdx.x;
  if (e >= NETOT) return;
  int s, d, t0, t1;
  if (e < NEDGE){ s = el[e]; d = el[NEDGE+e]; t0 = et[e]; t1 = NRELS; }
  else { int i = e - NEDGE; s = nh[4*i+3]; d = nh[4*i+0]; t0 = nh[4*i+1]; t1 = nh[4*i+2]; }
  int p = rowofs[s] + atomicAdd(&cur[s], 1);
  erec[p] = make_int4(d, t0, t1, 0);
}

// ---------------------------------------------------------------- row kernels
template<int D, int KP>
__global__ __launch_bounds__(64) void k_l2norm_bf(const float* __restrict__ in,
                                                  __hip_bfloat16* __restrict__ bfout){
  constexpr int NK = KP/64;
  int n = blockIdx.x, lane = threadIdx.x;
  const float* row = in + (size_t)n*D;
  float v[NK]; float ss = 0.f;
  #pragma unroll
  for (int k = 0; k < NK; k++){ int c = lane + 64*k; v[k] = (c < D) ? row[c] : 0.f; ss += v[k]*v[k]; }
  #pragma unroll
  for (int o = 32; o; o >>= 1) ss += __shfl_xor(ss, o, 64);
  float sc = 1.0f / fmaxf(sqrtf(ss), 1e-12f);
  __hip_bfloat16* orow = bfout + (size_t)n*KP;
  #pragma unroll
  for (int k = 0; k < NK; k++){ int c = lane + 64*k; orow[c] = __float2bfloat16(v[k]*sc); }
}

// out = l2norm(base + m*h): fp32 out (c<D) and optional bf16 out (all KP cols, pad zero)
template<int D, int KP>
__global__ __launch_bounds__(64) void k_combine_norm(const float* __restrict__ base,
                                                     const float* __restrict__ h,
                                                     const float* __restrict__ mask,
                                                     float* __restrict__ outf,
                                                     __hip_bfloat16* __restrict__ outb){
  constexpr int NK = (KP+63)/64;
  int n = blockIdx.x, lane = threadIdx.x;
  float m = mask ? mask[n] : 1.0f;
  const float* b = base + (size_t)n*D;
  const float* hr = h + (size_t)n*D;
  float v[NK]; float ss = 0.f;
  #pragma unroll
  for (int k = 0; k < NK; k++){ int c = lane + 64*k; v[k] = (c < D) ? (b[c] + m*hr[c]) : 0.f; ss += v[k]*v[k]; }
  #pragma unroll
  for (int o = 32; o; o >>= 1) ss += __shfl_xor(ss, o, 64);
  float sc = 1.0f / fmaxf(sqrtf(ss), 1e-12f);
  float* orow = outf + (size_t)n*D;
  #pragma unroll
  for (int k = 0; k < NK; k++){ int c = lane + 64*k; if (c < D) orow[c] = v[k]*sc; }
  if (outb){
    __hip_bfloat16* brow = outb + (size_t)n*KP;
    #pragma unroll
    for (int k = 0; k < NK; k++){ int c = lane + 64*k; if (c < KP) brow[c] = __float2bfloat16(v[k]*sc); }
  }
}

// paired rowdot on interleaved bf16 C
__global__ void k_rowdot2(const __hip_bfloat16* __restrict__ X, int M, int ldx,
                          int c0, int c1, int D, const float* __restrict__ a2,
                          float* __restrict__ o0, float* __restrict__ o1){
  int wid = threadIdx.x >> 6, lane = threadIdx.x & 63;
  int row = blockIdx.x*4 + wid;
  if (row >= M) return;
  int nl = D >> 2;
  float p0 = 0.f, p1 = 0.f;
  if (lane < nl){
    float4 a = *(const float4*)(a2 + 4*lane);
    const __hip_bfloat16* base = X + (size_t)row*ldx;
    ushort4 x0 = *(const ushort4*)(base + c0 + 4*lane);
    p0 = bf2f(x0.x)*a.x + bf2f(x0.y)*a.y + bf2f(x0.z)*a.z + bf2f(x0.w)*a.w;
    if (o1){
      ushort4 x1 = *(const ushort4*)(base + c1 + 4*lane);
      p1 = bf2f(x1.x)*a.x + bf2f(x1.y)*a.y + bf2f(x1.z)*a.z + bf2f(x1.w)*a.w;
    }
  }
  #pragma unroll
  for (int o = 32; o; o >>= 1){ p0 += __shfl_xor(p0, o, 64); p1 += __shfl_xor(p1, o, 64); }
  if (lane == 0){ o0[row] = p0; if (o1) o1[row] = p1; }
}

// ---------------------------------------------------------------- mega weight->bf16 conversion
struct WEnt { int src, ld, boff, rows, K, tr, dstoff, Kp, rp; };
__device__ const WEnt g_went[18] = {
  {0,200,0,200,100,1,      0,128,256},
  {3,200,0,200,100,1,  32768,128,256},
  {1,300,  0,100,100,0,  65536,128,128},
  {1,300,100,100,100,0,  81920,128,128},
  {2,300,  0,100,100,0,  98304,128,128},
  {2,300,100,100,100,0, 114688,128,128},
  {1,300,200,100,100,0, 131072,128,128},
  {2,300,200,100,100,0, 147456,128,128},
  {4,600,  0,200,200,0, 163840,224,256},
  {4,600,200,200,200,0, 221184,224,256},
  {4,600,400,200,200,0, 278528,224,256},
  {5,600,  0,200,200,0, 335872,224,256},
  {5,600,200,200,200,0, 393216,224,256},
  {5,600,400,200,200,0, 450560,224,256},
  {6,200,0,200,200,1,   507904,224,256},
  {7,600,  0,200,200,0, 565248,224,256},
  {7,600,200,200,200,0, 622592,224,256},
  {7,600,400,200,200,0, 679936,224,256},
};
struct Ptr8 { const float* p[8]; };
__global__ void k_wconv(Ptr8 srcs, __hip_bfloat16* __restrict__ dst){
  WEnt e = g_went[blockIdx.y];
  int i = blockIdx.x*256 + threadIdx.x;
  if (i >= e.rp*e.Kp) return;
  int r = i / e.Kp, k = i - r*e.Kp;
  float v = 0.f;
  if (r < e.rows && k < e.K)
    v = e.tr ? srcs.p[e.src][(size_t)k*e.ld + r] : srcs.p[e.src][(size_t)r*e.ld + e.boff + k];
  dst[e.dstoff + i] = __float2bfloat16(v);
}

__global__ void k_w2bf_nt(const float* __restrict__ src, int ldsrc,
                          int rows, int K, __hip_bfloat16* __restrict__ dst, int Kp, int rowsPad){
  int i = blockIdx.x*blockDim.x + threadIdx.x;
  if (i >= rowsPad*Kp) return;
  int r = i / Kp, k = i - r*Kp;
  float v = (r < rows && k < K) ? src[(size_t)r*ldsrc + k] : 0.f;
  dst[i] = __float2bfloat16(v);
}

// ---------------------------------------------------------------- bf16 MFMA GEMM (NT)
template<typename CT>
__global__ __launch_bounds__(256) void k_gemm_mfma(
    const __hip_bfloat16* __restrict__ A, const __hip_bfloat16* __restrict__ B,
    CT* __restrict__ C, int M, int Nn, int Kp, int ldc)
{
  __shared__ __hip_bfloat16 As[128*32];
  __shared__ __hip_bfloat16 Bs[64*32];
  const int tid = threadIdx.x;
  const int wave = tid >> 6, lane = tid & 63;
  const int lg = lane >> 4, li = lane & 15;
  const int m0 = blockIdx.y * 128, n0 = blockIdx.x * 64;
  const int wr = wave >> 1, wc = wave & 1;
  f32x4 acc[4][2] = {};

  const int ar0 = tid >> 2;
  const int ar1 = (tid + 256) >> 2;
  const int ap  = tid & 3;
  const char* Ab = (const char*)A;
  const char* Bb = (const char*)B;
  char* asB = (char*)As;
  char* bsB = (char*)Bs;

  for (int kk = 0; kk < Kp; kk += 32){
    {
      int g0 = ap ^ ((ar0 >> 1) & 3);
      const char* s0 = Ab + ((size_t)(m0 + ar0)*Kp + kk)*2 + g0*16;
      __builtin_amdgcn_global_load_lds((const __attribute__((address_space(1))) void*)s0,
          (__attribute__((address_space(3))) void*)(asB + wave*1024), 16, 0, 0);
      int g1 = ap ^ ((ar1 >> 1) & 3);
      const char* s1 = Ab + ((size_t)(m0 + ar1)*Kp + kk)*2 + g1*16;
      __builtin_amdgcn_global_load_lds((const __attribute__((address_space(1))) void*)s1,
          (__attribute__((address_space(3))) void*)(asB + 4096 + wave*1024), 16, 0, 0);
      int gb = ap ^ ((ar0 >> 1) & 3);
      const char* sb = Bb + ((size_t)(n0 + ar0)*Kp + kk)*2 + gb*16;
      __builtin_amdgcn_global_load_lds((const __attribute__((address_space(1))) void*)sb,
          (__attribute__((address_space(3))) void*)(bsB + wave*1024), 16, 0, 0);
    }
    __syncthreads();
    bf16x8 av[4], bv[2];
    #pragma unroll
    for (int mf = 0; mf < 4; mf++){
      int row = wr*64 + mf*16 + li;
      int p = lg ^ ((row >> 1) & 3);
      av[mf] = *(const bf16x8*)(asB + row*64 + p*16);
    }
    #pragma unroll
    for (int nf = 0; nf < 2; nf++){
      int row = wc*32 + nf*16 + li;
      int p = lg ^ ((row >> 1) & 3);
      bv[nf] = *(const bf16x8*)(bsB + row*64 + p*16);
    }
    #pragma unroll
    for (int mf = 0; mf < 4; mf++)
      #pragma unroll
      for (int nf = 0; nf < 2; nf++)
        acc[mf][nf] = __builtin_amdgcn_mfma_f32_16x16x32_bf16(av[mf], bv[nf], acc[mf][nf], 0, 0, 0);
    __syncthreads();
  }
  #pragma unroll
  for (int mf = 0; mf < 4; mf++){
    #pragma unroll
    for (int nf = 0; nf < 2; nf++){
      int gc = n0 + wc*32 + nf*16 + li;
      if (gc >= Nn) continue;
      int gr0 = m0 + wr*64 + mf*16 + lg*4;
      #pragma unroll
      for (int r = 0; r < 4; r++){
        int gr = gr0 + r;
        if (gr < M){
          if constexpr (std::is_same<CT,float>::value) C[(size_t)gr*ldc + gc] = acc[mf][nf][r];
          else C[(size_t)gr*ldc + gc] = __float2bfloat16(acc[mf][nf][r]);
        }
      }
    }
  }
}

// ---------------------------------------------------------------- aggregation v4
// Batched-logit edge processing for one wave. Returns per-lane partial S and acc.
// DD=200: one edge across 50 lanes, 2-deep row pipeline.
// DD=100: two edges on half-waves (25 lanes each), 2-deep pipeline.
template<int DD>
__device__ inline void agg_edges(int bstart, int end, int bstep,
    const int4* __restrict__ erec, float psn,
    const float* __restrict__ pd, const float* __restrict__ prs,
    const __hip_bfloat16* __restrict__ XSD, int ldx, int cxd,
    const __hip_bfloat16* __restrict__ RRb, int ldr, int crr,
    int lane, float& Sl, f32x4& acc)
{
  const int sub = lane >> 5, li = lane & 31;
  for (int b = bstart; b < end; b += bstep){
    int m = end - b; if (m > 64) m = 64;
    int j = b + lane;
    int4 e; e.x = 0; e.y = NRELS; e.z = NRELS; e.w = 0;
    float wv = 0.f;
    if (j < end){
      e = erec[j];
      float lg = psn + pd[e.x] + prs[e.y] + prs[e.z];
      wv = __expf(-((lg > 0.f) ? lg : 0.2f*lg));
    }
    Sl += wv;
    if constexpr (DD == 200){
      bool act = lane < 50;
      ushort4 xa = {0,0,0,0}, ra = {0,0,0,0}, rb = {0,0,0,0};
      float w0;
      {
        w0 = __shfl(wv, 0);
        int di = __shfl(e.x, 0), t0 = __shfl(e.y, 0), t1 = __shfl(e.z, 0);
        if (act){
          xa = *(const ushort4*)(XSD + (size_t)di*ldx + cxd + 4*lane);
          ra = *(const ushort4*)(RRb + (size_t)t0*ldr + crr + 4*lane);
          rb = *(const ushort4*)(RRb + (size_t)t1*ldr + crr + 4*lane);
        }
      }
      for (int i = 0; i < m; ++i){
        ushort4 xn = {0,0,0,0}, rn0 = {0,0,0,0}, rn1 = {0,0,0,0};
        float wn = 0.f;
        if (i + 1 < m){
          wn = __shfl(wv, i+1);
          int di = __shfl(e.x, i+1), t0 = __shfl(e.y, i+1), t1 = __shfl(e.z, i+1);
          if (act){
            xn  = *(const ushort4*)(XSD + (size_t)di*ldx + cxd + 4*lane);
            rn0 = *(const ushort4*)(RRb + (size_t)t0*ldr + crr + 4*lane);
            rn1 = *(const ushort4*)(RRb + (size_t)t1*ldr + crr + 4*lane);
          }
        }
        if (act){
          acc.x += w0*(bf2f(xa.x)+bf2f(ra.x)+bf2f(rb.x));
          acc.y += w0*(bf2f(xa.y)+bf2f(ra.y)+bf2f(rb.y));
          acc.z += w0*(bf2f(xa.z)+bf2f(ra.z)+bf2f(rb.z));
          acc.w += w0*(bf2f(xa.w)+bf2f(ra.w)+bf2f(rb.w));
        }
        xa = xn; ra = rn0; rb = rn1; w0 = wn;
      }
    } else {
      bool act = li < 25;
      ushort4 xa = {0,0,0,0}, ra = {0,0,0,0}, rb = {0,0,0,0};
      float w0 = 0.f;
      if (sub < m){
        w0 = __shfl(wv, sub);
        int di = __shfl(e.x, sub), t0 = __shfl(e.y, sub), t1 = __shfl(e.z, sub);
        if (act){
          xa = *(const ushort4*)(XSD + (size_t)di*ldx + cxd + 4*li);
          ra = *(const ushort4*)(RRb + (size_t)t0*ldr + crr + 4*li);
          rb = *(const ushort4*)(RRb + (size_t)t1*ldr + crr + 4*li);
        }
      }
      for (int i = sub; i < m; i += 2){
        ushort4 xn = {0,0,0,0}, rn0 = {0,0,0,0}, rn1 = {0,0,0,0};
        float wn = 0.f;
        if (i + 2 < m){
          wn = __shfl(wv, i+2);
          int di = __shfl(e.x, i+2), t0 = __shfl(e.y, i+2), t1 = __shfl(e.z, i+2);
          if (act){
            xn  = *(const ushort4*)(XSD + (size_t)di*ldx + cxd + 4*li);
            rn0 = *(const ushort4*)(RRb + (size_t)t0*ldr + crr + 4*li);
            rn1 = *(const ushort4*)(RRb + (size_t)t1*ldr + crr + 4*li);
          }
        }
        if (act){
          acc.x += w0*(bf2f(xa.x)+bf2f(ra.x)+bf2f(rb.x));
          acc.y += w0*(bf2f(xa.y)+bf2f(ra.y)+bf2f(rb.y));
          acc.z += w0*(bf2f(xa.z)+bf2f(ra.z)+bf2f(rb.z));
          acc.w += w0*(bf2f(xa.w)+bf2f(ra.w)+bf2f(rb.w));
        }
        xa = xn; ra = rn0; rb = rn1; w0 = wn;
      }
    }
  }
}

template<int DD, bool OUTF>
__device__ inline void agg_finalize(int n, float S, f32x4 acc, int lane,
    const __hip_bfloat16* __restrict__ XSD, int ldx, int cxs,
    float* __restrict__ outf, __hip_bfloat16* __restrict__ outb, int ldb, int coffb)
{
  constexpr int NL = (DD == 200) ? 50 : 25;
  if (lane >= NL) return;
  float inv = (S > 0.f) ? 1.0f/S : 0.f;
  ushort4 xs4 = *(const ushort4*)(XSD + (size_t)n*ldx + cxs + 4*lane);
  float h0 = (S > 0.f) ? bf2f(xs4.x) + acc.x*inv : 0.f;
  float h1 = (S > 0.f) ? bf2f(xs4.y) + acc.y*inv : 0.f;
  float h2 = (S > 0.f) ? bf2f(xs4.z) + acc.z*inv : 0.f;
  float h3 = (S > 0.f) ? bf2f(xs4.w) + acc.w*inv : 0.f;
  h0 = (h0 > 0.f) ? h0 : expm1f(h0);
  h1 = (h1 > 0.f) ? h1 : expm1f(h1);
  h2 = (h2 > 0.f) ? h2 : expm1f(h2);
  h3 = (h3 > 0.f) ? h3 : expm1f(h3);
  if constexpr (OUTF){
    *(float4*)(outf + (size_t)n*200 + 4*lane) = make_float4(h0, h1, h2, h3);
  } else {
    ushort4 o; o.x = f2bf(h0); o.y = f2bf(h1); o.z = f2bf(h2); o.w = f2bf(h3);
    *(ushort4*)(outb + (size_t)n*ldb + coffb + 4*lane) = o;
  }
}

// blocks [0,HOTN): whole block per node (4 waves + LDS reduce)
// blocks [HOTN,...): 4 cold nodes per block, wave each
template<int DD, bool OUTF>
__global__ __launch_bounds__(256) void k_agg4(
    const int* __restrict__ rowofs, const int4* __restrict__ erec,
    const float* __restrict__ ps, const float* __restrict__ pd, const float* __restrict__ prs,
    const __hip_bfloat16* __restrict__ XSD, int ldx, int cxs, int cxd,
    const __hip_bfloat16* __restrict__ RRb, int ldr, int crr,
    float* __restrict__ outf, __hip_bfloat16* __restrict__ outb, int ldb, int coffb)
{
  __shared__ f32x4 redA[256];
  __shared__ float redS[4];
  int bid = blockIdx.x;
  int wave = threadIdx.x >> 6, lane = threadIdx.x & 63;

  if (bid < HOTN){
    int n = bid;
    int beg = rowofs[n], end = rowofs[n+1];
    float psn = ps[n];
    float Sl = 0.f;
    f32x4 acc = {0.f,0.f,0.f,0.f};
    agg_edges<DD>(beg + wave*64, end, 256, erec, psn, pd, prs,
                  XSD, ldx, cxd, RRb, ldr, crr, lane, Sl, acc);
    // wave-level S reduce
    float Sw = Sl;
    #pragma unroll
    for (int o = 32; o; o >>= 1) Sw += __shfl_xor(Sw, o, 64);
    if constexpr (DD == 100){
      acc.x += __shfl_xor(acc.x, 32, 64);
      acc.y += __shfl_xor(acc.y, 32, 64);
      acc.z += __shfl_xor(acc.z, 32, 64);
      acc.w += __shfl_xor(acc.w, 32, 64);
    }
    redA[threadIdx.x] = acc;
    if (lane == 0) redS[wave] = Sw;
    __syncthreads();
    if (wave == 0){
      f32x4 a0 = redA[lane], a1 = redA[lane+64], a2 = redA[lane+128], a3 = redA[lane+192];
      f32x4 at = {a0.x+a1.x+a2.x+a3.x, a0.y+a1.y+a2.y+a3.y,
                  a0.z+a1.z+a2.z+a3.z, a0.w+a1.w+a2.w+a3.w};
      float St = redS[0] + redS[1] + redS[2] + redS[3];
      agg_finalize<DD,OUTF>(n, St, at, lane, XSD, ldx, cxs, outf, outb, ldb, coffb);
    }
  } else {
    int n = HOTN + (bid - HOTN)*4 + wave;
    int beg = rowofs[n], end = rowofs[n+1];
    float psn = ps[n];
    float Sl = 0.f;
    f32x4 acc = {0.f,0.f,0.f,0.f};
    agg_edges<DD>(beg, end, 64, erec, psn, pd, prs,
                  XSD, ldx, cxd, RRb, ldr, crr, lane, Sl, acc);
    float S = Sl;
    #pragma unroll
    for (int o = 32; o; o >>= 1) S += __shfl_xor(S, o, 64);
    if constexpr (DD == 100){
      acc.x += __shfl_xor(acc.x, 32, 64);
      acc.y += __shfl_xor(acc.y, 32, 64);
      acc.z += __shfl_xor(acc.z, 32, 64);
      acc.w += __shfl_xor(acc.w, 32, 64);
      if (lane >= 32) return;
    }
    agg_finalize<DD,OUTF>(n, S, acc, lane, XSD, ldx, cxs, outf, outb, ldb, coffb);
  }
}

// ---------------------------------------------------------------- driver
extern "C" void kernel_launch(void* const* d_in, const int* in_sizes, int n_in,
                              void* d_out, int out_size, void* d_ws, size_t ws_size,
                              hipStream_t stream) {
  const float* entity   = (const float*)d_in[0];
  const float* relation = (const float*)d_in[1];
  const float* W_ent    = (const float*)d_in[2];
  const float* g0_a0    = (const float*)d_in[3];
  const float* g0_s0    = (const float*)d_in[4];
  const float* g0_a1    = (const float*)d_in[5];
  const float* g0_s1    = (const float*)d_in[6];
  const float* g0_W     = (const float*)d_in[7];
  const float* g0_oa    = (const float*)d_in[8];
  const float* g0_os    = (const float*)d_in[9];
  const float* g1_a0    = (const float*)d_in[10];
  const float* g1_s0    = (const float*)d_in[11];
  const float* g1_W     = (const float*)d_in[12];
  const float* g1_oa    = (const float*)d_in[13];
  const float* g1_os    = (const float*)d_in[14];
  const int*   el       = (const int*)d_in[15];
  const int*   et       = (const int*)d_in[16];
  const int*   nh       = (const int*)d_in[17];
  const int*   batch    = (const int*)d_in[18];
  (void)in_sizes; (void)n_in; (void)out_size; (void)ws_size;

  char* w = (char*)d_ws;
  auto alloc = [&](size_t bytes)->char*{ char* p = w; w += (bytes + 255) & ~(size_t)255; return p; };
  float* ENTUP = (float*)alloc((size_t)MP*200*4);
  float* ENT1  = (float*)alloc((size_t)NNODES*200*4);
  float* XSF   = (float*)alloc((size_t)MP*200*4);
  float* RELUP = (float*)alloc((size_t)RPAD*200*4);
  float* REL1  = (float*)alloc((size_t)NRELS*200*4);
  float* OR0   = (float*)alloc((size_t)RPAD*200*4);
  float* OR1   = (float*)alloc((size_t)RPAD*200*4);
  float* PS    = (float*)alloc((size_t)NNODES*4);
  float* PD    = (float*)alloc((size_t)NNODES*4);
  float* PRS   = (float*)alloc((size_t)(NRELS+4)*4);
  __hip_bfloat16* AENT0 = (__hip_bfloat16*)alloc((size_t)MP*128*2);
  __hip_bfloat16* AX1   = (__hip_bfloat16*)alloc((size_t)MP*224*2);
  __hip_bfloat16* AENT1 = (__hip_bfloat16*)alloc((size_t)MP*224*2);
  __hip_bfloat16* AREL0 = (__hip_bfloat16*)alloc((size_t)RPAD*128*2);
  __hip_bfloat16* AREL1 = (__hip_bfloat16*)alloc((size_t)RPAD*224*2);
  __hip_bfloat16* AOR   = (__hip_bfloat16*)alloc((size_t)RPAD*224*2);
  __hip_bfloat16* XSD   = (__hip_bfloat16*)alloc((size_t)MP*512*2);
  __hip_bfloat16* RRb   = (__hip_bfloat16*)alloc((size_t)RPAD*256*2);
  __hip_bfloat16* WA    = (__hip_bfloat16*)alloc((size_t)737280*2);
  int* IALL = (int*)alloc((size_t)150001*4);
  int* ROWOFS = IALL;
  int* CUR    = IALL + 50001;
  float* MASK = (float*)(IALL + 100001);
  int4* EREC  = (int4*)alloc((size_t)NETOT*16);
  int* PART   = (int*)alloc((size_t)256*4);

  const __hip_bfloat16* WET   = WA;
  const __hip_bfloat16* G0WT  = WA + 32768;
  const __hip_bfloat16* BH0   = WA + 65536;
  const __hip_bfloat16* BR0   = WA + 131072;
  const __hip_bfloat16* BO0   = WA + 163840;
  const __hip_bfloat16* BO0r  = WA + 278528;
  const __hip_bfloat16* BA1   = WA + 335872;
  const __hip_bfloat16* BA1r  = WA + 450560;
  const __hip_bfloat16* G1WT  = WA + 507904;
  const __hip_bfloat16* BO1   = WA + 565248;
  const __hip_bfloat16* BO1r  = WA + 679936;

  float* outEnt = (float*)d_out;
  float* outRel = outEnt + (size_t)NNODES*200;

  const int TB = 256;
  auto gb = [&](long long n){ return (int)((n + TB - 1)/TB); };
  const int AGG_GRID = HOTN + (NNODES - HOTN)/4;

  // ---- preprocessing ----
  k_zero<<<gb(150001), TB, 0, stream>>>(IALL, 150001);
  k_zero<<<gb((RPAD*128 + RPAD*224)/2), TB, 0, stream>>>((int*)AREL0, (RPAD*128 + RPAD*224)/2);
  k_mask_set<<<gb(10000), TB, 0, stream>>>(batch, MASK, 10000);
  k_hist<<<gb(NETOT), TB, 0, stream>>>(el, nh, ROWOFS);
  int nsb = (NNODES + 255)/256;
  k_scan1<<<nsb, 256, 0, stream>>>(ROWOFS, NNODES, PART);
  k_scan2<<<1, 256, 0, stream>>>(PART, nsb);
  k_scan3<<<nsb, 256, 0, stream>>>(ROWOFS, NNODES, PART);
  k_scatter<<<gb(NETOT), TB, 0, stream>>>(el, et, nh, ROWOFS, CUR, EREC);
  k_padcols<<<gb((long long)MP*24), TB, 0, stream>>>(AX1, MP, 200, 224);

  // ---- inputs -> bf16 arenas; weights -> bf16 arena ----
  k_l2norm_bf<100,128><<<NNODES, 64, 0, stream>>>(entity, AENT0);
  k_l2norm_bf<100,128><<<NRELS, 64, 0, stream>>>(relation, AREL0);
  {
    Ptr8 srcs;
    srcs.p[0] = W_ent; srcs.p[1] = g0_a0; srcs.p[2] = g0_a1; srcs.p[3] = g0_W;
    srcs.p[4] = g0_oa; srcs.p[5] = g1_a0; srcs.p[6] = g1_W;  srcs.p[7] = g1_oa;
    dim3 g(448, 18);
    k_wconv<<<g, 256, 0, stream>>>(srcs, WA);
  }

  auto gemm_f = [&](const __hip_bfloat16* A, const __hip_bfloat16* B, float* C, int M, int Nn, int Kp, int ldc){
    dim3 g((Nn + 63)/64, (M + 127)/128);
    k_gemm_mfma<float><<<g, 256, 0, stream>>>(A, B, C, M, Nn, Kp, ldc);
  };
  auto gemm_b = [&](const __hip_bfloat16* A, const __hip_bfloat16* B, __hip_bfloat16* C, int M, int Nn, int Kp, int ldc){
    dim3 g((Nn + 63)/64, (M + 127)/128);
    k_gemm_mfma<__hip_bfloat16><<<g, 256, 0, stream>>>(A, B, C, M, Nn, Kp, ldc);
  };
  auto rd2_node = [&](int c0, int c1, int D, const float* a2){
    k_rowdot2<<<(NNODES + 3)/4, 256, 0, stream>>>(XSD, NNODES, 512, c0, c1, D, a2, PS, PD);
  };
  auto rd2_rel = [&](int c0, int D, const float* a2){
    k_rowdot2<<<(NRELS + 4)/4, 256, 0, stream>>>(RRb, NRELS+1, 256, c0, -1, D, a2, PRS, nullptr);
  };

  // ---- ent_up / rel_up ----
  gemm_f(AENT0, WET, ENTUP, MP, 200, 128, 200);
  gemm_f(AREL0, WET, RELUP, RPAD, 200, 128, 200);

  // ---- layer0 heads ----
  gemm_b(AENT0, BH0, XSD, MP, 512, 128, 512);
  gemm_b(AREL0, BR0, RRb, RPAD, 256, 128, 256);
  for (int h = 0; h < 2; h++){
    const float* s2 = h ? g0_s1 : g0_s0;
    rd2_node(256*h, 256*h + 128, 100, s2);
    rd2_rel(128*h, 100, s2);
    k_agg4<100,false><<<AGG_GRID, 256, 0, stream>>>(ROWOFS, EREC, PS, PD, PRS,
        XSD, 512, 256*h, 256*h + 128, RRb, 256, 128*h, nullptr, AX1, 224, 100*h);
  }

  // ---- layer0 out-attention ----
  gemm_f(AREL0, G0WT, OR0, RPAD, 200, 128, 200);
  k_w2bf_nt<<<gb((long long)RPAD*224), TB, 0, stream>>>(OR0, 200, NRELS, 200, AOR, 224, RPAD);
  gemm_b(AX1, BO0, XSD, MP, 512, 224, 512);
  gemm_b(AOR, BO0r, RRb, RPAD, 256, 224, 256);
  rd2_node(0, 256, 200, g0_os);
  rd2_rel(0, 200, g0_os);
  k_agg4<200,true><<<AGG_GRID, 256, 0, stream>>>(ROWOFS, EREC, PS, PD, PRS,
      XSD, 512, 0, 256, RRb, 256, 0, XSF, nullptr, 0, 0);
  k_combine_norm<200,224><<<NNODES, 64, 0, stream>>>(ENTUP, XSF, MASK, ENT1, AENT1);
  k_combine_norm<200,224><<<NRELS, 64, 0, stream>>>(RELUP, OR0, nullptr, REL1, AREL1);

  // ---- layer1 head ----
  gemm_b(AENT1, BA1, XSD, MP, 512, 224, 512);
  gemm_b(AREL1, BA1r, RRb, RPAD, 256, 224, 256);
  rd2_node(0, 256, 200, g1_s0);
  rd2_rel(0, 200, g1_s0);
  k_agg4<200,false><<<AGG_GRID, 256, 0, stream>>>(ROWOFS, EREC, PS, PD, PRS,
      XSD, 512, 0, 256, RRb, 256, 0, nullptr, AX1, 224, 0);

  // ---- layer1 out-attention ----
  gemm_f(AREL1, G1WT, OR1, RPAD, 200, 224, 200);
  k_w2bf_nt<<<gb((long long)RPAD*224), TB, 0, stream>>>(OR1, 200, NRELS, 200, AOR, 224, RPAD);
  gemm_b(AX1, BO1, XSD, MP, 512, 224, 512);
  gemm_b(AOR, BO1r, RRb, RPAD, 256, 224, 256);
  rd2_node(0, 256, 200, g1_os);
  rd2_rel(0, 200, g1_os);
  k_agg4<200,true><<<AGG_GRID, 256, 0, stream>>>(ROWOFS, EREC, PS, PD, PRS,
      XSD, 512, 0, 256, RRb, 256, 0, XSF, nullptr, 0, 0);

  // ---- final combines -> d_out ----
  k_combine_norm<200,224><<<NNODES, 64, 0, stream>>>(ENT1, XSF, MASK, outEnt, nullptr);
  k_combine_norm<200,224><<<NRELS, 64, 0, stream>>>(REL1, OR1, nullptr, outRel, nullptr);
}

// Round 6
// 783.575 us; speedup vs baseline: 4.6802x; 1.0492x over previous
//
#include <hip/hip_runtime.h>
#include <hip/hip_bf16.h>
#include <cstdint>
#include <cstddef>
#include <type_traits>

#define NNODES 50000
#define NRELS  500
#define NEDGE  500000
#define NETOT  600000
#define MP     50048
#define RPAD   512
#define HOTN   512

typedef __attribute__((ext_vector_type(8))) short bf16x8;
typedef __attribute__((ext_vector_type(4))) float f32x4;

__device__ inline float bf2f(unsigned short s){
  union { unsigned u; float f; } v; v.u = ((unsigned)s) << 16; return v.f;
}
__device__ inline unsigned short f2bf(float f){
  __hip_bfloat16 h = __float2bfloat16(f);
  return __builtin_bit_cast(unsigned short, h);
}

// ---------------------------------------------------------------- utilities
__global__ void k_zero(int* __restrict__ p, int n){
  int i = blockIdx.x*blockDim.x + threadIdx.x;
  if (i < n) p[i] = 0;
}
__global__ void k_mask_set(const int* __restrict__ batch, float* __restrict__ mask, int nb){
  int i = blockIdx.x*blockDim.x + threadIdx.x;
  if (i < nb) mask[batch[3*i+2]] = 1.0f;
}
__global__ void k_padcols(__hip_bfloat16* __restrict__ dst, int Mpad, int K, int Kp){
  int padw = Kp - K;
  long long i = (long long)blockIdx.x*blockDim.x + threadIdx.x;
  if (i >= (long long)Mpad*padw) return;
  int r = (int)(i / padw), k = K + (int)(i - (long long)r*padw);
  dst[(size_t)r*Kp + k] = __float2bfloat16(0.f);
}

// ---------------------------------------------------------------- edge CSR
__global__ void k_hist(const int* __restrict__ el, const int* __restrict__ nh, int* __restrict__ deg){
  int e = blockIdx.x*blockDim.x + threadIdx.x;
  if (e >= NETOT) return;
  int s = (e < NEDGE) ? el[e] : nh[4*(e-NEDGE)+3];
  atomicAdd(&deg[s], 1);
}
__global__ void k_scan1(int* __restrict__ data, int n, int* __restrict__ part){
  __shared__ int sh[256];
  int t = threadIdx.x, i = blockIdx.x*256 + t;
  int v = (i < n) ? data[i] : 0;
  sh[t] = v; __syncthreads();
  for (int o = 1; o < 256; o <<= 1){
    int x = (t >= o) ? sh[t-o] : 0;
    __syncthreads(); sh[t] += x; __syncthreads();
  }
  if (i < n) data[i] = sh[t] - v;
  if (t == 255) part[blockIdx.x] = sh[255];
}
__global__ void k_scan2(int* __restrict__ part, int nb){
  __shared__ int sh[256];
  int t = threadIdx.x;
  int v = (t < nb) ? part[t] : 0;
  sh[t] = v; __syncthreads();
  for (int o = 1; o < 256; o <<= 1){
    int x = (t >= o) ? sh[t-o] : 0;
    __syncthreads(); sh[t] += x; __syncthreads();
  }
  if (t < nb) part[t] = sh[t] - v;
}
__global__ void k_scan3(int* __restrict__ data, int n, const int* __restrict__ part){
  int i = blockIdx.x*256 + threadIdx.x;
  if (i < n) data[i] += part[blockIdx.x];
  if (i == 0) data[n] = NETOT;
}
// unified scatter: t1 = NRELS (zero row) for 1-hop edges
__global__ void k_scatter(const int* __restrict__ el, const int* __restrict__ et,
                          const int* __restrict__ nh, const int* __restrict__ rowofs,
                          int* __restrict__ cur, int4* __restrict__ erec){
  int e = blockIdx.x*blockDim.x + threadIdx.x;
  if (e >= NETOT) return;
  int s, d, t0, t1;
  if (e < NEDGE){ s = el[e]; d = el[NEDGE+e]; t0 = et[e]; t1 = NRELS; }
  else { int i = e - NEDGE; s = nh[4*i+3]; d = nh[4*i+0]; t0 = nh[4*i+1]; t1 = nh[4*i+2]; }
  int p = rowofs[s] + atomicAdd(&cur[s], 1);
  erec[p] = make_int4(d, t0, t1, 0);
}

// ---------------------------------------------------------------- row kernels
template<int D, int KP>
__global__ __launch_bounds__(64) void k_l2norm_bf(const float* __restrict__ in,
                                                  __hip_bfloat16* __restrict__ bfout){
  constexpr int NK = KP/64;
  int n = blockIdx.x, lane = threadIdx.x;
  const float* row = in + (size_t)n*D;
  float v[NK]; float ss = 0.f;
  #pragma unroll
  for (int k = 0; k < NK; k++){ int c = lane + 64*k; v[k] = (c < D) ? row[c] : 0.f; ss += v[k]*v[k]; }
  #pragma unroll
  for (int o = 32; o; o >>= 1) ss += __shfl_xor(ss, o, 64);
  float sc = 1.0f / fmaxf(sqrtf(ss), 1e-12f);
  __hip_bfloat16* orow = bfout + (size_t)n*KP;
  #pragma unroll
  for (int k = 0; k < NK; k++){ int c = lane + 64*k; orow[c] = __float2bfloat16(v[k]*sc); }
}

template<int D, int KP>
__global__ __launch_bounds__(64) void k_combine_norm(const float* __restrict__ base,
                                                     const float* __restrict__ h,
                                                     const float* __restrict__ mask,
                                                     float* __restrict__ outf,
                                                     __hip_bfloat16* __restrict__ outb){
  constexpr int NK = (KP+63)/64;
  int n = blockIdx.x, lane = threadIdx.x;
  float m = mask ? mask[n] : 1.0f;
  const float* b = base + (size_t)n*D;
  const float* hr = h + (size_t)n*D;
  float v[NK]; float ss = 0.f;
  #pragma unroll
  for (int k = 0; k < NK; k++){ int c = lane + 64*k; v[k] = (c < D) ? (b[c] + m*hr[c]) : 0.f; ss += v[k]*v[k]; }
  #pragma unroll
  for (int o = 32; o; o >>= 1) ss += __shfl_xor(ss, o, 64);
  float sc = 1.0f / fmaxf(sqrtf(ss), 1e-12f);
  float* orow = outf + (size_t)n*D;
  #pragma unroll
  for (int k = 0; k < NK; k++){ int c = lane + 64*k; if (c < D) orow[c] = v[k]*sc; }
  if (outb){
    __hip_bfloat16* brow = outb + (size_t)n*KP;
    #pragma unroll
    for (int k = 0; k < NK; k++){ int c = lane + 64*k; if (c < KP) brow[c] = __float2bfloat16(v[k]*sc); }
  }
}

// paired rowdot on interleaved bf16 C
__global__ void k_rowdot2(const __hip_bfloat16* __restrict__ X, int M, int ldx,
                          int c0, int c1, int D, const float* __restrict__ a2,
                          float* __restrict__ o0, float* __restrict__ o1){
  int wid = threadIdx.x >> 6, lane = threadIdx.x & 63;
  int row = blockIdx.x*4 + wid;
  if (row >= M) return;
  int nl = D >> 2;
  float p0 = 0.f, p1 = 0.f;
  if (lane < nl){
    float4 a = *(const float4*)(a2 + 4*lane);
    const __hip_bfloat16* base = X + (size_t)row*ldx;
    ushort4 x0 = *(const ushort4*)(base + c0 + 4*lane);
    p0 = bf2f(x0.x)*a.x + bf2f(x0.y)*a.y + bf2f(x0.z)*a.z + bf2f(x0.w)*a.w;
    if (o1){
      ushort4 x1 = *(const ushort4*)(base + c1 + 4*lane);
      p1 = bf2f(x1.x)*a.x + bf2f(x1.y)*a.y + bf2f(x1.z)*a.z + bf2f(x1.w)*a.w;
    }
  }
  #pragma unroll
  for (int o = 32; o; o >>= 1){ p0 += __shfl_xor(p0, o, 64); p1 += __shfl_xor(p1, o, 64); }
  if (lane == 0){ o0[row] = p0; if (o1) o1[row] = p1; }
}

// ---------------------------------------------------------------- mega weight->bf16 conversion
struct WEnt { int src, ld, boff, rows, K, tr, dstoff, Kp, rp; };
__device__ const WEnt g_went[18] = {
  {0,200,0,200,100,1,      0,128,256},
  {3,200,0,200,100,1,  32768,128,256},
  {1,300,  0,100,100,0,  65536,128,128},
  {1,300,100,100,100,0,  81920,128,128},
  {2,300,  0,100,100,0,  98304,128,128},
  {2,300,100,100,100,0, 114688,128,128},
  {1,300,200,100,100,0, 131072,128,128},
  {2,300,200,100,100,0, 147456,128,128},
  {4,600,  0,200,200,0, 163840,224,256},
  {4,600,200,200,200,0, 221184,224,256},
  {4,600,400,200,200,0, 278528,224,256},
  {5,600,  0,200,200,0, 335872,224,256},
  {5,600,200,200,200,0, 393216,224,256},
  {5,600,400,200,200,0, 450560,224,256},
  {6,200,0,200,200,1,   507904,224,256},
  {7,600,  0,200,200,0, 565248,224,256},
  {7,600,200,200,200,0, 622592,224,256},
  {7,600,400,200,200,0, 679936,224,256},
};
struct Ptr8 { const float* p[8]; };
__global__ void k_wconv(Ptr8 srcs, __hip_bfloat16* __restrict__ dst){
  WEnt e = g_went[blockIdx.y];
  int i = blockIdx.x*256 + threadIdx.x;
  if (i >= e.rp*e.Kp) return;
  int r = i / e.Kp, k = i - r*e.Kp;
  float v = 0.f;
  if (r < e.rows && k < e.K)
    v = e.tr ? srcs.p[e.src][(size_t)k*e.ld + r] : srcs.p[e.src][(size_t)r*e.ld + e.boff + k];
  dst[e.dstoff + i] = __float2bfloat16(v);
}

__global__ void k_w2bf_nt(const float* __restrict__ src, int ldsrc,
                          int rows, int K, __hip_bfloat16* __restrict__ dst, int Kp, int rowsPad){
  int i = blockIdx.x*blockDim.x + threadIdx.x;
  if (i >= rowsPad*Kp) return;
  int r = i / Kp, k = i - r*Kp;
  float v = (r < rows && k < K) ? src[(size_t)r*ldsrc + k] : 0.f;
  dst[i] = __float2bfloat16(v);
}

// ---------------------------------------------------------------- bf16 MFMA GEMM (NT)
template<typename CT>
__global__ __launch_bounds__(256) void k_gemm_mfma(
    const __hip_bfloat16* __restrict__ A, const __hip_bfloat16* __restrict__ B,
    CT* __restrict__ C, int M, int Nn, int Kp, int ldc)
{
  __shared__ __hip_bfloat16 As[128*32];
  __shared__ __hip_bfloat16 Bs[64*32];
  const int tid = threadIdx.x;
  const int wave = tid >> 6, lane = tid & 63;
  const int lg = lane >> 4, li = lane & 15;
  const int m0 = blockIdx.y * 128, n0 = blockIdx.x * 64;
  const int wr = wave >> 1, wc = wave & 1;
  f32x4 acc[4][2] = {};

  const int ar0 = tid >> 2;
  const int ar1 = (tid + 256) >> 2;
  const int ap  = tid & 3;
  const char* Ab = (const char*)A;
  const char* Bb = (const char*)B;
  char* asB = (char*)As;
  char* bsB = (char*)Bs;

  for (int kk = 0; kk < Kp; kk += 32){
    {
      int g0 = ap ^ ((ar0 >> 1) & 3);
      const char* s0 = Ab + ((size_t)(m0 + ar0)*Kp + kk)*2 + g0*16;
      __builtin_amdgcn_global_load_lds((const __attribute__((address_space(1))) void*)s0,
          (__attribute__((address_space(3))) void*)(asB + wave*1024), 16, 0, 0);
      int g1 = ap ^ ((ar1 >> 1) & 3);
      const char* s1 = Ab + ((size_t)(m0 + ar1)*Kp + kk)*2 + g1*16;
      __builtin_amdgcn_global_load_lds((const __attribute__((address_space(1))) void*)s1,
          (__attribute__((address_space(3))) void*)(asB + 4096 + wave*1024), 16, 0, 0);
      int gb = ap ^ ((ar0 >> 1) & 3);
      const char* sb = Bb + ((size_t)(n0 + ar0)*Kp + kk)*2 + gb*16;
      __builtin_amdgcn_global_load_lds((const __attribute__((address_space(1))) void*)sb,
          (__attribute__((address_space(3))) void*)(bsB + wave*1024), 16, 0, 0);
    }
    __syncthreads();
    bf16x8 av[4], bv[2];
    #pragma unroll
    for (int mf = 0; mf < 4; mf++){
      int row = wr*64 + mf*16 + li;
      int p = lg ^ ((row >> 1) & 3);
      av[mf] = *(const bf16x8*)(asB + row*64 + p*16);
    }
    #pragma unroll
    for (int nf = 0; nf < 2; nf++){
      int row = wc*32 + nf*16 + li;
      int p = lg ^ ((row >> 1) & 3);
      bv[nf] = *(const bf16x8*)(bsB + row*64 + p*16);
    }
    #pragma unroll
    for (int mf = 0; mf < 4; mf++)
      #pragma unroll
      for (int nf = 0; nf < 2; nf++)
        acc[mf][nf] = __builtin_amdgcn_mfma_f32_16x16x32_bf16(av[mf], bv[nf], acc[mf][nf], 0, 0, 0);
    __syncthreads();
  }
  #pragma unroll
  for (int mf = 0; mf < 4; mf++){
    #pragma unroll
    for (int nf = 0; nf < 2; nf++){
      int gc = n0 + wc*32 + nf*16 + li;
      if (gc >= Nn) continue;
      int gr0 = m0 + wr*64 + mf*16 + lg*4;
      #pragma unroll
      for (int r = 0; r < 4; r++){
        int gr = gr0 + r;
        if (gr < M){
          if constexpr (std::is_same<CT,float>::value) C[(size_t)gr*ldc + gc] = acc[mf][nf][r];
          else C[(size_t)gr*ldc + gc] = __float2bfloat16(acc[mf][nf][r]);
        }
      }
    }
  }
}

// ---------------------------------------------------------------- aggregation v5 (D=200)
// Batched logit, zero-row skip, float4 pk math. Lanes 0..49 own 4 cols each.
__device__ inline void agg5_edges(int bstart, int end, int bstep,
    const int4* __restrict__ erec, float psn,
    const float* __restrict__ pd, const float* __restrict__ prs,
    const __hip_bfloat16* __restrict__ XSD, int ldx, int cxd,
    const __hip_bfloat16* __restrict__ RRb, int ldr, int crr,
    int lane, float& Sl, float4& acc)
{
  bool act = lane < 50;
  const __hip_bfloat16* xb = XSD + cxd + 4*lane;
  const __hip_bfloat16* rb = RRb + crr + 4*lane;
  for (int b = bstart; b < end; b += bstep){
    int j = b + lane;
    int4 e = make_int4(0, NRELS, NRELS, 0);
    float wv = 0.f;
    if (j < end){
      e = erec[j];
      float lg = psn + pd[e.x] + prs[e.y] + prs[e.z];
      wv = __expf(-((lg > 0.f) ? lg : 0.2f*lg));
    }
    Sl += wv;
    int m = end - b; if (m > 64) m = 64;
    for (int i = 0; i < m; ++i){
      float w0 = __shfl(wv, i);
      int di = __shfl(e.x, i), t0 = __shfl(e.y, i), t1 = __shfl(e.z, i);
      if (act){
        ushort4 xa = *(const ushort4*)(xb + (size_t)di*ldx);
        ushort4 ra = *(const ushort4*)(rb + (size_t)t0*ldr);
        float sx = bf2f(xa.x) + bf2f(ra.x);
        float sy = bf2f(xa.y) + bf2f(ra.y);
        float sz = bf2f(xa.z) + bf2f(ra.z);
        float sw = bf2f(xa.w) + bf2f(ra.w);
        if (t1 != NRELS){
          ushort4 rc = *(const ushort4*)(rb + (size_t)t1*ldr);
          sx += bf2f(rc.x); sy += bf2f(rc.y); sz += bf2f(rc.z); sw += bf2f(rc.w);
        }
        acc.x += w0*sx; acc.y += w0*sy; acc.z += w0*sz; acc.w += w0*sw;
      }
    }
  }
}

template<bool OUTF>
__device__ inline void agg5_finalize(int n, float S, float4 acc, int lane,
    const __hip_bfloat16* __restrict__ XSD, int ldx, int cxs,
    float* __restrict__ outf, __hip_bfloat16* __restrict__ outb, int ldb, int coffb)
{
  if (lane >= 50) return;
  float inv = (S > 0.f) ? 1.0f/S : 0.f;
  ushort4 xs4 = *(const ushort4*)(XSD + (size_t)n*ldx + cxs + 4*lane);
  float h0 = (S > 0.f) ? bf2f(xs4.x) + acc.x*inv : 0.f;
  float h1 = (S > 0.f) ? bf2f(xs4.y) + acc.y*inv : 0.f;
  float h2 = (S > 0.f) ? bf2f(xs4.z) + acc.z*inv : 0.f;
  float h3 = (S > 0.f) ? bf2f(xs4.w) + acc.w*inv : 0.f;
  h0 = (h0 > 0.f) ? h0 : expm1f(h0);
  h1 = (h1 > 0.f) ? h1 : expm1f(h1);
  h2 = (h2 > 0.f) ? h2 : expm1f(h2);
  h3 = (h3 > 0.f) ? h3 : expm1f(h3);
  if constexpr (OUTF){
    *(float4*)(outf + (size_t)n*200 + 4*lane) = make_float4(h0, h1, h2, h3);
  } else {
    ushort4 o; o.x = f2bf(h0); o.y = f2bf(h1); o.z = f2bf(h2); o.w = f2bf(h3);
    *(ushort4*)(outb + (size_t)n*ldb + coffb + 4*lane) = o;
  }
}

template<bool OUTF>
__global__ __launch_bounds__(256) void k_agg5(
    const int* __restrict__ rowofs, const int4* __restrict__ erec,
    const float* __restrict__ ps, const float* __restrict__ pd, const float* __restrict__ prs,
    const __hip_bfloat16* __restrict__ XSD, int ldx, int cxs, int cxd,
    const __hip_bfloat16* __restrict__ RRb, int ldr, int crr,
    float* __restrict__ outf, __hip_bfloat16* __restrict__ outb, int ldb, int coffb)
{
  __shared__ float4 redA[256];
  __shared__ float redS[4];
  int bid = blockIdx.x;
  int wave = threadIdx.x >> 6, lane = threadIdx.x & 63;

  if (bid < HOTN){
    int n = bid;
    int beg = rowofs[n], end = rowofs[n+1];
    float psn = ps[n];
    float Sl = 0.f;
    float4 acc = make_float4(0.f,0.f,0.f,0.f);
    agg5_edges(beg + wave*64, end, 256, erec, psn, pd, prs,
               XSD, ldx, cxd, RRb, ldr, crr, lane, Sl, acc);
    float Sw = Sl;
    #pragma unroll
    for (int o = 32; o; o >>= 1) Sw += __shfl_xor(Sw, o, 64);
    redA[threadIdx.x] = acc;
    if (lane == 0) redS[wave] = Sw;
    __syncthreads();
    if (wave == 0){
      float4 a0 = redA[lane], a1 = redA[lane+64], a2 = redA[lane+128], a3 = redA[lane+192];
      float4 at = make_float4(a0.x+a1.x+a2.x+a3.x, a0.y+a1.y+a2.y+a3.y,
                              a0.z+a1.z+a2.z+a3.z, a0.w+a1.w+a2.w+a3.w);
      float St = redS[0] + redS[1] + redS[2] + redS[3];
      agg5_finalize<OUTF>(n, St, at, lane, XSD, ldx, cxs, outf, outb, ldb, coffb);
    }
  } else {
    int n = HOTN + (bid - HOTN)*4 + wave;
    int beg = rowofs[n], end = rowofs[n+1];
    float psn = ps[n];
    float Sl = 0.f;
    float4 acc = make_float4(0.f,0.f,0.f,0.f);
    agg5_edges(beg, end, 64, erec, psn, pd, prs,
               XSD, ldx, cxd, RRb, ldr, crr, lane, Sl, acc);
    float S = Sl;
    #pragma unroll
    for (int o = 32; o; o >>= 1) S += __shfl_xor(S, o, 64);
    agg5_finalize<OUTF>(n, S, acc, lane, XSD, ldx, cxs, outf, outb, ldb, coffb);
  }
}

// ---------------------------------------------------------------- fused layer0-heads aggregation (D=100 x2)
// Lanes 0..24: head0 cols (cxd=128,crr=0); lanes 25..49: head1 cols (cxd=384,crr=128).
// One edge walk serves both heads.
__device__ inline void aggh_edges(int bstart, int end, int bstep,
    const int4* __restrict__ erec,
    float ps0n, const float* __restrict__ pd0, const float* __restrict__ prs0,
    float ps1n, const float* __restrict__ pd1, const float* __restrict__ prs1,
    const __hip_bfloat16* __restrict__ XSD, int ldx,
    const __hip_bfloat16* __restrict__ RRb, int ldr,
    int lane, float& Sl0, float& Sl1, float4& acc)
{
  bool act = lane < 50;
  int head = (lane >= 25) ? 1 : 0;
  int li = lane - 25*head;
  const __hip_bfloat16* xb = XSD + (head ? 384 : 128) + 4*li;
  const __hip_bfloat16* rb = RRb + (head ? 128 : 0) + 4*li;
  for (int b = bstart; b < end; b += bstep){
    int j = b + lane;
    int4 e = make_int4(0, NRELS, NRELS, 0);
    float wv0 = 0.f, wv1 = 0.f;
    if (j < end){
      e = erec[j];
      float lg0 = ps0n + pd0[e.x] + prs0[e.y] + prs0[e.z];
      float lg1 = ps1n + pd1[e.x] + prs1[e.y] + prs1[e.z];
      wv0 = __expf(-((lg0 > 0.f) ? lg0 : 0.2f*lg0));
      wv1 = __expf(-((lg1 > 0.f) ? lg1 : 0.2f*lg1));
    }
    Sl0 += wv0; Sl1 += wv1;
    int m = end - b; if (m > 64) m = 64;
    for (int i = 0; i < m; ++i){
      float wA = __shfl(wv0, i);
      float wB = __shfl(wv1, i);
      int di = __shfl(e.x, i), t0 = __shfl(e.y, i), t1 = __shfl(e.z, i);
      if (act){
        float w = head ? wB : wA;
        ushort4 xa = *(const ushort4*)(xb + (size_t)di*ldx);
        ushort4 ra = *(const ushort4*)(rb + (size_t)t0*ldr);
        float sx = bf2f(xa.x) + bf2f(ra.x);
        float sy = bf2f(xa.y) + bf2f(ra.y);
        float sz = bf2f(xa.z) + bf2f(ra.z);
        float sw = bf2f(xa.w) + bf2f(ra.w);
        if (t1 != NRELS){
          ushort4 rc = *(const ushort4*)(rb + (size_t)t1*ldr);
          sx += bf2f(rc.x); sy += bf2f(rc.y); sz += bf2f(rc.z); sw += bf2f(rc.w);
        }
        acc.x += w*sx; acc.y += w*sy; acc.z += w*sz; acc.w += w*sw;
      }
    }
  }
}

__device__ inline void aggh_finalize(int n, float S0, float S1, float4 acc, int lane,
    const __hip_bfloat16* __restrict__ XSD, int ldx,
    __hip_bfloat16* __restrict__ outb, int ldb)
{
  if (lane >= 50) return;
  int head = (lane >= 25) ? 1 : 0;
  int li = lane - 25*head;
  float S = head ? S1 : S0;
  float inv = (S > 0.f) ? 1.0f/S : 0.f;
  ushort4 xs4 = *(const ushort4*)(XSD + (size_t)n*ldx + (head ? 256 : 0) + 4*li);
  float h0 = (S > 0.f) ? bf2f(xs4.x) + acc.x*inv : 0.f;
  float h1 = (S > 0.f) ? bf2f(xs4.y) + acc.y*inv : 0.f;
  float h2 = (S > 0.f) ? bf2f(xs4.z) + acc.z*inv : 0.f;
  float h3 = (S > 0.f) ? bf2f(xs4.w) + acc.w*inv : 0.f;
  h0 = (h0 > 0.f) ? h0 : expm1f(h0);
  h1 = (h1 > 0.f) ? h1 : expm1f(h1);
  h2 = (h2 > 0.f) ? h2 : expm1f(h2);
  h3 = (h3 > 0.f) ? h3 : expm1f(h3);
  ushort4 o; o.x = f2bf(h0); o.y = f2bf(h1); o.z = f2bf(h2); o.w = f2bf(h3);
  *(ushort4*)(outb + (size_t)n*ldb + 100*head + 4*li) = o;
}

__global__ __launch_bounds__(256) void k_aggh(
    const int* __restrict__ rowofs, const int4* __restrict__ erec,
    const float* __restrict__ ps0, const float* __restrict__ pd0, const float* __restrict__ prs0,
    const float* __restrict__ ps1, const float* __restrict__ pd1, const float* __restrict__ prs1,
    const __hip_bfloat16* __restrict__ XSD, int ldx,
    const __hip_bfloat16* __restrict__ RRb, int ldr,
    __hip_bfloat16* __restrict__ outb, int ldb)
{
  __shared__ float4 redA[256];
  __shared__ float redS0[4];
  __shared__ float redS1[4];
  int bid = blockIdx.x;
  int wave = threadIdx.x >> 6, lane = threadIdx.x & 63;

  if (bid < HOTN){
    int n = bid;
    int beg = rowofs[n], end = rowofs[n+1];
    float ps0n = ps0[n], ps1n = ps1[n];
    float Sl0 = 0.f, Sl1 = 0.f;
    float4 acc = make_float4(0.f,0.f,0.f,0.f);
    aggh_edges(beg + wave*64, end, 256, erec, ps0n, pd0, prs0, ps1n, pd1, prs1,
               XSD, ldx, RRb, ldr, lane, Sl0, Sl1, acc);
    float Sw0 = Sl0, Sw1 = Sl1;
    #pragma unroll
    for (int o = 32; o; o >>= 1){ Sw0 += __shfl_xor(Sw0, o, 64); Sw1 += __shfl_xor(Sw1, o, 64); }
    redA[threadIdx.x] = acc;
    if (lane == 0){ redS0[wave] = Sw0; redS1[wave] = Sw1; }
    __syncthreads();
    if (wave == 0){
      float4 a0 = redA[lane], a1 = redA[lane+64], a2 = redA[lane+128], a3 = redA[lane+192];
      float4 at = make_float4(a0.x+a1.x+a2.x+a3.x, a0.y+a1.y+a2.y+a3.y,
                              a0.z+a1.z+a2.z+a3.z, a0.w+a1.w+a2.w+a3.w);
      float St0 = redS0[0] + redS0[1] + redS0[2] + redS0[3];
      float St1 = redS1[0] + redS1[1] + redS1[2] + redS1[3];
      aggh_finalize(n, St0, St1, at, lane, XSD, ldx, outb, ldb);
    }
  } else {
    int n = HOTN + (bid - HOTN)*4 + wave;
    int beg = rowofs[n], end = rowofs[n+1];
    float ps0n = ps0[n], ps1n = ps1[n];
    float Sl0 = 0.f, Sl1 = 0.f;
    float4 acc = make_float4(0.f,0.f,0.f,0.f);
    aggh_edges(beg, end, 64, erec, ps0n, pd0, prs0, ps1n, pd1, prs1,
               XSD, ldx, RRb, ldr, lane, Sl0, Sl1, acc);
    float S0 = Sl0, S1 = Sl1;
    #pragma unroll
    for (int o = 32; o; o >>= 1){ S0 += __shfl_xor(S0, o, 64); S1 += __shfl_xor(S1, o, 64); }
    aggh_finalize(n, S0, S1, acc, lane, XSD, ldx, outb, ldb);
  }
}

// ---------------------------------------------------------------- driver
extern "C" void kernel_launch(void* const* d_in, const int* in_sizes, int n_in,
                              void* d_out, int out_size, void* d_ws, size_t ws_size,
                              hipStream_t stream) {
  const float* entity   = (const float*)d_in[0];
  const float* relation = (const float*)d_in[1];
  const float* W_ent    = (const float*)d_in[2];
  const float* g0_a0    = (const float*)d_in[3];
  const float* g0_s0    = (const float*)d_in[4];
  const float* g0_a1    = (const float*)d_in[5];
  const float* g0_s1    = (const float*)d_in[6];
  const float* g0_W     = (const float*)d_in[7];
  const float* g0_oa    = (const float*)d_in[8];
  const float* g0_os    = (const float*)d_in[9];
  const float* g1_a0    = (const float*)d_in[10];
  const float* g1_s0    = (const float*)d_in[11];
  const float* g1_W     = (const float*)d_in[12];
  const float* g1_oa    = (const float*)d_in[13];
  const float* g1_os    = (const float*)d_in[14];
  const int*   el       = (const int*)d_in[15];
  const int*   et       = (const int*)d_in[16];
  const int*   nh       = (const int*)d_in[17];
  const int*   batch    = (const int*)d_in[18];
  (void)in_sizes; (void)n_in; (void)out_size; (void)ws_size;

  char* w = (char*)d_ws;
  auto alloc = [&](size_t bytes)->char*{ char* p = w; w += (bytes + 255) & ~(size_t)255; return p; };
  float* ENTUP = (float*)alloc((size_t)MP*200*4);
  float* ENT1  = (float*)alloc((size_t)NNODES*200*4);
  float* XSF   = (float*)alloc((size_t)MP*200*4);
  float* RELUP = (float*)alloc((size_t)RPAD*200*4);
  float* REL1  = (float*)alloc((size_t)NRELS*200*4);
  float* OR0   = (float*)alloc((size_t)RPAD*200*4);
  float* OR1   = (float*)alloc((size_t)RPAD*200*4);
  float* PS0   = (float*)alloc((size_t)NNODES*4);
  float* PD0   = (float*)alloc((size_t)NNODES*4);
  float* PS1   = (float*)alloc((size_t)NNODES*4);
  float* PD1   = (float*)alloc((size_t)NNODES*4);
  float* PRS0  = (float*)alloc((size_t)(NRELS+4)*4);
  float* PRS1  = (float*)alloc((size_t)(NRELS+4)*4);
  __hip_bfloat16* AENT0 = (__hip_bfloat16*)alloc((size_t)MP*128*2);
  __hip_bfloat16* AX1   = (__hip_bfloat16*)alloc((size_t)MP*224*2);
  __hip_bfloat16* AENT1 = (__hip_bfloat16*)alloc((size_t)MP*224*2);
  __hip_bfloat16* AREL0 = (__hip_bfloat16*)alloc((size_t)RPAD*128*2);
  __hip_bfloat16* AREL1 = (__hip_bfloat16*)alloc((size_t)RPAD*224*2);
  __hip_bfloat16* AOR   = (__hip_bfloat16*)alloc((size_t)RPAD*224*2);
  __hip_bfloat16* XSD   = (__hip_bfloat16*)alloc((size_t)MP*512*2);
  __hip_bfloat16* RRb   = (__hip_bfloat16*)alloc((size_t)RPAD*256*2);
  __hip_bfloat16* WA    = (__hip_bfloat16*)alloc((size_t)737280*2);
  int* IALL = (int*)alloc((size_t)150001*4);
  int* ROWOFS = IALL;
  int* CUR    = IALL + 50001;
  float* MASK = (float*)(IALL + 100001);
  int4* EREC  = (int4*)alloc((size_t)NETOT*16);
  int* PART   = (int*)alloc((size_t)256*4);

  const __hip_bfloat16* WET   = WA;
  const __hip_bfloat16* G0WT  = WA + 32768;
  const __hip_bfloat16* BH0   = WA + 65536;
  const __hip_bfloat16* BR0   = WA + 131072;
  const __hip_bfloat16* BO0   = WA + 163840;
  const __hip_bfloat16* BO0r  = WA + 278528;
  const __hip_bfloat16* BA1   = WA + 335872;
  const __hip_bfloat16* BA1r  = WA + 450560;
  const __hip_bfloat16* G1WT  = WA + 507904;
  const __hip_bfloat16* BO1   = WA + 565248;
  const __hip_bfloat16* BO1r  = WA + 679936;

  float* outEnt = (float*)d_out;
  float* outRel = outEnt + (size_t)NNODES*200;

  const int TB = 256;
  auto gb = [&](long long n){ return (int)((n + TB - 1)/TB); };
  const int AGG_GRID = HOTN + (NNODES - HOTN)/4;

  // ---- preprocessing ----
  k_zero<<<gb(150001), TB, 0, stream>>>(IALL, 150001);
  k_zero<<<gb((RPAD*128 + RPAD*224)/2), TB, 0, stream>>>((int*)AREL0, (RPAD*128 + RPAD*224)/2);
  k_mask_set<<<gb(10000), TB, 0, stream>>>(batch, MASK, 10000);
  k_hist<<<gb(NETOT), TB, 0, stream>>>(el, nh, ROWOFS);
  int nsb = (NNODES + 255)/256;
  k_scan1<<<nsb, 256, 0, stream>>>(ROWOFS, NNODES, PART);
  k_scan2<<<1, 256, 0, stream>>>(PART, nsb);
  k_scan3<<<nsb, 256, 0, stream>>>(ROWOFS, NNODES, PART);
  k_scatter<<<gb(NETOT), TB, 0, stream>>>(el, et, nh, ROWOFS, CUR, EREC);
  k_padcols<<<gb((long long)MP*24), TB, 0, stream>>>(AX1, MP, 200, 224);

  // ---- inputs -> bf16 arenas; weights -> bf16 arena ----
  k_l2norm_bf<100,128><<<NNODES, 64, 0, stream>>>(entity, AENT0);
  k_l2norm_bf<100,128><<<NRELS, 64, 0, stream>>>(relation, AREL0);
  {
    Ptr8 srcs;
    srcs.p[0] = W_ent; srcs.p[1] = g0_a0; srcs.p[2] = g0_a1; srcs.p[3] = g0_W;
    srcs.p[4] = g0_oa; srcs.p[5] = g1_a0; srcs.p[6] = g1_W;  srcs.p[7] = g1_oa;
    dim3 g(448, 18);
    k_wconv<<<g, 256, 0, stream>>>(srcs, WA);
  }

  auto gemm_f = [&](const __hip_bfloat16* A, const __hip_bfloat16* B, float* C, int M, int Nn, int Kp, int ldc){
    dim3 g((Nn + 63)/64, (M + 127)/128);
    k_gemm_mfma<float><<<g, 256, 0, stream>>>(A, B, C, M, Nn, Kp, ldc);
  };
  auto gemm_b = [&](const __hip_bfloat16* A, const __hip_bfloat16* B, __hip_bfloat16* C, int M, int Nn, int Kp, int ldc){
    dim3 g((Nn + 63)/64, (M + 127)/128);
    k_gemm_mfma<__hip_bfloat16><<<g, 256, 0, stream>>>(A, B, C, M, Nn, Kp, ldc);
  };

  // ---- ent_up / rel_up ----
  gemm_f(AENT0, WET, ENTUP, MP, 200, 128, 200);
  gemm_f(AREL0, WET, RELUP, RPAD, 200, 128, 200);

  // ---- layer0 heads: mega GEMMs + fused aggregation ----
  gemm_b(AENT0, BH0, XSD, MP, 512, 128, 512);
  gemm_b(AREL0, BR0, RRb, RPAD, 256, 128, 256);
  k_rowdot2<<<(NNODES + 3)/4, 256, 0, stream>>>(XSD, NNODES, 512, 0, 128, 100, g0_s0, PS0, PD0);
  k_rowdot2<<<(NNODES + 3)/4, 256, 0, stream>>>(XSD, NNODES, 512, 256, 384, 100, g0_s1, PS1, PD1);
  k_rowdot2<<<(NRELS + 4)/4, 256, 0, stream>>>(RRb, NRELS+1, 256, 0, -1, 100, g0_s0, PRS0, nullptr);
  k_rowdot2<<<(NRELS + 4)/4, 256, 0, stream>>>(RRb, NRELS+1, 256, 128, -1, 100, g0_s1, PRS1, nullptr);
  k_aggh<<<AGG_GRID, 256, 0, stream>>>(ROWOFS, EREC, PS0, PD0, PRS0, PS1, PD1, PRS1,
      XSD, 512, RRb, 256, AX1, 224);

  // ---- layer0 out-attention ----
  gemm_f(AREL0, G0WT, OR0, RPAD, 200, 128, 200);
  k_w2bf_nt<<<gb((long long)RPAD*224), TB, 0, stream>>>(OR0, 200, NRELS, 200, AOR, 224, RPAD);
  gemm_b(AX1, BO0, XSD, MP, 512, 224, 512);
  gemm_b(AOR, BO0r, RRb, RPAD, 256, 224, 256);
  k_rowdot2<<<(NNODES + 3)/4, 256, 0, stream>>>(XSD, NNODES, 512, 0, 256, 200, g0_os, PS0, PD0);
  k_rowdot2<<<(NRELS + 4)/4, 256, 0, stream>>>(RRb, NRELS+1, 256, 0, -1, 200, g0_os, PRS0, nullptr);
  k_agg5<true><<<AGG_GRID, 256, 0, stream>>>(ROWOFS, EREC, PS0, PD0, PRS0,
      XSD, 512, 0, 256, RRb, 256, 0, XSF, nullptr, 0, 0);
  k_combine_norm<200,224><<<NNODES, 64, 0, stream>>>(ENTUP, XSF, MASK, ENT1, AENT1);
  k_combine_norm<200,224><<<NRELS, 64, 0, stream>>>(RELUP, OR0, nullptr, REL1, AREL1);

  // ---- layer1 head ----
  gemm_b(AENT1, BA1, XSD, MP, 512, 224, 512);
  gemm_b(AREL1, BA1r, RRb, RPAD, 256, 224, 256);
  k_rowdot2<<<(NNODES + 3)/4, 256, 0, stream>>>(XSD, NNODES, 512, 0, 256, 200, g1_s0, PS0, PD0);
  k_rowdot2<<<(NRELS + 4)/4, 256, 0, stream>>>(RRb, NRELS+1, 256, 0, -1, 200, g1_s0, PRS0, nullptr);
  k_agg5<false><<<AGG_GRID, 256, 0, stream>>>(ROWOFS, EREC, PS0, PD0, PRS0,
      XSD, 512, 0, 256, RRb, 256, 0, nullptr, AX1, 224, 0);

  // ---- layer1 out-attention ----
  gemm_f(AREL1, G1WT, OR1, RPAD, 200, 224, 200);
  k_w2bf_nt<<<gb((long long)RPAD*224), TB, 0, stream>>>(OR1, 200, NRELS, 200, AOR, 224, RPAD);
  gemm_b(AX1, BO1, XSD, MP, 512, 224, 512);
  gemm_b(AOR, BO1r, RRb, RPAD, 256, 224, 256);
  k_rowdot2<<<(NNODES + 3)/4, 256, 0, stream>>>(XSD, NNODES, 512, 0, 256, 200, g1_os, PS0, PD0);
  k_rowdot2<<<(NRELS + 4)/4, 256, 0, stream>>>(RRb, NRELS+1, 256, 0, -1, 200, g1_os, PRS0, nullptr);
  k_agg5<true><<<AGG_GRID, 256, 0, stream>>>(ROWOFS, EREC, PS0, PD0, PRS0,
      XSD, 512, 0, 256, RRb, 256, 0, XSF, nullptr, 0, 0);

  // ---- final combines -> d_out ----
  k_combine_norm<200,224><<<NNODES, 64, 0, stream>>>(ENT1, XSF, MASK, outEnt, nullptr);
  k_combine_norm<200,224><<<NRELS, 64, 0, stream>>>(REL1, OR1, nullptr, outRel, nullptr);
}

// Round 7
// 634.904 us; speedup vs baseline: 5.7761x; 1.2342x over previous
//
#include <hip/hip_runtime.h>
#include <hip/hip_bf16.h>
#include <cstdint>
#include <cstddef>

#define NNODES 50000
#define NRELS  500
#define NEDGE  500000
#define NETOT  600000
#define MP     50048
#define RPAD   512
#define HOTN   512

typedef __attribute__((ext_vector_type(8))) short bf16x8;
typedef __attribute__((ext_vector_type(4))) float f32x4;

__device__ inline float bf2f(unsigned short s){
  union { unsigned u; float f; } v; v.u = ((unsigned)s) << 16; return v.f;
}
__device__ inline unsigned short f2bf(float f){
  __hip_bfloat16 h = __float2bfloat16(f);
  return __builtin_bit_cast(unsigned short, h);
}

// ---------------------------------------------------------------- utilities
__global__ void k_zero(int* __restrict__ p, int n){
  int i = blockIdx.x*blockDim.x + threadIdx.x;
  if (i < n) p[i] = 0;
}
__global__ void k_mask_set(const int* __restrict__ batch, float* __restrict__ mask, int nb){
  int i = blockIdx.x*blockDim.x + threadIdx.x;
  if (i < nb) mask[batch[3*i+2]] = 1.0f;
}
__global__ void k_padcols(__hip_bfloat16* __restrict__ dst, int Mpad, int K, int Kp){
  int padw = Kp - K;
  long long i = (long long)blockIdx.x*blockDim.x + threadIdx.x;
  if (i >= (long long)Mpad*padw) return;
  int r = (int)(i / padw), k = K + (int)(i - (long long)r*padw);
  dst[(size_t)r*Kp + k] = __float2bfloat16(0.f);
}

// ---------------------------------------------------------------- edge CSR
__global__ void k_hist(const int* __restrict__ el, const int* __restrict__ nh, int* __restrict__ deg){
  int e = blockIdx.x*blockDim.x + threadIdx.x;
  if (e >= NETOT) return;
  int s = (e < NEDGE) ? el[e] : nh[4*(e-NEDGE)+3];
  atomicAdd(&deg[s], 1);
}
__global__ void k_scan1(int* __restrict__ data, int n, int* __restrict__ part){
  __shared__ int sh[256];
  int t = threadIdx.x, i = blockIdx.x*256 + t;
  int v = (i < n) ? data[i] : 0;
  sh[t] = v; __syncthreads();
  for (int o = 1; o < 256; o <<= 1){
    int x = (t >= o) ? sh[t-o] : 0;
    __syncthreads(); sh[t] += x; __syncthreads();
  }
  if (i < n) data[i] = sh[t] - v;
  if (t == 255) part[blockIdx.x] = sh[255];
}
__global__ void k_scan2(int* __restrict__ part, int nb){
  __shared__ int sh[256];
  int t = threadIdx.x;
  int v = (t < nb) ? part[t] : 0;
  sh[t] = v; __syncthreads();
  for (int o = 1; o < 256; o <<= 1){
    int x = (t >= o) ? sh[t-o] : 0;
    __syncthreads(); sh[t] += x; __syncthreads();
  }
  if (t < nb) part[t] = sh[t] - v;
}
__global__ void k_scan3(int* __restrict__ data, int n, const int* __restrict__ part){
  int i = blockIdx.x*256 + threadIdx.x;
  if (i < n) data[i] += part[blockIdx.x];
  if (i == 0) data[n] = NETOT;
}
__global__ void k_scatter(const int* __restrict__ el, const int* __restrict__ et,
                          const int* __restrict__ nh, const int* __restrict__ rowofs,
                          int* __restrict__ cur, int4* __restrict__ erec){
  int e = blockIdx.x*blockDim.x + threadIdx.x;
  if (e >= NETOT) return;
  int s, d, t0, t1;
  if (e < NEDGE){ s = el[e]; d = el[NEDGE+e]; t0 = et[e]; t1 = NRELS; }
  else { int i = e - NEDGE; s = nh[4*i+3]; d = nh[4*i+0]; t0 = nh[4*i+1]; t1 = nh[4*i+2]; }
  int p = rowofs[s] + atomicAdd(&cur[s], 1);
  erec[p] = make_int4(d, t0, t1, 0);
}

// ---------------------------------------------------------------- l2norm -> bf16
template<int D, int KP>
__global__ __launch_bounds__(64) void k_l2norm_bf(const float* __restrict__ in,
                                                  __hip_bfloat16* __restrict__ bfout){
  constexpr int NK = KP/64;
  int n = blockIdx.x, lane = threadIdx.x;
  const float* row = in + (size_t)n*D;
  float v[NK]; float ss = 0.f;
  #pragma unroll
  for (int k = 0; k < NK; k++){ int c = lane + 64*k; v[k] = (c < D) ? row[c] : 0.f; ss += v[k]*v[k]; }
  #pragma unroll
  for (int o = 32; o; o >>= 1) ss += __shfl_xor(ss, o, 64);
  float sc = 1.0f / fmaxf(sqrtf(ss), 1e-12f);
  __hip_bfloat16* orow = bfout + (size_t)n*KP;
  #pragma unroll
  for (int k = 0; k < NK; k++){ int c = lane + 64*k; orow[c] = __float2bfloat16(v[k]*sc); }
}

// ---------------------------------------------------------------- fused combine: l2norm(base + m*h)
// grid = NNODES + NRELS; bf16 inputs (ld 224); FINAL -> fp32 out (ld 200), else bf16 out (ld 224, pad 0)
template<bool FINAL>
__global__ __launch_bounds__(64) void k_combine2(
    const __hip_bfloat16* __restrict__ baseE, const __hip_bfloat16* __restrict__ hE,
    const float* __restrict__ mask,
    const __hip_bfloat16* __restrict__ baseR, const __hip_bfloat16* __restrict__ hR,
    float* __restrict__ outfE, float* __restrict__ outfR,
    __hip_bfloat16* __restrict__ outbE, __hip_bfloat16* __restrict__ outbR)
{
  int n = blockIdx.x, lane = threadIdx.x;
  bool isE = n < NNODES;
  int row = isE ? n : n - NNODES;
  const __hip_bfloat16* b = (isE ? baseE : baseR) + (size_t)row*224;
  const __hip_bfloat16* h = (isE ? hE : hR) + (size_t)row*224;
  float m = isE ? mask[row] : 1.0f;
  int c = lane*4;
  float4 v = make_float4(0.f,0.f,0.f,0.f);
  if (c < 200){
    ushort4 bb = *(const ushort4*)(b + c);
    ushort4 hh = *(const ushort4*)(h + c);
    v.x = bf2f(bb.x) + m*bf2f(hh.x);
    v.y = bf2f(bb.y) + m*bf2f(hh.y);
    v.z = bf2f(bb.z) + m*bf2f(hh.z);
    v.w = bf2f(bb.w) + m*bf2f(hh.w);
  }
  float ss = v.x*v.x + v.y*v.y + v.z*v.z + v.w*v.w;
  #pragma unroll
  for (int o = 32; o; o >>= 1) ss += __shfl_xor(ss, o, 64);
  float sc = 1.0f / fmaxf(sqrtf(ss), 1e-12f);
  if constexpr (FINAL){
    if (c < 200){
      float* o = (isE ? outfE : outfR) + (size_t)row*200 + c;
      *(float4*)o = make_float4(v.x*sc, v.y*sc, v.z*sc, v.w*sc);
    }
  } else {
    if (c < 224){
      __hip_bfloat16* o = (isE ? outbE : outbR) + (size_t)row*224 + c;
      ushort4 w4; w4.x = f2bf(v.x*sc); w4.y = f2bf(v.y*sc); w4.z = f2bf(v.z*sc); w4.w = f2bf(v.w*sc);
      *(ushort4*)o = w4;
    }
  }
}

// ---------------------------------------------------------------- weight tables for rowdot
// WT layout: TA[512]@0 (layer0 node), TB[256]@512 (layer0 rel), TC[512]@768 (g0_os),
//            TD[512]@1280 (g1_s0), TE[512]@1792 (g1_os)
__global__ void k_wtab(const float* __restrict__ s0h, const float* __restrict__ s1h,
                       const float* __restrict__ os0, const float* __restrict__ s1l,
                       const float* __restrict__ os1, float* __restrict__ WT){
  int i = blockIdx.x*256 + threadIdx.x;
  if (i >= 2304) return;
  float v = 0.f;
  if (i < 512){
    int c = i & 127;
    const float* s = (i < 256) ? s0h : s1h;
    if (c < 100) v = s[c];
  } else if (i < 768){
    int j = i - 512, c = j & 127;
    const float* s = (j < 128) ? s0h : s1h;
    if (c < 100) v = s[c];
  } else {
    int j = i - 768, t = j >> 9, c = j & 255;
    const float* s = (t == 0) ? os0 : (t == 1) ? s1l : os1;
    if (c < 200) v = s[c];
  }
  WT[i] = v;
}

// weighted segmented rowdot: row of 64*EPL bf16 cols, dot with wt, reduce per 16*GPO lane group
template<int EPL, int GPO>
__global__ __launch_bounds__(256) void k_rowdotW(const __hip_bfloat16* __restrict__ X, int ld, int M,
    const float* __restrict__ wt,
    float* __restrict__ o0, float* __restrict__ o1, float* __restrict__ o2, float* __restrict__ o3){
  int wave = threadIdx.x >> 6, lane = threadIdx.x & 63;
  int row = blockIdx.x*4 + wave;
  if (row >= M) return;
  int c0 = lane*EPL;
  const __hip_bfloat16* xr = X + (size_t)row*ld + c0;
  float p = 0.f;
  #pragma unroll
  for (int k = 0; k < EPL/4; k++){
    ushort4 x = *(const ushort4*)(xr + 4*k);
    float4 a = *(const float4*)(wt + c0 + 4*k);
    p += bf2f(x.x)*a.x + bf2f(x.y)*a.y + bf2f(x.z)*a.z + bf2f(x.w)*a.w;
  }
  constexpr int G = 16*GPO;
  #pragma unroll
  for (int o = G/2; o; o >>= 1) p += __shfl_xor(p, o, 64);
  if ((lane & (G-1)) == 0){
    int g = lane / G;
    float* o = (g == 0) ? o0 : (g == 1) ? o1 : (g == 2) ? o2 : o3;
    o[row] = p;
  }
}

// ---------------------------------------------------------------- mega weight->bf16 conversion
struct WEnt { int src, ld, boff, rows, K, tr, dstoff, Kp, rp; };
__device__ const WEnt g_went[18] = {
  {0,200,0,200,100,1,      0,128,256},
  {3,200,0,200,100,1,  32768,128,256},
  {1,300,  0,100,100,0,  65536,128,128},
  {1,300,100,100,100,0,  81920,128,128},
  {2,300,  0,100,100,0,  98304,128,128},
  {2,300,100,100,100,0, 114688,128,128},
  {1,300,200,100,100,0, 131072,128,128},
  {2,300,200,100,100,0, 147456,128,128},
  {4,600,  0,200,200,0, 163840,224,256},
  {4,600,200,200,200,0, 221184,224,256},
  {4,600,400,200,200,0, 278528,224,256},
  {5,600,  0,200,200,0, 335872,224,256},
  {5,600,200,200,200,0, 393216,224,256},
  {5,600,400,200,200,0, 450560,224,256},
  {6,200,0,200,200,1,   507904,224,256},
  {7,600,  0,200,200,0, 565248,224,256},
  {7,600,200,200,200,0, 622592,224,256},
  {7,600,400,200,200,0, 679936,224,256},
};
struct Ptr8 { const float* p[8]; };
__global__ void k_wconv(Ptr8 srcs, __hip_bfloat16* __restrict__ dst){
  WEnt e = g_went[blockIdx.y];
  int i = blockIdx.x*256 + threadIdx.x;
  if (i >= e.rp*e.Kp) return;
  int r = i / e.Kp, k = i - r*e.Kp;
  float v = 0.f;
  if (r < e.rows && k < e.K)
    v = e.tr ? srcs.p[e.src][(size_t)k*e.ld + r] : srcs.p[e.src][(size_t)r*e.ld + e.boff + k];
  dst[e.dstoff + i] = __float2bfloat16(v);
}

// ---------------------------------------------------------------- bf16 MFMA GEMM (NT), bf16 C out
__global__ __launch_bounds__(256) void k_gemm_mfma(
    const __hip_bfloat16* __restrict__ A, const __hip_bfloat16* __restrict__ B,
    __hip_bfloat16* __restrict__ C, int M, int Nn, int Kp, int ldc)
{
  __shared__ __hip_bfloat16 As[128*32];
  __shared__ __hip_bfloat16 Bs[64*32];
  const int tid = threadIdx.x;
  const int wave = tid >> 6, lane = tid & 63;
  const int lg = lane >> 4, li = lane & 15;
  // bijective XCD-chunk swizzle (L2 locality for same-row blocks)
  int nwg = gridDim.x * gridDim.y;
  int bidl = blockIdx.y * gridDim.x + blockIdx.x;
  if ((nwg & 7) == 0){
    int q = nwg >> 3;
    bidl = (bidl & 7) * q + (bidl >> 3);
  }
  const int bx = bidl % gridDim.x, by = bidl / gridDim.x;
  const int m0 = by * 128, n0 = bx * 64;
  const int wr = wave >> 1, wc = wave & 1;
  f32x4 acc[4][2] = {};

  const int ar0 = tid >> 2;
  const int ar1 = (tid + 256) >> 2;
  const int ap  = tid & 3;
  const char* Ab = (const char*)A;
  const char* Bb = (const char*)B;
  char* asB = (char*)As;
  char* bsB = (char*)Bs;

  for (int kk = 0; kk < Kp; kk += 32){
    {
      int g0 = ap ^ ((ar0 >> 1) & 3);
      const char* s0 = Ab + ((size_t)(m0 + ar0)*Kp + kk)*2 + g0*16;
      __builtin_amdgcn_global_load_lds((const __attribute__((address_space(1))) void*)s0,
          (__attribute__((address_space(3))) void*)(asB + wave*1024), 16, 0, 0);
      int g1 = ap ^ ((ar1 >> 1) & 3);
      const char* s1 = Ab + ((size_t)(m0 + ar1)*Kp + kk)*2 + g1*16;
      __builtin_amdgcn_global_load_lds((const __attribute__((address_space(1))) void*)s1,
          (__attribute__((address_space(3))) void*)(asB + 4096 + wave*1024), 16, 0, 0);
      int gb = ap ^ ((ar0 >> 1) & 3);
      const char* sb = Bb + ((size_t)(n0 + ar0)*Kp + kk)*2 + gb*16;
      __builtin_amdgcn_global_load_lds((const __attribute__((address_space(1))) void*)sb,
          (__attribute__((address_space(3))) void*)(bsB + wave*1024), 16, 0, 0);
    }
    __syncthreads();
    bf16x8 av[4], bv[2];
    #pragma unroll
    for (int mf = 0; mf < 4; mf++){
      int row = wr*64 + mf*16 + li;
      int p = lg ^ ((row >> 1) & 3);
      av[mf] = *(const bf16x8*)(asB + row*64 + p*16);
    }
    #pragma unroll
    for (int nf = 0; nf < 2; nf++){
      int row = wc*32 + nf*16 + li;
      int p = lg ^ ((row >> 1) & 3);
      bv[nf] = *(const bf16x8*)(bsB + row*64 + p*16);
    }
    #pragma unroll
    for (int mf = 0; mf < 4; mf++)
      #pragma unroll
      for (int nf = 0; nf < 2; nf++)
        acc[mf][nf] = __builtin_amdgcn_mfma_f32_16x16x32_bf16(av[mf], bv[nf], acc[mf][nf], 0, 0, 0);
    __syncthreads();
  }
  #pragma unroll
  for (int mf = 0; mf < 4; mf++){
    #pragma unroll
    for (int nf = 0; nf < 2; nf++){
      int gc = n0 + wc*32 + nf*16 + li;
      if (gc >= Nn) continue;
      int gr0 = m0 + wr*64 + mf*16 + lg*4;
      #pragma unroll
      for (int r = 0; r < 4; r++){
        int gr = gr0 + r;
        if (gr < M) C[(size_t)gr*ldc + gc] = __float2bfloat16(acc[mf][nf][r]);
      }
    }
  }
}

// ---------------------------------------------------------------- aggregation (D=200), dual-edge ILP
__device__ inline void agg5_edges(int bstart, int end, int bstep,
    const int4* __restrict__ erec, float psn,
    const float* __restrict__ pd, const float* __restrict__ prs,
    const __hip_bfloat16* __restrict__ XSD, int ldx, int cxd,
    const __hip_bfloat16* __restrict__ RRb, int ldr, int crr,
    int lane, float& Sl, float4& accO)
{
  bool act = lane < 50;
  const __hip_bfloat16* xb = XSD + cxd + 4*lane;
  const __hip_bfloat16* rb = RRb + crr + 4*lane;
  float4 accA = make_float4(0.f,0.f,0.f,0.f);
  float4 accB = make_float4(0.f,0.f,0.f,0.f);
  for (int b = bstart; b < end; b += bstep){
    int j = b + lane;
    int4 e = make_int4(0, NRELS, NRELS, 0);
    float wv = 0.f;
    if (j < end){
      e = erec[j];
      float lg = psn + pd[e.x] + prs[e.y] + prs[e.z];
      wv = __expf(-((lg > 0.f) ? lg : 0.2f*lg));
    }
    Sl += wv;
    int m = end - b; if (m > 64) m = 64;
    int i = 0;
    for (; i + 1 < m; i += 2){
      float wA = __shfl(wv, i),   wB = __shfl(wv, i+1);
      int dA = __shfl(e.x, i),   tA0 = __shfl(e.y, i),   tA1 = __shfl(e.z, i);
      int dB = __shfl(e.x, i+1), tB0 = __shfl(e.y, i+1), tB1 = __shfl(e.z, i+1);
      if (act){
        ushort4 xA = *(const ushort4*)(xb + (size_t)dA*ldx);
        ushort4 rA = *(const ushort4*)(rb + (size_t)tA0*ldr);
        ushort4 xB = *(const ushort4*)(xb + (size_t)dB*ldx);
        ushort4 rB = *(const ushort4*)(rb + (size_t)tB0*ldr);
        float ax = bf2f(xA.x)+bf2f(rA.x), ay = bf2f(xA.y)+bf2f(rA.y);
        float az = bf2f(xA.z)+bf2f(rA.z), aw = bf2f(xA.w)+bf2f(rA.w);
        if (tA1 != NRELS){
          ushort4 rc = *(const ushort4*)(rb + (size_t)tA1*ldr);
          ax += bf2f(rc.x); ay += bf2f(rc.y); az += bf2f(rc.z); aw += bf2f(rc.w);
        }
        float bx = bf2f(xB.x)+bf2f(rB.x), by = bf2f(xB.y)+bf2f(rB.y);
        float bz = bf2f(xB.z)+bf2f(rB.z), bw = bf2f(xB.w)+bf2f(rB.w);
        if (tB1 != NRELS){
          ushort4 rc = *(const ushort4*)(rb + (size_t)tB1*ldr);
          bx += bf2f(rc.x); by += bf2f(rc.y); bz += bf2f(rc.z); bw += bf2f(rc.w);
        }
        accA.x += wA*ax; accA.y += wA*ay; accA.z += wA*az; accA.w += wA*aw;
        accB.x += wB*bx; accB.y += wB*by; accB.z += wB*bz; accB.w += wB*bw;
      }
    }
    if (i < m){
      float wA = __shfl(wv, i);
      int dA = __shfl(e.x, i), tA0 = __shfl(e.y, i), tA1 = __shfl(e.z, i);
      if (act){
        ushort4 xA = *(const ushort4*)(xb + (size_t)dA*ldx);
        ushort4 rA = *(const ushort4*)(rb + (size_t)tA0*ldr);
        float ax = bf2f(xA.x)+bf2f(rA.x), ay = bf2f(xA.y)+bf2f(rA.y);
        float az = bf2f(xA.z)+bf2f(rA.z), aw = bf2f(xA.w)+bf2f(rA.w);
        if (tA1 != NRELS){
          ushort4 rc = *(const ushort4*)(rb + (size_t)tA1*ldr);
          ax += bf2f(rc.x); ay += bf2f(rc.y); az += bf2f(rc.z); aw += bf2f(rc.w);
        }
        accA.x += wA*ax; accA.y += wA*ay; accA.z += wA*az; accA.w += wA*aw;
      }
    }
  }
  accO.x += accA.x + accB.x; accO.y += accA.y + accB.y;
  accO.z += accA.z + accB.z; accO.w += accA.w + accB.w;
}

__device__ inline void agg5_finalize(int n, float S, float4 acc, int lane,
    const __hip_bfloat16* __restrict__ XSD, int ldx, int cxs,
    __hip_bfloat16* __restrict__ outb, int ldb, int coffb)
{
  if (lane >= 50) return;
  float inv = (S > 0.f) ? 1.0f/S : 0.f;
  ushort4 xs4 = *(const ushort4*)(XSD + (size_t)n*ldx + cxs + 4*lane);
  float h0 = (S > 0.f) ? bf2f(xs4.x) + acc.x*inv : 0.f;
  float h1 = (S > 0.f) ? bf2f(xs4.y) + acc.y*inv : 0.f;
  float h2 = (S > 0.f) ? bf2f(xs4.z) + acc.z*inv : 0.f;
  float h3 = (S > 0.f) ? bf2f(xs4.w) + acc.w*inv : 0.f;
  h0 = (h0 > 0.f) ? h0 : expm1f(h0);
  h1 = (h1 > 0.f) ? h1 : expm1f(h1);
  h2 = (h2 > 0.f) ? h2 : expm1f(h2);
  h3 = (h3 > 0.f) ? h3 : expm1f(h3);
  ushort4 o; o.x = f2bf(h0); o.y = f2bf(h1); o.z = f2bf(h2); o.w = f2bf(h3);
  *(ushort4*)(outb + (size_t)n*ldb + coffb + 4*lane) = o;
}

__global__ __launch_bounds__(256) void k_agg5(
    const int* __restrict__ rowofs, const int4* __restrict__ erec,
    const float* __restrict__ ps, const float* __restrict__ pd, const float* __restrict__ prs,
    const __hip_bfloat16* __restrict__ XSD, int ldx, int cxs, int cxd,
    const __hip_bfloat16* __restrict__ RRb, int ldr, int crr,
    __hip_bfloat16* __restrict__ outb, int ldb, int coffb)
{
  __shared__ float4 redA[256];
  __shared__ float redS[4];
  int bid = blockIdx.x;
  int wave = threadIdx.x >> 6, lane = threadIdx.x & 63;

  if (bid < HOTN){
    int n = bid;
    int beg = rowofs[n], end = rowofs[n+1];
    float psn = ps[n];
    float Sl = 0.f;
    float4 acc = make_float4(0.f,0.f,0.f,0.f);
    agg5_edges(beg + wave*64, end, 256, erec, psn, pd, prs,
               XSD, ldx, cxd, RRb, ldr, crr, lane, Sl, acc);
    float Sw = Sl;
    #pragma unroll
    for (int o = 32; o; o >>= 1) Sw += __shfl_xor(Sw, o, 64);
    redA[threadIdx.x] = acc;
    if (lane == 0) redS[wave] = Sw;
    __syncthreads();
    if (wave == 0){
      float4 a0 = redA[lane], a1 = redA[lane+64], a2 = redA[lane+128], a3 = redA[lane+192];
      float4 at = make_float4(a0.x+a1.x+a2.x+a3.x, a0.y+a1.y+a2.y+a3.y,
                              a0.z+a1.z+a2.z+a3.z, a0.w+a1.w+a2.w+a3.w);
      float St = redS[0] + redS[1] + redS[2] + redS[3];
      agg5_finalize(n, St, at, lane, XSD, ldx, cxs, outb, ldb, coffb);
    }
  } else {
    int n = HOTN + (bid - HOTN)*4 + wave;
    int beg = rowofs[n], end = rowofs[n+1];
    float psn = ps[n];
    float Sl = 0.f;
    float4 acc = make_float4(0.f,0.f,0.f,0.f);
    agg5_edges(beg, end, 64, erec, psn, pd, prs,
               XSD, ldx, cxd, RRb, ldr, crr, lane, Sl, acc);
    float S = Sl;
    #pragma unroll
    for (int o = 32; o; o >>= 1) S += __shfl_xor(S, o, 64);
    agg5_finalize(n, S, acc, lane, XSD, ldx, cxs, outb, ldb, coffb);
  }
}

// ---------------------------------------------------------------- fused layer0-heads aggregation
__device__ inline void aggh_edges(int bstart, int end, int bstep,
    const int4* __restrict__ erec,
    float ps0n, const float* __restrict__ pd0, const float* __restrict__ prs0,
    float ps1n, const float* __restrict__ pd1, const float* __restrict__ prs1,
    const __hip_bfloat16* __restrict__ XSD, int ldx,
    const __hip_bfloat16* __restrict__ RRb, int ldr,
    int lane, float& Sl0, float& Sl1, float4& accO)
{
  bool act = lane < 50;
  int head = (lane >= 25) ? 1 : 0;
  int li = lane - 25*head;
  const __hip_bfloat16* xb = XSD + (head ? 384 : 128) + 4*li;
  const __hip_bfloat16* rb = RRb + (head ? 128 : 0) + 4*li;
  float4 accA = make_float4(0.f,0.f,0.f,0.f);
  float4 accB = make_float4(0.f,0.f,0.f,0.f);
  for (int b = bstart; b < end; b += bstep){
    int j = b + lane;
    int4 e = make_int4(0, NRELS, NRELS, 0);
    float wv0 = 0.f, wv1 = 0.f;
    if (j < end){
      e = erec[j];
      float lg0 = ps0n + pd0[e.x] + prs0[e.y] + prs0[e.z];
      float lg1 = ps1n + pd1[e.x] + prs1[e.y] + prs1[e.z];
      wv0 = __expf(-((lg0 > 0.f) ? lg0 : 0.2f*lg0));
      wv1 = __expf(-((lg1 > 0.f) ? lg1 : 0.2f*lg1));
    }
    Sl0 += wv0; Sl1 += wv1;
    int m = end - b; if (m > 64) m = 64;
    int i = 0;
    for (; i + 1 < m; i += 2){
      float wA0 = __shfl(wv0, i),   wA1 = __shfl(wv1, i);
      float wB0 = __shfl(wv0, i+1), wB1 = __shfl(wv1, i+1);
      int dA = __shfl(e.x, i),   tA0 = __shfl(e.y, i),   tA1 = __shfl(e.z, i);
      int dB = __shfl(e.x, i+1), tB0 = __shfl(e.y, i+1), tB1 = __shfl(e.z, i+1);
      if (act){
        float wA = head ? wA1 : wA0;
        float wB = head ? wB1 : wB0;
        ushort4 xA = *(const ushort4*)(xb + (size_t)dA*ldx);
        ushort4 rA = *(const ushort4*)(rb + (size_t)tA0*ldr);
        ushort4 xB = *(const ushort4*)(xb + (size_t)dB*ldx);
        ushort4 rB = *(const ushort4*)(rb + (size_t)tB0*ldr);
        float ax = bf2f(xA.x)+bf2f(rA.x), ay = bf2f(xA.y)+bf2f(rA.y);
        float az = bf2f(xA.z)+bf2f(rA.z), aw = bf2f(xA.w)+bf2f(rA.w);
        if (tA1 != NRELS){
          ushort4 rc = *(const ushort4*)(rb + (size_t)tA1*ldr);
          ax += bf2f(rc.x); ay += bf2f(rc.y); az += bf2f(rc.z); aw += bf2f(rc.w);
        }
        float bx = bf2f(xB.x)+bf2f(rB.x), by = bf2f(xB.y)+bf2f(rB.y);
        float bz = bf2f(xB.z)+bf2f(rB.z), bw = bf2f(xB.w)+bf2f(rB.w);
        if (tB1 != NRELS){
          ushort4 rc = *(const ushort4*)(rb + (size_t)tB1*ldr);
          bx += bf2f(rc.x); by += bf2f(rc.y); bz += bf2f(rc.z); bw += bf2f(rc.w);
        }
        accA.x += wA*ax; accA.y += wA*ay; accA.z += wA*az; accA.w += wA*aw;
        accB.x += wB*bx; accB.y += wB*by; accB.z += wB*bz; accB.w += wB*bw;
      }
    }
    if (i < m){
      float wA0 = __shfl(wv0, i), wA1 = __shfl(wv1, i);
      int dA = __shfl(e.x, i), tA0 = __shfl(e.y, i), tA1 = __shfl(e.z, i);
      if (act){
        float wA = head ? wA1 : wA0;
        ushort4 xA = *(const ushort4*)(xb + (size_t)dA*ldx);
        ushort4 rA = *(const ushort4*)(rb + (size_t)tA0*ldr);
        float ax = bf2f(xA.x)+bf2f(rA.x), ay = bf2f(xA.y)+bf2f(rA.y);
        float az = bf2f(xA.z)+bf2f(rA.z), aw = bf2f(xA.w)+bf2f(rA.w);
        if (tA1 != NRELS){
          ushort4 rc = *(const ushort4*)(rb + (size_t)tA1*ldr);
          ax += bf2f(rc.x); ay += bf2f(rc.y); az += bf2f(rc.z); aw += bf2f(rc.w);
        }
        accA.x += wA*ax; accA.y += wA*ay; accA.z += wA*az; accA.w += wA*aw;
      }
    }
  }
  accO.x += accA.x + accB.x; accO.y += accA.y + accB.y;
  accO.z += accA.z + accB.z; accO.w += accA.w + accB.w;
}

__device__ inline void aggh_finalize(int n, float S0, float S1, float4 acc, int lane,
    const __hip_bfloat16* __restrict__ XSD, int ldx,
    __hip_bfloat16* __restrict__ outb, int ldb)
{
  if (lane >= 50) return;
  int head = (lane >= 25) ? 1 : 0;
  int li = lane - 25*head;
  float S = head ? S1 : S0;
  float inv = (S > 0.f) ? 1.0f/S : 0.f;
  ushort4 xs4 = *(const ushort4*)(XSD + (size_t)n*ldx + (head ? 256 : 0) + 4*li);
  float h0 = (S > 0.f) ? bf2f(xs4.x) + acc.x*inv : 0.f;
  float h1 = (S > 0.f) ? bf2f(xs4.y) + acc.y*inv : 0.f;
  float h2 = (S > 0.f) ? bf2f(xs4.z) + acc.z*inv : 0.f;
  float h3 = (S > 0.f) ? bf2f(xs4.w) + acc.w*inv : 0.f;
  h0 = (h0 > 0.f) ? h0 : expm1f(h0);
  h1 = (h1 > 0.f) ? h1 : expm1f(h1);
  h2 = (h2 > 0.f) ? h2 : expm1f(h2);
  h3 = (h3 > 0.f) ? h3 : expm1f(h3);
  ushort4 o; o.x = f2bf(h0); o.y = f2bf(h1); o.z = f2bf(h2); o.w = f2bf(h3);
  *(ushort4*)(outb + (size_t)n*ldb + 100*head + 4*li) = o;
}

__global__ __launch_bounds__(256) void k_aggh(
    const int* __restrict__ rowofs, const int4* __restrict__ erec,
    const float* __restrict__ ps0, const float* __restrict__ pd0, const float* __restrict__ prs0,
    const float* __restrict__ ps1, const float* __restrict__ pd1, const float* __restrict__ prs1,
    const __hip_bfloat16* __restrict__ XSD, int ldx,
    const __hip_bfloat16* __restrict__ RRb, int ldr,
    __hip_bfloat16* __restrict__ outb, int ldb)
{
  __shared__ float4 redA[256];
  __shared__ float redS0[4];
  __shared__ float redS1[4];
  int bid = blockIdx.x;
  int wave = threadIdx.x >> 6, lane = threadIdx.x & 63;

  if (bid < HOTN){
    int n = bid;
    int beg = rowofs[n], end = rowofs[n+1];
    float ps0n = ps0[n], ps1n = ps1[n];
    float Sl0 = 0.f, Sl1 = 0.f;
    float4 acc = make_float4(0.f,0.f,0.f,0.f);
    aggh_edges(beg + wave*64, end, 256, erec, ps0n, pd0, prs0, ps1n, pd1, prs1,
               XSD, ldx, RRb, ldr, lane, Sl0, Sl1, acc);
    float Sw0 = Sl0, Sw1 = Sl1;
    #pragma unroll
    for (int o = 32; o; o >>= 1){ Sw0 += __shfl_xor(Sw0, o, 64); Sw1 += __shfl_xor(Sw1, o, 64); }
    redA[threadIdx.x] = acc;
    if (lane == 0){ redS0[wave] = Sw0; redS1[wave] = Sw1; }
    __syncthreads();
    if (wave == 0){
      float4 a0 = redA[lane], a1 = redA[lane+64], a2 = redA[lane+128], a3 = redA[lane+192];
      float4 at = make_float4(a0.x+a1.x+a2.x+a3.x, a0.y+a1.y+a2.y+a3.y,
                              a0.z+a1.z+a2.z+a3.z, a0.w+a1.w+a2.w+a3.w);
      float St0 = redS0[0] + redS0[1] + redS0[2] + redS0[3];
      float St1 = redS1[0] + redS1[1] + redS1[2] + redS1[3];
      aggh_finalize(n, St0, St1, at, lane, XSD, ldx, outb, ldb);
    }
  } else {
    int n = HOTN + (bid - HOTN)*4 + wave;
    int beg = rowofs[n], end = rowofs[n+1];
    float ps0n = ps0[n], ps1n = ps1[n];
    float Sl0 = 0.f, Sl1 = 0.f;
    float4 acc = make_float4(0.f,0.f,0.f,0.f);
    aggh_edges(beg, end, 64, erec, ps0n, pd0, prs0, ps1n, pd1, prs1,
               XSD, ldx, RRb, ldr, lane, Sl0, Sl1, acc);
    float S0 = Sl0, S1 = Sl1;
    #pragma unroll
    for (int o = 32; o; o >>= 1){ S0 += __shfl_xor(S0, o, 64); S1 += __shfl_xor(S1, o, 64); }
    aggh_finalize(n, S0, S1, acc, lane, XSD, ldx, outb, ldb);
  }
}

// ---------------------------------------------------------------- driver
extern "C" void kernel_launch(void* const* d_in, const int* in_sizes, int n_in,
                              void* d_out, int out_size, void* d_ws, size_t ws_size,
                              hipStream_t stream) {
  const float* entity   = (const float*)d_in[0];
  const float* relation = (const float*)d_in[1];
  const float* W_ent    = (const float*)d_in[2];
  const float* g0_a0    = (const float*)d_in[3];
  const float* g0_s0    = (const float*)d_in[4];
  const float* g0_a1    = (const float*)d_in[5];
  const float* g0_s1    = (const float*)d_in[6];
  const float* g0_W     = (const float*)d_in[7];
  const float* g0_oa    = (const float*)d_in[8];
  const float* g0_os    = (const float*)d_in[9];
  const float* g1_a0    = (const float*)d_in[10];
  const float* g1_s0    = (const float*)d_in[11];
  const float* g1_W     = (const float*)d_in[12];
  const float* g1_oa    = (const float*)d_in[13];
  const float* g1_os    = (const float*)d_in[14];
  const int*   el       = (const int*)d_in[15];
  const int*   et       = (const int*)d_in[16];
  const int*   nh       = (const int*)d_in[17];
  const int*   batch    = (const int*)d_in[18];
  (void)in_sizes; (void)n_in; (void)out_size; (void)ws_size;

  char* w = (char*)d_ws;
  auto alloc = [&](size_t bytes)->char*{ char* p = w; w += (bytes + 255) & ~(size_t)255; return p; };
  // scalars
  float* PS0   = (float*)alloc((size_t)NNODES*4);
  float* PD0   = (float*)alloc((size_t)NNODES*4);
  float* PS1   = (float*)alloc((size_t)NNODES*4);
  float* PD1   = (float*)alloc((size_t)NNODES*4);
  float* PRS0  = (float*)alloc((size_t)(NRELS+4)*4);
  float* PRS1  = (float*)alloc((size_t)(NRELS+4)*4);
  float* WT    = (float*)alloc((size_t)2304*4);
  // bf16 arenas
  __hip_bfloat16* AENT0  = (__hip_bfloat16*)alloc((size_t)MP*128*2);
  __hip_bfloat16* AX1    = (__hip_bfloat16*)alloc((size_t)MP*224*2);
  __hip_bfloat16* AENT1  = (__hip_bfloat16*)alloc((size_t)MP*224*2);
  __hip_bfloat16* ENTUPb = (__hip_bfloat16*)alloc((size_t)MP*224*2);
  __hip_bfloat16* HB     = (__hip_bfloat16*)alloc((size_t)MP*224*2);
  __hip_bfloat16* AREL0  = (__hip_bfloat16*)alloc((size_t)RPAD*128*2);
  __hip_bfloat16* AREL1  = (__hip_bfloat16*)alloc((size_t)RPAD*224*2);
  __hip_bfloat16* RELUPb = (__hip_bfloat16*)alloc((size_t)RPAD*224*2);
  __hip_bfloat16* ORb0   = (__hip_bfloat16*)alloc((size_t)RPAD*224*2);
  __hip_bfloat16* ORb1   = (__hip_bfloat16*)alloc((size_t)RPAD*224*2);
  __hip_bfloat16* XSD    = (__hip_bfloat16*)alloc((size_t)MP*512*2);
  __hip_bfloat16* RRb    = (__hip_bfloat16*)alloc((size_t)RPAD*256*2);
  __hip_bfloat16* WA     = (__hip_bfloat16*)alloc((size_t)737280*2);
  // ints
  int* IALL = (int*)alloc((size_t)150001*4);
  int* ROWOFS = IALL;
  int* CUR    = IALL + 50001;
  float* MASK = (float*)(IALL + 100001);
  int4* EREC  = (int4*)alloc((size_t)NETOT*16);
  int* PART   = (int*)alloc((size_t)256*4);

  const __hip_bfloat16* WET   = WA;
  const __hip_bfloat16* G0WT  = WA + 32768;
  const __hip_bfloat16* BH0   = WA + 65536;
  const __hip_bfloat16* BR0   = WA + 131072;
  const __hip_bfloat16* BO0   = WA + 163840;
  const __hip_bfloat16* BO0r  = WA + 278528;
  const __hip_bfloat16* BA1   = WA + 335872;
  const __hip_bfloat16* BA1r  = WA + 450560;
  const __hip_bfloat16* G1WT  = WA + 507904;
  const __hip_bfloat16* BO1   = WA + 565248;
  const __hip_bfloat16* BO1r  = WA + 679936;

  float* outEnt = (float*)d_out;
  float* outRel = outEnt + (size_t)NNODES*200;

  const int TB = 256;
  auto gb = [&](long long n){ return (int)((n + TB - 1)/TB); };
  const int AGG_GRID = HOTN + (NNODES - HOTN)/4;

  // ---- preprocessing: zeros / pads ----
  k_zero<<<gb(150001), TB, 0, stream>>>(IALL, 150001);
  k_zero<<<gb((48*128 + 48*224)/2), TB, 0, stream>>>((int*)(AENT0 + (size_t)NNODES*128), 48*128/2);
  k_zero<<<gb(48*224/2), TB, 0, stream>>>((int*)(AX1 + (size_t)NNODES*224), 48*224/2);
  k_zero<<<gb(48*224/2), TB, 0, stream>>>((int*)(AENT1 + (size_t)NNODES*224), 48*224/2);
  k_zero<<<gb((RPAD*128 + RPAD*224)/2), TB, 0, stream>>>((int*)AREL0, (RPAD*128 + RPAD*224)/2); // AREL0+AREL1 (adjacent)
  k_padcols<<<gb((long long)MP*24), TB, 0, stream>>>(AX1, MP, 200, 224);
  k_padcols<<<gb((long long)RPAD*24), TB, 0, stream>>>(ORb0, RPAD, 200, 224);
  k_padcols<<<gb((long long)RPAD*24), TB, 0, stream>>>(ORb1, RPAD, 200, 224);
  k_mask_set<<<gb(10000), TB, 0, stream>>>(batch, MASK, 10000);
  k_hist<<<gb(NETOT), TB, 0, stream>>>(el, nh, ROWOFS);
  int nsb = (NNODES + 255)/256;
  k_scan1<<<nsb, 256, 0, stream>>>(ROWOFS, NNODES, PART);
  k_scan2<<<1, 256, 0, stream>>>(PART, nsb);
  k_scan3<<<nsb, 256, 0, stream>>>(ROWOFS, NNODES, PART);
  k_scatter<<<gb(NETOT), TB, 0, stream>>>(el, et, nh, ROWOFS, CUR, EREC);

  // ---- inputs/weights -> bf16 ----
  k_l2norm_bf<100,128><<<NNODES, 64, 0, stream>>>(entity, AENT0);
  k_l2norm_bf<100,128><<<NRELS, 64, 0, stream>>>(relation, AREL0);
  {
    Ptr8 srcs;
    srcs.p[0] = W_ent; srcs.p[1] = g0_a0; srcs.p[2] = g0_a1; srcs.p[3] = g0_W;
    srcs.p[4] = g0_oa; srcs.p[5] = g1_a0; srcs.p[6] = g1_W;  srcs.p[7] = g1_oa;
    dim3 g(448, 18);
    k_wconv<<<g, 256, 0, stream>>>(srcs, WA);
  }
  k_wtab<<<gb(2304), 256, 0, stream>>>(g0_s0, g0_s1, g0_os, g1_s0, g1_os, WT);

  auto gemm = [&](const __hip_bfloat16* A, const __hip_bfloat16* B, __hip_bfloat16* C,
                  int M, int Nn, int Kp, int ldc){
    dim3 g((Nn + 63)/64, (M + 127)/128);
    k_gemm_mfma<<<g, 256, 0, stream>>>(A, B, C, M, Nn, Kp, ldc);
  };

  // ---- ent_up / rel_up (bf16 out, ld 224) ----
  gemm(AENT0, WET, ENTUPb, MP, 200, 128, 224);
  gemm(AREL0, WET, RELUPb, RPAD, 200, 128, 224);

  // ---- layer0 heads ----
  gemm(AENT0, BH0, XSD, MP, 512, 128, 512);
  gemm(AREL0, BR0, RRb, RPAD, 256, 128, 256);
  k_rowdotW<8,1><<<(NNODES+3)/4, 256, 0, stream>>>(XSD, 512, NNODES, WT + 0, PS0, PD0, PS1, PD1);
  k_rowdotW<4,2><<<(NRELS+4)/4, 256, 0, stream>>>(RRb, 256, NRELS+1, WT + 512, PRS0, PRS1, nullptr, nullptr);
  k_aggh<<<AGG_GRID, 256, 0, stream>>>(ROWOFS, EREC, PS0, PD0, PRS0, PS1, PD1, PRS1,
      XSD, 512, RRb, 256, AX1, 224);

  // ---- layer0 out-attention ----
  gemm(AREL0, G0WT, ORb0, RPAD, 200, 128, 224);
  gemm(AX1, BO0, XSD, MP, 512, 224, 512);
  gemm(ORb0, BO0r, RRb, RPAD, 256, 224, 256);
  k_rowdotW<8,2><<<(NNODES+3)/4, 256, 0, stream>>>(XSD, 512, NNODES, WT + 768, PS0, PD0, nullptr, nullptr);
  k_rowdotW<4,4><<<(NRELS+4)/4, 256, 0, stream>>>(RRb, 256, NRELS+1, WT + 768, PRS0, nullptr, nullptr, nullptr);
  k_agg5<<<AGG_GRID, 256, 0, stream>>>(ROWOFS, EREC, PS0, PD0, PRS0,
      XSD, 512, 0, 256, RRb, 256, 0, HB, 224, 0);
  k_combine2<false><<<NNODES + NRELS, 64, 0, stream>>>(ENTUPb, HB, MASK, RELUPb, ORb0,
      nullptr, nullptr, AENT1, AREL1);

  // ---- layer1 head ----
  gemm(AENT1, BA1, XSD, MP, 512, 224, 512);
  gemm(AREL1, BA1r, RRb, RPAD, 256, 224, 256);
  k_rowdotW<8,2><<<(NNODES+3)/4, 256, 0, stream>>>(XSD, 512, NNODES, WT + 1280, PS0, PD0, nullptr, nullptr);
  k_rowdotW<4,4><<<(NRELS+4)/4, 256, 0, stream>>>(RRb, 256, NRELS+1, WT + 1280, PRS0, nullptr, nullptr, nullptr);
  k_agg5<<<AGG_GRID, 256, 0, stream>>>(ROWOFS, EREC, PS0, PD0, PRS0,
      XSD, 512, 0, 256, RRb, 256, 0, AX1, 224, 0);

  // ---- layer1 out-attention ----
  gemm(AREL1, G1WT, ORb1, RPAD, 200, 224, 224);
  gemm(AX1, BO1, XSD, MP, 512, 224, 512);
  gemm(ORb1, BO1r, RRb, RPAD, 256, 224, 256);
  k_rowdotW<8,2><<<(NNODES+3)/4, 256, 0, stream>>>(XSD, 512, NNODES, WT + 1792, PS0, PD0, nullptr, nullptr);
  k_rowdotW<4,4><<<(NRELS+4)/4, 256, 0, stream>>>(RRb, 256, NRELS+1, WT + 1792, PRS0, nullptr, nullptr, nullptr);
  k_agg5<<<AGG_GRID, 256, 0, stream>>>(ROWOFS, EREC, PS0, PD0, PRS0,
      XSD, 512, 0, 256, RRb, 256, 0, HB, 224, 0);

  // ---- final combines -> d_out ----
  k_combine2<true><<<NNODES + NRELS, 64, 0, stream>>>(AENT1, HB, MASK, AREL1, ORb1,
      outEnt, outRel, nullptr, nullptr);
}

// Round 8
// 612.182 us; speedup vs baseline: 5.9905x; 1.0371x over previous
//
#include <hip/hip_runtime.h>
#include <hip/hip_bf16.h>
#include <cstdint>
#include <cstddef>

#define NNODES 50000
#define NRELS  500
#define NEDGE  500000
#define NETOT  600000
#define MP     50048
#define RPAD   512
#define HOTN   512

typedef __attribute__((ext_vector_type(8))) short bf16x8;
typedef __attribute__((ext_vector_type(4))) float f32x4;

__device__ inline float bf2f(unsigned short s){
  union { unsigned u; float f; } v; v.u = ((unsigned)s) << 16; return v.f;
}
__device__ inline unsigned short f2bf(float f){
  __hip_bfloat16 h = __float2bfloat16(f);
  return __builtin_bit_cast(unsigned short, h);
}
__device__ inline float rl_f(float v, int i){
  return __builtin_bit_cast(float, __builtin_amdgcn_readlane(__builtin_bit_cast(int, v), i));
}

// ---------------------------------------------------------------- weight conversion table
struct WEnt { int src, ld, boff, rows, K, tr, dstoff, Kp, rp; };
__device__ const WEnt g_went[18] = {
  {0,200,0,200,100,1,      0,128,256},
  {3,200,0,200,100,1,  32768,128,256},
  {1,300,  0,100,100,0,  65536,128,128},
  {1,300,100,100,100,0,  81920,128,128},
  {2,300,  0,100,100,0,  98304,128,128},
  {2,300,100,100,100,0, 114688,128,128},
  {1,300,200,100,100,0, 131072,128,128},
  {2,300,200,100,100,0, 147456,128,128},
  {4,600,  0,200,200,0, 163840,224,256},
  {4,600,200,200,200,0, 221184,224,256},
  {4,600,400,200,200,0, 278528,224,256},
  {5,600,  0,200,200,0, 335872,224,256},
  {5,600,200,200,200,0, 393216,224,256},
  {5,600,400,200,200,0, 450560,224,256},
  {6,200,0,200,200,1,   507904,224,256},
  {7,600,  0,200,200,0, 565248,224,256},
  {7,600,200,200,200,0, 622592,224,256},
  {7,600,400,200,200,0, 679936,224,256},
};
struct Ptr8 { const float* p[8]; };

// ---------------------------------------------------------------- mega setup kernel (segmented grid)
// All segments write disjoint regions -> no intra-kernel ordering needed.
#define SB_O1 587
#define SB_O2 599
#define SB_O3 620
#define SB_O4 641
#define SB_O5 650
#define SB_O6 5342
#define SB_O7 5351
#define SB_O8 13415
#define SB_O9 25915
#define SB_TOT 26040

struct SetupArgs {
  int* iall;                               // 150001 ints (ROWOFS|CUR|MASK)
  __hip_bfloat16 *aent0, *ax1, *aent1, *arel0, *arel1;
  float* wt;
  const float *s0h, *s1h, *os0, *s1l, *os1;
  __hip_bfloat16* wa;
  Ptr8 wsrcs;
  const float *entity, *relation;
};

__global__ __launch_bounds__(256) void k_setup(SetupArgs a){
  int bid = blockIdx.x, tid = threadIdx.x;
  if (bid < SB_O1){ int i = bid*256 + tid; if (i < 150001) a.iall[i] = 0; return; }
  if (bid < SB_O2){ int i = (bid-SB_O1)*256 + tid;              // AENT0 pad rows (48x128)
    ((int*)(a.aent0 + (size_t)NNODES*128))[i] = 0; return; }
  if (bid < SB_O3){ int i = (bid-SB_O2)*256 + tid;              // AX1 pad rows (48x224)
    if (i < 5376) ((int*)(a.ax1 + (size_t)NNODES*224))[i] = 0; return; }
  if (bid < SB_O4){ int i = (bid-SB_O3)*256 + tid;              // AENT1 pad rows
    if (i < 5376) ((int*)(a.aent1 + (size_t)NNODES*224))[i] = 0; return; }
  if (bid < SB_O5){ int i = (bid-SB_O4)*256 + tid;              // AREL0/AREL1 pad rows (12x128 + 12x224)
    if (i < 768) ((int*)(a.arel0 + (size_t)NRELS*128))[i] = 0;
    else if (i < 2112) ((int*)(a.arel1 + (size_t)NRELS*224))[i - 768] = 0;
    return; }
  if (bid < SB_O6){ int i = (bid-SB_O5)*256 + tid;              // AX1 pad cols (MP x 24), exact
    int r = i / 24, k = 200 + (i - r*24);
    a.ax1[(size_t)r*224 + k] = __float2bfloat16(0.f); return; }
  if (bid < SB_O7){                                             // wtab (2304)
    int i = (bid-SB_O6)*256 + tid; if (i >= 2304) return;
    float v = 0.f;
    if (i < 512){ int c = i & 127; const float* s = (i < 256) ? a.s0h : a.s1h; if (c < 100) v = s[c]; }
    else if (i < 768){ int j2 = i - 512, c = j2 & 127; const float* s = (j2 < 128) ? a.s0h : a.s1h; if (c < 100) v = s[c]; }
    else { int j2 = i - 768, t = j2 >> 9, c = j2 & 255;
           const float* s = (t==0)?a.os0:(t==1)?a.s1l:a.os1; if (c < 200) v = s[c]; }
    a.wt[i] = v; return; }
  if (bid < SB_O8){                                             // wconv (18 x 448)
    int sb = bid - SB_O7;
    WEnt e = g_went[sb / 448];
    int i = (sb - (sb/448)*448)*256 + tid;
    if (i >= e.rp*e.Kp) return;
    int r = i / e.Kp, k = i - r*e.Kp;
    float v = 0.f;
    if (r < e.rows && k < e.K)
      v = e.tr ? a.wsrcs.p[e.src][(size_t)k*e.ld + r] : a.wsrcs.p[e.src][(size_t)r*e.ld + e.boff + k];
    a.wa[e.dstoff + i] = __float2bfloat16(v); return; }
  {                                                             // l2norm -> bf16, 4 rows/block
    int wave = tid >> 6, lane = tid & 63;
    const float* src; __hip_bfloat16* dst; int row;
    if (bid < SB_O9){ row = (bid - SB_O8)*4 + wave; src = a.entity; dst = a.aent0; }
    else            { row = (bid - SB_O9)*4 + wave; src = a.relation; dst = a.arel0; }
    const float* rp = src + (size_t)row*100;
    float v0 = (lane < 100) ? rp[lane] : 0.f;
    float v1 = (lane + 64 < 100) ? rp[lane + 64] : 0.f;
    float ss = v0*v0 + v1*v1;
    #pragma unroll
    for (int o = 32; o; o >>= 1) ss += __shfl_xor(ss, o, 64);
    float sc = 1.0f / fmaxf(sqrtf(ss), 1e-12f);
    __hip_bfloat16* orow = dst + (size_t)row*128;
    orow[lane] = __float2bfloat16(v0*sc);
    orow[lane + 64] = __float2bfloat16(v1*sc);
  }
}

__global__ void k_mask_set(const int* __restrict__ batch, float* __restrict__ mask, int nb){
  int i = blockIdx.x*blockDim.x + threadIdx.x;
  if (i < nb) mask[batch[3*i+2]] = 1.0f;
}

// ---------------------------------------------------------------- edge CSR
__global__ void k_hist(const int* __restrict__ el, const int* __restrict__ nh, int* __restrict__ deg){
  int e = blockIdx.x*blockDim.x + threadIdx.x;
  if (e >= NETOT) return;
  int s = (e < NEDGE) ? el[e] : nh[4*(e-NEDGE)+3];
  atomicAdd(&deg[s], 1);
}
__global__ void k_scan1(int* __restrict__ data, int n, int* __restrict__ part){
  __shared__ int sh[256];
  int t = threadIdx.x, i = blockIdx.x*256 + t;
  int v = (i < n) ? data[i] : 0;
  sh[t] = v; __syncthreads();
  for (int o = 1; o < 256; o <<= 1){
    int x = (t >= o) ? sh[t-o] : 0;
    __syncthreads(); sh[t] += x; __syncthreads();
  }
  if (i < n) data[i] = sh[t] - v;
  if (t == 255) part[blockIdx.x] = sh[255];
}
__global__ void k_scan2(int* __restrict__ part, int nb){
  __shared__ int sh[256];
  int t = threadIdx.x;
  int v = (t < nb) ? part[t] : 0;
  sh[t] = v; __syncthreads();
  for (int o = 1; o < 256; o <<= 1){
    int x = (t >= o) ? sh[t-o] : 0;
    __syncthreads(); sh[t] += x; __syncthreads();
  }
  if (t < nb) part[t] = sh[t] - v;
}
__global__ void k_scan3(int* __restrict__ data, int n, const int* __restrict__ part){
  int i = blockIdx.x*256 + threadIdx.x;
  if (i < n) data[i] += part[blockIdx.x];
  if (i == 0) data[n] = NETOT;
}
__global__ void k_scatter(const int* __restrict__ el, const int* __restrict__ et,
                          const int* __restrict__ nh, const int* __restrict__ rowofs,
                          int* __restrict__ cur, int4* __restrict__ erec){
  int e = blockIdx.x*blockDim.x + threadIdx.x;
  if (e >= NETOT) return;
  int s, d, t0, t1;
  if (e < NEDGE){ s = el[e]; d = el[NEDGE+e]; t0 = et[e]; t1 = NRELS; }
  else { int i = e - NEDGE; s = nh[4*i+3]; d = nh[4*i+0]; t0 = nh[4*i+1]; t1 = nh[4*i+2]; }
  int p = rowofs[s] + atomicAdd(&cur[s], 1);
  erec[p] = make_int4(d, t0, t1, 0);
}

// ---------------------------------------------------------------- fused combine: l2norm(base + m*h)
template<bool FINAL>
__global__ __launch_bounds__(64) void k_combine2(
    const __hip_bfloat16* __restrict__ baseE, const __hip_bfloat16* __restrict__ hE,
    const float* __restrict__ mask,
    const __hip_bfloat16* __restrict__ baseR, const __hip_bfloat16* __restrict__ hR,
    float* __restrict__ outfE, float* __restrict__ outfR,
    __hip_bfloat16* __restrict__ outbE, __hip_bfloat16* __restrict__ outbR)
{
  int n = blockIdx.x, lane = threadIdx.x;
  bool isE = n < NNODES;
  int row = isE ? n : n - NNODES;
  const __hip_bfloat16* b = (isE ? baseE : baseR) + (size_t)row*224;
  const __hip_bfloat16* h = (isE ? hE : hR) + (size_t)row*224;
  float m = isE ? mask[row] : 1.0f;
  int c = lane*4;
  float4 v = make_float4(0.f,0.f,0.f,0.f);
  if (c < 200){
    ushort4 bb = *(const ushort4*)(b + c);
    ushort4 hh = *(const ushort4*)(h + c);
    v.x = bf2f(bb.x) + m*bf2f(hh.x);
    v.y = bf2f(bb.y) + m*bf2f(hh.y);
    v.z = bf2f(bb.z) + m*bf2f(hh.z);
    v.w = bf2f(bb.w) + m*bf2f(hh.w);
  }
  float ss = v.x*v.x + v.y*v.y + v.z*v.z + v.w*v.w;
  #pragma unroll
  for (int o = 32; o; o >>= 1) ss += __shfl_xor(ss, o, 64);
  float sc = 1.0f / fmaxf(sqrtf(ss), 1e-12f);
  if constexpr (FINAL){
    if (c < 200){
      float* o = (isE ? outfE : outfR) + (size_t)row*200 + c;
      *(float4*)o = make_float4(v.x*sc, v.y*sc, v.z*sc, v.w*sc);
    }
  } else {
    if (c < 224){
      __hip_bfloat16* o = (isE ? outbE : outbR) + (size_t)row*224 + c;
      ushort4 w4; w4.x = f2bf(v.x*sc); w4.y = f2bf(v.y*sc); w4.z = f2bf(v.z*sc); w4.w = f2bf(v.w*sc);
      *(ushort4*)o = w4;
    }
  }
}

// ---------------------------------------------------------------- fused node+rel rowdot
__global__ __launch_bounds__(256) void k_rowdot3(
    const __hip_bfloat16* __restrict__ XN, const float* __restrict__ wtN, int GN,
    float* __restrict__ n0, float* __restrict__ n1, float* __restrict__ n2, float* __restrict__ n3,
    const __hip_bfloat16* __restrict__ XR, const float* __restrict__ wtR, int GR,
    float* __restrict__ r0, float* __restrict__ r1)
{
  int wave = threadIdx.x >> 6, lane = threadIdx.x & 63;
  int b = blockIdx.x;
  if (b < 12500){
    int row = b*4 + wave;
    const __hip_bfloat16* xr = XN + (size_t)row*512 + lane*8;
    const float* wr = wtN + lane*8;
    float p = 0.f;
    #pragma unroll
    for (int k = 0; k < 2; k++){
      ushort4 x = *(const ushort4*)(xr + 4*k);
      float4 a = *(const float4*)(wr + 4*k);
      p += bf2f(x.x)*a.x + bf2f(x.y)*a.y + bf2f(x.z)*a.z + bf2f(x.w)*a.w;
    }
    for (int o = GN>>1; o; o >>= 1) p += __shfl_xor(p, o, 64);
    if ((lane & (GN-1)) == 0){
      int g = lane / GN;
      float* out = (g==0)?n0:(g==1)?n1:(g==2)?n2:n3;
      out[row] = p;
    }
  } else {
    int row = (b - 12500)*4 + wave;
    if (row >= NRELS + 1) return;
    const __hip_bfloat16* xr = XR + (size_t)row*256 + lane*4;
    ushort4 x = *(const ushort4*)xr;
    float4 a = *(const float4*)(wtR + lane*4);
    float p = bf2f(x.x)*a.x + bf2f(x.y)*a.y + bf2f(x.z)*a.z + bf2f(x.w)*a.w;
    for (int o = GR>>1; o; o >>= 1) p += __shfl_xor(p, o, 64);
    if ((lane & (GR-1)) == 0){
      int g = lane / GR;
      float* out = (g==0)?r0:r1;
      out[row] = p;
    }
  }
}

// ---------------------------------------------------------------- dual bf16 MFMA GEMM (NT)
struct GemmDesc {
  const __hip_bfloat16 *A, *B; __hip_bfloat16* C;
  int M, Nn, Kp, ldc, gx, nblk;
};
__global__ __launch_bounds__(256) void k_gemm2(GemmDesc g1, GemmDesc g2)
{
  __shared__ __hip_bfloat16 As[128*32];
  __shared__ __hip_bfloat16 Bs[64*32];
  const int tid = threadIdx.x;
  const int wave = tid >> 6, lane = tid & 63;
  const int lg = lane >> 4, li = lane & 15;
  // bijective XCD-chunk swizzle over the 1-D grid
  int nwg = gridDim.x;
  int orig = blockIdx.x;
  int q = nwg >> 3, r = nwg & 7;
  int xcd = orig & 7, off = orig >> 3;
  int wg = (xcd < r ? xcd*(q+1) : r*(q+1) + (xcd - r)*q) + off;
  GemmDesc g = (wg < g1.nblk) ? g1 : g2;
  int local = (wg < g1.nblk) ? wg : wg - g1.nblk;
  const int bx = local % g.gx, by = local / g.gx;
  const int m0 = by * 128, n0 = bx * 64;
  const int Kp = g.Kp;
  const int wr = wave >> 1, wc = wave & 1;
  f32x4 acc[4][2] = {};

  const int ar0 = tid >> 2;
  const int ar1 = (tid + 256) >> 2;
  const int ap  = tid & 3;
  const char* Ab = (const char*)g.A;
  const char* Bb = (const char*)g.B;
  char* asB = (char*)As;
  char* bsB = (char*)Bs;

  for (int kk = 0; kk < Kp; kk += 32){
    {
      int p0 = ap ^ ((ar0 >> 1) & 3);
      const char* s0 = Ab + ((size_t)(m0 + ar0)*Kp + kk)*2 + p0*16;
      __builtin_amdgcn_global_load_lds((const __attribute__((address_space(1))) void*)s0,
          (__attribute__((address_space(3))) void*)(asB + wave*1024), 16, 0, 0);
      int p1 = ap ^ ((ar1 >> 1) & 3);
      const char* s1 = Ab + ((size_t)(m0 + ar1)*Kp + kk)*2 + p1*16;
      __builtin_amdgcn_global_load_lds((const __attribute__((address_space(1))) void*)s1,
          (__attribute__((address_space(3))) void*)(asB + 4096 + wave*1024), 16, 0, 0);
      int pb = ap ^ ((ar0 >> 1) & 3);
      const char* sb = Bb + ((size_t)(n0 + ar0)*Kp + kk)*2 + pb*16;
      __builtin_amdgcn_global_load_lds((const __attribute__((address_space(1))) void*)sb,
          (__attribute__((address_space(3))) void*)(bsB + wave*1024), 16, 0, 0);
    }
    __syncthreads();
    bf16x8 av[4], bv[2];
    #pragma unroll
    for (int mf = 0; mf < 4; mf++){
      int row = wr*64 + mf*16 + li;
      int p = lg ^ ((row >> 1) & 3);
      av[mf] = *(const bf16x8*)(asB + row*64 + p*16);
    }
    #pragma unroll
    for (int nf = 0; nf < 2; nf++){
      int row = wc*32 + nf*16 + li;
      int p = lg ^ ((row >> 1) & 3);
      bv[nf] = *(const bf16x8*)(bsB + row*64 + p*16);
    }
    #pragma unroll
    for (int mf = 0; mf < 4; mf++)
      #pragma unroll
      for (int nf = 0; nf < 2; nf++)
        acc[mf][nf] = __builtin_amdgcn_mfma_f32_16x16x32_bf16(av[mf], bv[nf], acc[mf][nf], 0, 0, 0);
    __syncthreads();
  }
  #pragma unroll
  for (int mf = 0; mf < 4; mf++){
    #pragma unroll
    for (int nf = 0; nf < 2; nf++){
      int gc = n0 + wc*32 + nf*16 + li;
      if (gc >= g.Nn) continue;
      int gr0 = m0 + wr*64 + mf*16 + lg*4;
      #pragma unroll
      for (int rr = 0; rr < 4; rr++){
        int gr = gr0 + rr;
        if (gr < g.M) g.C[(size_t)gr*g.ldc + gc] = __float2bfloat16(acc[mf][nf][rr]);
      }
    }
  }
}

// ---------------------------------------------------------------- aggregation v6 (readlane/SGPR broadcast)
__device__ inline void agg6_edges(int bstart, int end, int bstep,
    const int4* __restrict__ erec, float psn,
    const float* __restrict__ pd, const float* __restrict__ prs,
    const __hip_bfloat16* __restrict__ xdb, int ldx,
    const __hip_bfloat16* __restrict__ rrb, int ldr,
    int lane, float& Sl, float4& acc)
{
  const bool act = lane < 50;
  const int co = 4*lane;
  for (int b = bstart; b < end; b += bstep){
    int j = b + lane;
    int4 e = make_int4(0, NRELS, NRELS, 0);
    float wv = 0.f;
    if (j < end){
      e = erec[j];
      float lg = psn + pd[e.x] + prs[e.y] + prs[e.z];
      wv = __expf(-((lg > 0.f) ? lg : 0.2f*lg));
    }
    Sl += wv;
    int m = end - b; if (m > 64) m = 64;
    if (act){
      #pragma unroll 8
      for (int i = 0; i < m; ++i){
        float w0 = rl_f(wv, i);
        int d  = __builtin_amdgcn_readlane(e.x, i);
        int t0 = __builtin_amdgcn_readlane(e.y, i);
        int t1 = __builtin_amdgcn_readlane(e.z, i);
        const __hip_bfloat16* xr  = xdb + (size_t)d*ldx;   // uniform base (SGPR)
        const __hip_bfloat16* rr0 = rrb + (size_t)t0*ldr;
        ushort4 xa = *(const ushort4*)(xr + co);
        ushort4 ra = *(const ushort4*)(rr0 + co);
        float sx = bf2f(xa.x)+bf2f(ra.x), sy = bf2f(xa.y)+bf2f(ra.y);
        float sz = bf2f(xa.z)+bf2f(ra.z), sw = bf2f(xa.w)+bf2f(ra.w);
        if (t1 != NRELS){
          const __hip_bfloat16* rr1 = rrb + (size_t)t1*ldr;
          ushort4 rc = *(const ushort4*)(rr1 + co);
          sx += bf2f(rc.x); sy += bf2f(rc.y); sz += bf2f(rc.z); sw += bf2f(rc.w);
        }
        acc.x += w0*sx; acc.y += w0*sy; acc.z += w0*sz; acc.w += w0*sw;
      }
    }
  }
}

__device__ inline void agg5_finalize(int n, float S, float4 acc, int lane,
    const __hip_bfloat16* __restrict__ XSD, int cxs,
    __hip_bfloat16* __restrict__ outb, int ldb, int coffb)
{
  if (lane >= 50) return;
  float inv = (S > 0.f) ? 1.0f/S : 0.f;
  ushort4 xs4 = *(const ushort4*)(XSD + (size_t)n*512 + cxs + 4*lane);
  float h0 = (S > 0.f) ? bf2f(xs4.x) + acc.x*inv : 0.f;
  float h1 = (S > 0.f) ? bf2f(xs4.y) + acc.y*inv : 0.f;
  float h2 = (S > 0.f) ? bf2f(xs4.z) + acc.z*inv : 0.f;
  float h3 = (S > 0.f) ? bf2f(xs4.w) + acc.w*inv : 0.f;
  h0 = (h0 > 0.f) ? h0 : expm1f(h0);
  h1 = (h1 > 0.f) ? h1 : expm1f(h1);
  h2 = (h2 > 0.f) ? h2 : expm1f(h2);
  h3 = (h3 > 0.f) ? h3 : expm1f(h3);
  ushort4 o; o.x = f2bf(h0); o.y = f2bf(h1); o.z = f2bf(h2); o.w = f2bf(h3);
  *(ushort4*)(outb + (size_t)n*ldb + coffb + 4*lane) = o;
}

__global__ __launch_bounds__(256) void k_agg5(
    const int* __restrict__ rowofs, const int4* __restrict__ erec,
    const float* __restrict__ ps, const float* __restrict__ pd, const float* __restrict__ prs,
    const __hip_bfloat16* __restrict__ XSD,
    const __hip_bfloat16* __restrict__ RRb,
    __hip_bfloat16* __restrict__ outb, int ldb, int coffb)
{
  __shared__ float4 redA[256];
  __shared__ float redS[4];
  int bid = blockIdx.x;
  int wave = threadIdx.x >> 6, lane = threadIdx.x & 63;
  const __hip_bfloat16* xdb = XSD + 256;   // cxd = 256

  if (bid < HOTN){
    int n = bid;
    int beg = rowofs[n], end = rowofs[n+1];
    float psn = ps[n];
    float Sl = 0.f;
    float4 acc = make_float4(0.f,0.f,0.f,0.f);
    agg6_edges(beg + wave*64, end, 256, erec, psn, pd, prs,
               xdb, 512, RRb, 256, lane, Sl, acc);
    float Sw = Sl;
    #pragma unroll
    for (int o = 32; o; o >>= 1) Sw += __shfl_xor(Sw, o, 64);
    redA[threadIdx.x] = acc;
    if (lane == 0) redS[wave] = Sw;
    __syncthreads();
    if (wave == 0){
      float4 a0 = redA[lane], a1 = redA[lane+64], a2 = redA[lane+128], a3 = redA[lane+192];
      float4 at = make_float4(a0.x+a1.x+a2.x+a3.x, a0.y+a1.y+a2.y+a3.y,
                              a0.z+a1.z+a2.z+a3.z, a0.w+a1.w+a2.w+a3.w);
      float St = redS[0] + redS[1] + redS[2] + redS[3];
      agg5_finalize(n, St, at, lane, XSD, 0, outb, ldb, coffb);
    }
  } else {
    int n = HOTN + (bid - HOTN)*4 + wave;
    int beg = rowofs[n], end = rowofs[n+1];
    float psn = ps[n];
    float Sl = 0.f;
    float4 acc = make_float4(0.f,0.f,0.f,0.f);
    agg6_edges(beg, end, 64, erec, psn, pd, prs,
               xdb, 512, RRb, 256, lane, Sl, acc);
    float S = Sl;
    #pragma unroll
    for (int o = 32; o; o >>= 1) S += __shfl_xor(S, o, 64);
    agg5_finalize(n, S, acc, lane, XSD, 0, outb, ldb, coffb);
  }
}

// fused layer0 heads (D=100 x2): lanes 0-24 head0, 25-49 head1
__device__ inline void agg6h_edges(int bstart, int end, int bstep,
    const int4* __restrict__ erec,
    float ps0n, const float* __restrict__ pd0, const float* __restrict__ prs0,
    float ps1n, const float* __restrict__ pd1, const float* __restrict__ prs1,
    const __hip_bfloat16* __restrict__ XSD, const __hip_bfloat16* __restrict__ RRb,
    int lane, float& Sl0, float& Sl1, float4& acc)
{
  const bool act = lane < 50;
  const int head = (lane >= 25) ? 1 : 0;
  const int li = lane - 25*head;
  const int loffX = (head ? 384 : 128) + 4*li;
  const int loffR = (head ? 128 : 0) + 4*li;
  for (int b = bstart; b < end; b += bstep){
    int j = b + lane;
    int4 e = make_int4(0, NRELS, NRELS, 0);
    float wv0 = 0.f, wv1 = 0.f;
    if (j < end){
      e = erec[j];
      float lg0 = ps0n + pd0[e.x] + prs0[e.y] + prs0[e.z];
      float lg1 = ps1n + pd1[e.x] + prs1[e.y] + prs1[e.z];
      wv0 = __expf(-((lg0 > 0.f) ? lg0 : 0.2f*lg0));
      wv1 = __expf(-((lg1 > 0.f) ? lg1 : 0.2f*lg1));
    }
    Sl0 += wv0; Sl1 += wv1;
    int m = end - b; if (m > 64) m = 64;
    if (act){
      #pragma unroll 8
      for (int i = 0; i < m; ++i){
        float wH0 = rl_f(wv0, i);
        float wH1 = rl_f(wv1, i);
        int d  = __builtin_amdgcn_readlane(e.x, i);
        int t0 = __builtin_amdgcn_readlane(e.y, i);
        int t1 = __builtin_amdgcn_readlane(e.z, i);
        float w = head ? wH1 : wH0;
        const __hip_bfloat16* xr = XSD + (size_t)d*512;
        const __hip_bfloat16* r0 = RRb + (size_t)t0*256;
        ushort4 xa = *(const ushort4*)(xr + loffX);
        ushort4 ra = *(const ushort4*)(r0 + loffR);
        float sx = bf2f(xa.x)+bf2f(ra.x), sy = bf2f(xa.y)+bf2f(ra.y);
        float sz = bf2f(xa.z)+bf2f(ra.z), sw = bf2f(xa.w)+bf2f(ra.w);
        if (t1 != NRELS){
          const __hip_bfloat16* r1 = RRb + (size_t)t1*256;
          ushort4 rc = *(const ushort4*)(r1 + loffR);
          sx += bf2f(rc.x); sy += bf2f(rc.y); sz += bf2f(rc.z); sw += bf2f(rc.w);
        }
        acc.x += w*sx; acc.y += w*sy; acc.z += w*sz; acc.w += w*sw;
      }
    }
  }
}

__device__ inline void aggh_finalize(int n, float S0, float S1, float4 acc, int lane,
    const __hip_bfloat16* __restrict__ XSD,
    __hip_bfloat16* __restrict__ outb, int ldb)
{
  if (lane >= 50) return;
  int head = (lane >= 25) ? 1 : 0;
  int li = lane - 25*head;
  float S = head ? S1 : S0;
  float inv = (S > 0.f) ? 1.0f/S : 0.f;
  ushort4 xs4 = *(const ushort4*)(XSD + (size_t)n*512 + (head ? 256 : 0) + 4*li);
  float h0 = (S > 0.f) ? bf2f(xs4.x) + acc.x*inv : 0.f;
  float h1 = (S > 0.f) ? bf2f(xs4.y) + acc.y*inv : 0.f;
  float h2 = (S > 0.f) ? bf2f(xs4.z) + acc.z*inv : 0.f;
  float h3 = (S > 0.f) ? bf2f(xs4.w) + acc.w*inv : 0.f;
  h0 = (h0 > 0.f) ? h0 : expm1f(h0);
  h1 = (h1 > 0.f) ? h1 : expm1f(h1);
  h2 = (h2 > 0.f) ? h2 : expm1f(h2);
  h3 = (h3 > 0.f) ? h3 : expm1f(h3);
  ushort4 o; o.x = f2bf(h0); o.y = f2bf(h1); o.z = f2bf(h2); o.w = f2bf(h3);
  *(ushort4*)(outb + (size_t)n*ldb + 100*head + 4*li) = o;
}

__global__ __launch_bounds__(256) void k_aggh(
    const int* __restrict__ rowofs, const int4* __restrict__ erec,
    const float* __restrict__ ps0, const float* __restrict__ pd0, const float* __restrict__ prs0,
    const float* __restrict__ ps1, const float* __restrict__ pd1, const float* __restrict__ prs1,
    const __hip_bfloat16* __restrict__ XSD, const __hip_bfloat16* __restrict__ RRb,
    __hip_bfloat16* __restrict__ outb, int ldb)
{
  __shared__ float4 redA[256];
  __shared__ float redS0[4];
  __shared__ float redS1[4];
  int bid = blockIdx.x;
  int wave = threadIdx.x >> 6, lane = threadIdx.x & 63;

  if (bid < HOTN){
    int n = bid;
    int beg = rowofs[n], end = rowofs[n+1];
    float ps0n = ps0[n], ps1n = ps1[n];
    float Sl0 = 0.f, Sl1 = 0.f;
    float4 acc = make_float4(0.f,0.f,0.f,0.f);
    agg6h_edges(beg + wave*64, end, 256, erec, ps0n, pd0, prs0, ps1n, pd1, prs1,
                XSD, RRb, lane, Sl0, Sl1, acc);
    float Sw0 = Sl0, Sw1 = Sl1;
    #pragma unroll
    for (int o = 32; o; o >>= 1){ Sw0 += __shfl_xor(Sw0, o, 64); Sw1 += __shfl_xor(Sw1, o, 64); }
    redA[threadIdx.x] = acc;
    if (lane == 0){ redS0[wave] = Sw0; redS1[wave] = Sw1; }
    __syncthreads();
    if (wave == 0){
      float4 a0 = redA[lane], a1 = redA[lane+64], a2 = redA[lane+128], a3 = redA[lane+192];
      float4 at = make_float4(a0.x+a1.x+a2.x+a3.x, a0.y+a1.y+a2.y+a3.y,
                              a0.z+a1.z+a2.z+a3.z, a0.w+a1.w+a2.w+a3.w);
      float St0 = redS0[0] + redS0[1] + redS0[2] + redS0[3];
      float St1 = redS1[0] + redS1[1] + redS1[2] + redS1[3];
      aggh_finalize(n, St0, St1, at, lane, XSD, outb, ldb);
    }
  } else {
    int n = HOTN + (bid - HOTN)*4 + wave;
    int beg = rowofs[n], end = rowofs[n+1];
    float ps0n = ps0[n], ps1n = ps1[n];
    float Sl0 = 0.f, Sl1 = 0.f;
    float4 acc = make_float4(0.f,0.f,0.f,0.f);
    agg6h_edges(beg, end, 64, erec, ps0n, pd0, prs0, ps1n, pd1, prs1,
                XSD, RRb, lane, Sl0, Sl1, acc);
    float S0 = Sl0, S1 = Sl1;
    #pragma unroll
    for (int o = 32; o; o >>= 1){ S0 += __shfl_xor(S0, o, 64); S1 += __shfl_xor(S1, o, 64); }
    aggh_finalize(n, S0, S1, acc, lane, XSD, outb, ldb);
  }
}

// ---------------------------------------------------------------- driver
extern "C" void kernel_launch(void* const* d_in, const int* in_sizes, int n_in,
                              void* d_out, int out_size, void* d_ws, size_t ws_size,
                              hipStream_t stream) {
  const float* entity   = (const float*)d_in[0];
  const float* relation = (const float*)d_in[1];
  const float* W_ent    = (const float*)d_in[2];
  const float* g0_a0    = (const float*)d_in[3];
  const float* g0_s0    = (const float*)d_in[4];
  const float* g0_a1    = (const float*)d_in[5];
  const float* g0_s1    = (const float*)d_in[6];
  const float* g0_W     = (const float*)d_in[7];
  const float* g0_oa    = (const float*)d_in[8];
  const float* g0_os    = (const float*)d_in[9];
  const float* g1_a0    = (const float*)d_in[10];
  const float* g1_s0    = (const float*)d_in[11];
  const float* g1_W     = (const float*)d_in[12];
  const float* g1_oa    = (const float*)d_in[13];
  const float* g1_os    = (const float*)d_in[14];
  const int*   el       = (const int*)d_in[15];
  const int*   et       = (const int*)d_in[16];
  const int*   nh       = (const int*)d_in[17];
  const int*   batch    = (const int*)d_in[18];
  (void)in_sizes; (void)n_in; (void)out_size; (void)ws_size;

  char* w = (char*)d_ws;
  auto alloc = [&](size_t bytes)->char*{ char* p = w; w += (bytes + 255) & ~(size_t)255; return p; };
  float* PS0   = (float*)alloc((size_t)NNODES*4);
  float* PD0   = (float*)alloc((size_t)NNODES*4);
  float* PS1   = (float*)alloc((size_t)NNODES*4);
  float* PD1   = (float*)alloc((size_t)NNODES*4);
  float* PRS0  = (float*)alloc((size_t)(NRELS+4)*4);
  float* PRS1  = (float*)alloc((size_t)(NRELS+4)*4);
  float* WT    = (float*)alloc((size_t)2304*4);
  __hip_bfloat16* AENT0  = (__hip_bfloat16*)alloc((size_t)MP*128*2);
  __hip_bfloat16* AX1    = (__hip_bfloat16*)alloc((size_t)MP*224*2);
  __hip_bfloat16* AENT1  = (__hip_bfloat16*)alloc((size_t)MP*224*2);
  __hip_bfloat16* ENTUPb = (__hip_bfloat16*)alloc((size_t)MP*224*2);
  __hip_bfloat16* HB     = (__hip_bfloat16*)alloc((size_t)MP*224*2);
  __hip_bfloat16* AREL0  = (__hip_bfloat16*)alloc((size_t)RPAD*128*2);
  __hip_bfloat16* AREL1  = (__hip_bfloat16*)alloc((size_t)RPAD*224*2);
  __hip_bfloat16* RELUPb = (__hip_bfloat16*)alloc((size_t)RPAD*224*2);
  __hip_bfloat16* ORb0   = (__hip_bfloat16*)alloc((size_t)RPAD*224*2);
  __hip_bfloat16* ORb1   = (__hip_bfloat16*)alloc((size_t)RPAD*224*2);
  __hip_bfloat16* XSD    = (__hip_bfloat16*)alloc((size_t)MP*512*2);
  __hip_bfloat16* RRb    = (__hip_bfloat16*)alloc((size_t)RPAD*256*2);
  __hip_bfloat16* WA     = (__hip_bfloat16*)alloc((size_t)737280*2);
  int* IALL = (int*)alloc((size_t)150001*4);
  int* ROWOFS = IALL;
  int* CUR    = IALL + 50001;
  float* MASK = (float*)(IALL + 100001);
  int4* EREC  = (int4*)alloc((size_t)NETOT*16);
  int* PART   = (int*)alloc((size_t)256*4);

  const __hip_bfloat16* WET   = WA;
  const __hip_bfloat16* G0WT  = WA + 32768;
  const __hip_bfloat16* BH0   = WA + 65536;
  const __hip_bfloat16* BR0   = WA + 131072;
  const __hip_bfloat16* BO0   = WA + 163840;
  const __hip_bfloat16* BO0r  = WA + 278528;
  const __hip_bfloat16* BA1   = WA + 335872;
  const __hip_bfloat16* BA1r  = WA + 450560;
  const __hip_bfloat16* G1WT  = WA + 507904;
  const __hip_bfloat16* BO1   = WA + 565248;
  const __hip_bfloat16* BO1r  = WA + 679936;

  float* outEnt = (float*)d_out;
  float* outRel = outEnt + (size_t)NNODES*200;

  const int TB = 256;
  auto gb = [&](long long n){ return (int)((n + TB - 1)/TB); };
  const int AGG_GRID = HOTN + (NNODES - HOTN)/4;
  const int RD_GRID = 12500 + 126;

  // ---- setup (everything order-independent in one dispatch) ----
  {
    SetupArgs a;
    a.iall = IALL; a.aent0 = AENT0; a.ax1 = AX1; a.aent1 = AENT1; a.arel0 = AREL0; a.arel1 = AREL1;
    a.wt = WT; a.s0h = g0_s0; a.s1h = g0_s1; a.os0 = g0_os; a.s1l = g1_s0; a.os1 = g1_os;
    a.wa = WA;
    a.wsrcs.p[0] = W_ent; a.wsrcs.p[1] = g0_a0; a.wsrcs.p[2] = g0_a1; a.wsrcs.p[3] = g0_W;
    a.wsrcs.p[4] = g0_oa; a.wsrcs.p[5] = g1_a0; a.wsrcs.p[6] = g1_W;  a.wsrcs.p[7] = g1_oa;
    a.entity = entity; a.relation = relation;
    k_setup<<<SB_TOT, 256, 0, stream>>>(a);
  }
  k_mask_set<<<gb(10000), TB, 0, stream>>>(batch, MASK, 10000);
  k_hist<<<gb(NETOT), TB, 0, stream>>>(el, nh, ROWOFS);
  int nsb = (NNODES + 255)/256;
  k_scan1<<<nsb, 256, 0, stream>>>(ROWOFS, NNODES, PART);
  k_scan2<<<1, 256, 0, stream>>>(PART, nsb);
  k_scan3<<<nsb, 256, 0, stream>>>(ROWOFS, NNODES, PART);
  k_scatter<<<gb(NETOT), TB, 0, stream>>>(el, et, nh, ROWOFS, CUR, EREC);

  auto mkdesc = [](const __hip_bfloat16* A, const __hip_bfloat16* B, __hip_bfloat16* C,
                   int M, int Nn, int Kp, int ldc){
    GemmDesc d; d.A = A; d.B = B; d.C = C; d.M = M; d.Nn = Nn; d.Kp = Kp; d.ldc = ldc;
    d.gx = (Nn + 63)/64; d.nblk = d.gx * ((M + 127)/128); return d;
  };
  GemmDesc dnull = {}; dnull.nblk = 0;
  auto gemm2 = [&](GemmDesc d1, GemmDesc d2){
    k_gemm2<<<d1.nblk + d2.nblk, 256, 0, stream>>>(d1, d2);
  };

  // ---- ent_up / rel_up ----
  gemm2(mkdesc(AENT0, WET, ENTUPb, MP, 200, 128, 224),
        mkdesc(AREL0, WET, RELUPb, RPAD, 200, 128, 224));

  // ---- layer0 heads ----
  gemm2(mkdesc(AENT0, BH0, XSD, MP, 512, 128, 512),
        mkdesc(AREL0, BR0, RRb, RPAD, 256, 128, 256));
  k_rowdot3<<<RD_GRID, 256, 0, stream>>>(XSD, WT + 0, 16, PS0, PD0, PS1, PD1,
                                         RRb, WT + 512, 32, PRS0, PRS1);
  k_aggh<<<AGG_GRID, 256, 0, stream>>>(ROWOFS, EREC, PS0, PD0, PRS0, PS1, PD1, PRS1,
                                       XSD, RRb, AX1, 224);

  // ---- layer0 out-attention ----
  gemm2(mkdesc(AX1, BO0, XSD, MP, 512, 224, 512),
        mkdesc(AREL0, G0WT, ORb0, RPAD, 224, 128, 224));
  gemm2(mkdesc(ORb0, BO0r, RRb, RPAD, 256, 224, 256), dnull);
  k_rowdot3<<<RD_GRID, 256, 0, stream>>>(XSD, WT + 768, 32, PS0, PD0, nullptr, nullptr,
                                         RRb, WT + 768, 64, PRS0, nullptr);
  k_agg5<<<AGG_GRID, 256, 0, stream>>>(ROWOFS, EREC, PS0, PD0, PRS0, XSD, RRb, HB, 224, 0);
  k_combine2<false><<<NNODES + NRELS, 64, 0, stream>>>(ENTUPb, HB, MASK, RELUPb, ORb0,
      nullptr, nullptr, AENT1, AREL1);

  // ---- layer1 head ----
  gemm2(mkdesc(AENT1, BA1, XSD, MP, 512, 224, 512),
        mkdesc(AREL1, BA1r, RRb, RPAD, 256, 224, 256));
  k_rowdot3<<<RD_GRID, 256, 0, stream>>>(XSD, WT + 1280, 32, PS0, PD0, nullptr, nullptr,
                                         RRb, WT + 1280, 64, PRS0, nullptr);
  k_agg5<<<AGG_GRID, 256, 0, stream>>>(ROWOFS, EREC, PS0, PD0, PRS0, XSD, RRb, AX1, 224, 0);

  // ---- layer1 out-attention ----
  gemm2(mkdesc(AX1, BO1, XSD, MP, 512, 224, 512),
        mkdesc(AREL1, G1WT, ORb1, RPAD, 224, 224, 224));
  gemm2(mkdesc(ORb1, BO1r, RRb, RPAD, 256, 224, 256), dnull);
  k_rowdot3<<<RD_GRID, 256, 0, stream>>>(XSD, WT + 1792, 32, PS0, PD0, nullptr, nullptr,
                                         RRb, WT + 1792, 64, PRS0, nullptr);
  k_agg5<<<AGG_GRID, 256, 0, stream>>>(ROWOFS, EREC, PS0, PD0, PRS0, XSD, RRb, HB, 224, 0);

  // ---- final combines -> d_out ----
  k_combine2<true><<<NNODES + NRELS, 64, 0, stream>>>(AENT1, HB, MASK, AREL1, ORb1,
      outEnt, outRel, nullptr, nullptr);
}